// Round 8
// baseline (3492.181 us; speedup 1.0000x reference)
//
#include <hip/hip_runtime.h>
#include <hip/hip_bf16.h>

#define NN 100000   // nodes
#define NE 200000   // bonds
#define NB 600000   // bond neighbours
#define FN 133
#define FB 14
#define FIB 147     // FN+FB
#define DD 256

typedef __hip_bfloat16 bf16;
typedef __attribute__((ext_vector_type(8))) short short8;   // 8 bf16 = 4 VGPR
typedef __attribute__((ext_vector_type(4))) float f32x4;

__device__ __forceinline__ float hswish(float x) {
    float c = fminf(fmaxf(x + 3.f, 0.f), 6.f);
    return x * c * (1.f / 6.f);
}
__device__ __forceinline__ float sigmoidf(float x) {
    return 1.f / (1.f + __expf(-x));
}
__device__ __forceinline__ float bf2f(unsigned short u) {
    union { unsigned int i; float f; } c; c.i = (unsigned int)u << 16; return c.f;
}
__device__ __forceinline__ unsigned short f2bf(float v) {
    bf16 b = __float2bfloat16(v);
    unsigned short u; __builtin_memcpy(&u, &b, 2); return u;
}
__device__ __forceinline__ void unp8(short8 v, float* f) {
    #pragma unroll
    for (int j = 0; j < 8; j++) {
        short s = v[j]; unsigned short u; __builtin_memcpy(&u, &s, 2);
        f[j] = bf2f(u);
    }
}
__device__ __forceinline__ uint4 pk8(const float* f) {
    uint4 v;
    v.x = f2bf(f[0]) | ((unsigned)f2bf(f[1]) << 16);
    v.y = f2bf(f[2]) | ((unsigned)f2bf(f[3]) << 16);
    v.z = f2bf(f[4]) | ((unsigned)f2bf(f[5]) << 16);
    v.w = f2bf(f[6]) | ((unsigned)f2bf(f[7]) << 16);
    return v;
}

// ---------------- fill (zero counts + ws-guard sentinel) ----------------
__global__ __launch_bounds__(256) void fill_kernel(float* __restrict__ p, float v, long n4) {
    long i = (long)blockIdx.x * 256 + threadIdx.x;
    long st = (long)gridDim.x * 256;
    float4 z = {v, v, v, v};
    for (; i < n4; i += st) ((float4*)p)[i] = z;
}

// ---------------- IB build: IBbf[e][160] = [node[i_idx[e]] | bond[e] | 0]
__global__ __launch_bounds__(256) void build_ib_bf(
    const float* __restrict__ node, const float* __restrict__ bond,
    const int* __restrict__ i_idx, bf16* __restrict__ IB)
{
    int t = blockIdx.x * 256 + threadIdx.x;
    int row = t >> 6;
    if (row >= NE) return;
    int lane = t & 63;
    if (lane >= 40) return;
    int src = i_idx[row];
    int c = lane * 4;
    unsigned short us[4];
    #pragma unroll
    for (int j = 0; j < 4; j++) {
        int k = c + j;
        float v = 0.f;
        if (k < FN)       v = node[(size_t)src * FN + k];
        else if (k < FIB) v = bond[(size_t)row * FB + (k - FN)];
        us[j] = f2bf(v);
    }
    ushort4 o = {us[0], us[1], us[2], us[3]};
    *(ushort4*)((unsigned short*)IB + (size_t)row * 160 + c) = o;
}

// ---------------- CSR build helpers -------------------------------------
__global__ __launch_bounds__(256) void count_kernel(
    const int* __restrict__ idx, int n, int* __restrict__ cnt)
{
    int i = blockIdx.x * 256 + threadIdx.x;
    if (i < n) atomicAdd(&cnt[idx[i]], 1);
}

__global__ __launch_bounds__(256) void scan_block(int* __restrict__ data, int* __restrict__ bsum)
{
    __shared__ int lds[256];
    int base = blockIdx.x * 1024 + threadIdx.x * 4;
    int c0 = data[base], c1 = data[base + 1], c2 = data[base + 2], c3 = data[base + 3];
    int t = c0 + c1 + c2 + c3;
    lds[threadIdx.x] = t;
    __syncthreads();
    int x = t;
    for (int off = 1; off < 256; off <<= 1) {
        int y = (threadIdx.x >= off) ? lds[threadIdx.x - off] : 0;
        __syncthreads();
        x += y; lds[threadIdx.x] = x;
        __syncthreads();
    }
    int excl = x - t;
    data[base] = excl; data[base + 1] = excl + c0;
    data[base + 2] = excl + c0 + c1; data[base + 3] = excl + c0 + c1 + c2;
    if (threadIdx.x == 255) bsum[blockIdx.x] = x;
}

__global__ __launch_bounds__(256) void scan_bsum(int* __restrict__ bsum, int n)
{
    __shared__ int lds[256];
    int t = (threadIdx.x < n) ? bsum[threadIdx.x] : 0;
    lds[threadIdx.x] = t;
    __syncthreads();
    int x = t;
    for (int off = 1; off < 256; off <<= 1) {
        int y = (threadIdx.x >= off) ? lds[threadIdx.x - off] : 0;
        __syncthreads();
        x += y; lds[threadIdx.x] = x;
        __syncthreads();
    }
    if (threadIdx.x < n) bsum[threadIdx.x] = x - t;
}

__global__ __launch_bounds__(256) void scan_add(
    int* __restrict__ data, const int* __restrict__ bsum, int n)
{
    int i = blockIdx.x * 256 + threadIdx.x;
    if (i < n) data[i] += bsum[i >> 10];
}

__global__ __launch_bounds__(256) void copy_int(
    int* __restrict__ dst, const int* __restrict__ src, int n)
{
    int i = blockIdx.x * 256 + threadIdx.x;
    if (i < n) dst[i] = src[i];
}

__global__ __launch_bounds__(256) void fill_nb_list(
    const int* __restrict__ ij, const int* __restrict__ ki,
    int* __restrict__ cur, int* __restrict__ lst)
{
    int e = blockIdx.x * 256 + threadIdx.x;
    if (e < NB) { int p = atomicAdd(&cur[ij[e]], 1); lst[p] = ki[e]; }
}

__global__ __launch_bounds__(256) void fill_agg_list(
    const int* __restrict__ jidx, int* __restrict__ cur, int* __restrict__ lst)
{
    int e = blockIdx.x * 256 + threadIdx.x;
    if (e < NE) { int p = atomicAdd(&cur[jidx[e]], 1); lst[p] = e; }
}

// ---------------- CSR segment sum (AGG only) ----------------------------
__global__ __launch_bounds__(256) void seg_s_kernel(
    const bf16* __restrict__ MB, const int* __restrict__ off,
    const int* __restrict__ lst, bf16* __restrict__ S, int nseg)
{
    int sid = blockIdx.x * 4 + (threadIdx.x >> 6);
    if (sid >= nseg) return;
    int lane = threadIdx.x & 63;
    int b = off[sid], e = off[sid + 1];
    float a0 = 0, a1 = 0, a2 = 0, a3 = 0;
    for (int t = b; t < e; t++) {
        int src = lst[t];
        ushort4 u = *(const ushort4*)((const unsigned short*)MB + (size_t)src * DD + lane * 4);
        a0 += bf2f(u.x); a1 += bf2f(u.y); a2 += bf2f(u.z); a3 += bf2f(u.w);
    }
    ushort4 o = {f2bf(a0), f2bf(a1), f2bf(a2), f2bf(a3)};
    *(ushort4*)((unsigned short*)S + (size_t)sid * DD + lane * 4) = o;
}

// ------------- weight pack: dst[n][k] = bf16(seg(k, n)), K-padded -------
__global__ __launch_bounds__(256) void pack_wt(
    const float* W1, int K1, const float* W2, int K2, const float* W3, int K3,
    int KTpad, bf16* dst)
{
    int idx = blockIdx.x * 256 + threadIdx.x;
    if (idx >= 256 * KTpad) return;
    int n = idx / KTpad, k = idx % KTpad;
    float v = 0.f;
    if (k < K1)                { if (W1) v = W1[(size_t)k * DD + n]; }
    else if (k < K1 + K2)      { if (W2) v = W2[(size_t)(k - K1) * DD + n]; }
    else if (k < K1 + K2 + K3) { if (W3) v = W3[(size_t)(k - K1 - K2) * DD + n]; }
    dst[(size_t)n * KTpad + k] = __float2bfloat16(v);
}

// ---------------- unified MFMA GEMM, all-vector staging -----------------
// (same as round 7)
template <int BN, int NT, int DUAL, int EPB>
__global__ __launch_bounds__(NT) void bg(
    const void* __restrict__ A1, int a1stride, int a1kw, int a1real, int a1f32,
    const void* __restrict__ A2, int a2stride, int a2kw, int a2real, int a2f32,
    const bf16* __restrict__ WT1, const bf16* __restrict__ WT2, int KT,
    const float* __restrict__ bias1, const float* __restrict__ bias2,
    const bf16* __restrict__ PZb, const bf16* __restrict__ PMb,
    void* __restrict__ out1, void* __restrict__ out2, int M)
{
    constexpr int BM = 128;
    constexpr int nWc = BN / 64;
    constexpr int nWr = (NT / 64) / nWc;
    constexpr int MSPAN = BM / nWr;
    constexpr int MFR = MSPAN / 16;
    __shared__ __align__(16) unsigned short As[BM * 40];
    __shared__ __align__(16) unsigned short As2[(DUAL == 2 ? BM : 8) * 40];
    __shared__ __align__(16) unsigned short Bs[BN * 40];
    __shared__ __align__(16) unsigned short Bs2[(DUAL ? BN : 8) * 40];
    const int tid = threadIdx.x;
    const int row0 = blockIdx.x * BM, col0 = blockIdx.y * BN;
    const int lane = tid & 63, w = tid >> 6;
    const int wr = w / nWc, wc = w % nWc;
    const int fr = lane & 15, ko = (lane >> 4) * 8;

    f32x4 acc[MFR][4] = {};
    f32x4 acc2[DUAL ? MFR : 1][DUAL ? 4 : 1] = {};

    for (int k0 = 0; k0 < KT; k0 += 32) {
        #pragma unroll
        for (int it = 0; it < BM * 4 / NT; ++it) {
            int mloc = (tid >> 2) + it * (NT / 4);
            int mg = row0 + mloc;
            bool mok = (mg < M);
            int kq = (tid & 3) * 8;
            int kg = k0 + kq;
            if (DUAL == 2) {
                uint4 v1 = {0, 0, 0, 0}, v2 = {0, 0, 0, 0};
                if (mok) {
                    v1 = *(const uint4*)((const bf16*)A1 + (size_t)mg * a1stride + kg);
                    v2 = *(const uint4*)((const bf16*)A2 + (size_t)mg * a2stride + kg);
                }
                *(uint4*)&As[mloc * 40 + kq] = v1;
                *(uint4*)&As2[mloc * 40 + kq] = v2;
            } else {
                const void* p; int stride, real, isf; int kk;
                if (kg < a1kw) { p = A1; stride = a1stride; real = a1real; isf = a1f32; kk = kg; }
                else           { p = A2; stride = a2stride; real = a2real; isf = a2f32; kk = kg - a1kw; }
                uint4 v = {0, 0, 0, 0};
                if (mok) {
                    if (!isf) {
                        v = *(const uint4*)((const bf16*)p + (size_t)mg * stride + kk);
                    } else {
                        const float* fp = (const float*)p + (size_t)mg * stride;
                        unsigned short us[8];
                        #pragma unroll
                        for (int j = 0; j < 8; j++)
                            us[j] = (kk + j < real) ? f2bf(fp[kk + j]) : (unsigned short)0;
                        v.x = us[0] | ((unsigned)us[1] << 16);
                        v.y = us[2] | ((unsigned)us[3] << 16);
                        v.z = us[4] | ((unsigned)us[5] << 16);
                        v.w = us[6] | ((unsigned)us[7] << 16);
                    }
                }
                *(uint4*)&As[mloc * 40 + kq] = v;
            }
        }
        #pragma unroll
        for (int it = 0; it < BN * 4 / NT; ++it) {
            int nloc = (tid >> 2) + it * (NT / 4);
            int kq = (tid & 3) * 8;
            *(uint4*)&Bs[nloc * 40 + kq] =
                *(const uint4*)&WT1[(size_t)(col0 + nloc) * KT + k0 + kq];
            if (DUAL)
                *(uint4*)&Bs2[nloc * 40 + kq] =
                    *(const uint4*)&WT2[(size_t)(col0 + nloc) * KT + k0 + kq];
        }
        __syncthreads();
        short8 a1f[MFR], b1f[4];
        short8 a2f[DUAL == 2 ? MFR : 1], b2f[DUAL ? 4 : 1];
        #pragma unroll
        for (int mf = 0; mf < MFR; mf++) {
            a1f[mf] = *(const short8*)&As[(wr * MSPAN + mf * 16 + fr) * 40 + ko];
            if (DUAL == 2)
                a2f[mf] = *(const short8*)&As2[(wr * MSPAN + mf * 16 + fr) * 40 + ko];
        }
        #pragma unroll
        for (int nf = 0; nf < 4; nf++) {
            b1f[nf] = *(const short8*)&Bs[(wc * 64 + nf * 16 + fr) * 40 + ko];
            if (DUAL)
                b2f[nf] = *(const short8*)&Bs2[(wc * 64 + nf * 16 + fr) * 40 + ko];
        }
        #pragma unroll
        for (int mf = 0; mf < MFR; mf++)
            #pragma unroll
            for (int nf = 0; nf < 4; nf++) {
                acc[mf][nf] = __builtin_amdgcn_mfma_f32_16x16x32_bf16(a1f[mf], b1f[nf], acc[mf][nf], 0, 0, 0);
                if (DUAL)
                    acc2[mf][nf] = __builtin_amdgcn_mfma_f32_16x16x32_bf16(
                        DUAL == 2 ? a2f[mf] : a1f[mf], b2f[nf], acc2[mf][nf], 0, 0, 0);
            }
        __syncthreads();
    }

    #pragma unroll
    for (int mf = 0; mf < MFR; mf++) {
        #pragma unroll
        for (int i = 0; i < 4; i++) {
            int mloc = wr * MSPAN + mf * 16 + (lane >> 4) * 4 + i;
            int gm = row0 + mloc;
            if (gm >= M) continue;
            #pragma unroll
            for (int nf = 0; nf < 4; nf++) {
                int gc = col0 + wc * 64 + nf * 16 + fr;
                size_t idx = (size_t)gm * DD + gc;
                float v = acc[mf][nf][i];
                if (EPB == 0) {
                    if (bias1) v += bias1[gc];
                    ((bf16*)out1)[idx] = __float2bfloat16(v);
                } else if (EPB == 1) {
                    ((bf16*)out1)[idx] = __float2bfloat16(hswish(v + bias1[gc]));
                } else if (EPB == 2) {
                    ((bf16*)out1)[idx] = __float2bfloat16(hswish(v + bias1[gc]));
                    ((bf16*)out2)[idx] = __float2bfloat16(acc2[mf][nf][i] + bias2[gc]);
                } else if (EPB == 3) {
                    ((bf16*)out1)[idx] = __float2bfloat16(v + bias1[gc]);
                    ((bf16*)out2)[idx] = __float2bfloat16(acc2[mf][nf][i] + bias2[gc]);
                } else if (EPB == 4) {
                    float z  = sigmoidf(v + __bfloat162float(PZb[idx]));
                    float mm = tanhf(acc2[mf][nf][i] + __bfloat162float(PMb[idx]));
                    float s  = __bfloat162float(((const bf16*)A1)[idx]);
                    ((bf16*)out1)[idx] = __float2bfloat16((1.f - z) * s + z * mm);
                } else if (EPB == 5) {
                    ((bf16*)out1)[idx] =
                        __float2bfloat16(hswish(v + __bfloat162float(PZb[idx])));
                } else {  // EPB == 6
                    ((float*)out1)[idx] = hswish(v + bias1[gc]);
                }
            }
        }
    }
}

// ============ fused seg_s + seg_r + blend, S/R never hit global =========
// Per 128-bond block: gather R->LDS, acc2 = R@WTu; gather S->same LDS,
// acc1 = S@WTz2; epilogue: z=sig(acc1+PZ), m=tanh(acc2+PM),
// MBnext = (1-z)*S(LDS) + z*m.
__global__ __launch_bounds__(512) void fblend(
    const bf16* __restrict__ MBcur, const bf16* __restrict__ TRg,
    const bf16* __restrict__ PRg, const bf16* __restrict__ PZg,
    const bf16* __restrict__ PMg,
    const int* __restrict__ off, const int* __restrict__ lst,
    const bf16* __restrict__ WTz2, const bf16* __restrict__ WTu,
    bf16* __restrict__ MBnext)
{
    __shared__ __align__(16) unsigned short Al[128 * 264];  // 67.6 KB
    __shared__ __align__(16) unsigned short Bs[256 * 40];   // 20.5 KB
    const int tid = threadIdx.x;
    const int row0 = blockIdx.x * 128;
    const int lane = tid & 63, w = tid >> 6;
    const int wr = w >> 2, wc = w & 3;          // 2 x 4 wave grid
    const int fr = lane & 15, ko = (lane >> 4) * 8;
    const int sw = tid >> 5, li = tid & 31;     // gather: 16 half-waves

    f32x4 acc1[4][4] = {};
    f32x4 acc2[4][4] = {};

    // ---------- gather R into Al ----------
    for (int rr = 0; rr < 8; rr++) {
        int r = sw * 8 + rr;
        int sid = row0 + r;
        float a[8] = {0, 0, 0, 0, 0, 0, 0, 0};
        if (sid < NE) {
            float p[8];
            unp8(*(const short8*)((const unsigned short*)PRg + (size_t)sid * DD + li * 8), p);
            int b = off[sid], e = off[sid + 1];
            for (int t = b; t < e; t++) {
                int src = lst[t];
                float tf[8], mf8[8];
                unp8(*(const short8*)((const unsigned short*)TRg + (size_t)src * DD + li * 8), tf);
                unp8(*(const short8*)((const unsigned short*)MBcur + (size_t)src * DD + li * 8), mf8);
                #pragma unroll
                for (int j = 0; j < 8; j++)
                    a[j] += sigmoidf(p[j] + tf[j]) * mf8[j];
            }
        }
        *(uint4*)&Al[r * 264 + li * 8] = pk8(a);
    }
    __syncthreads();

    // ---------- acc2 = R @ WTu ----------
    for (int k0 = 0; k0 < DD; k0 += 32) {
        #pragma unroll
        for (int it = 0; it < 2; ++it) {
            int nloc = (tid >> 2) + it * 128;
            int kq = (tid & 3) * 8;
            *(uint4*)&Bs[nloc * 40 + kq] =
                *(const uint4*)((const unsigned short*)WTu + (size_t)nloc * DD + k0 + kq);
        }
        __syncthreads();
        short8 af[4], bf8[4];
        #pragma unroll
        for (int mf = 0; mf < 4; mf++)
            af[mf] = *(const short8*)&Al[(wr * 64 + mf * 16 + fr) * 264 + k0 + ko];
        #pragma unroll
        for (int nf = 0; nf < 4; nf++)
            bf8[nf] = *(const short8*)&Bs[(wc * 64 + nf * 16 + fr) * 40 + ko];
        #pragma unroll
        for (int mf = 0; mf < 4; mf++)
            #pragma unroll
            for (int nf = 0; nf < 4; nf++)
                acc2[mf][nf] = __builtin_amdgcn_mfma_f32_16x16x32_bf16(af[mf], bf8[nf], acc2[mf][nf], 0, 0, 0);
        __syncthreads();
    }

    // ---------- gather S into Al (overwrites R) ----------
    for (int rr = 0; rr < 8; rr++) {
        int r = sw * 8 + rr;
        int sid = row0 + r;
        float a[8] = {0, 0, 0, 0, 0, 0, 0, 0};
        if (sid < NE) {
            int b = off[sid], e = off[sid + 1];
            for (int t = b; t < e; t++) {
                int src = lst[t];
                float mf8[8];
                unp8(*(const short8*)((const unsigned short*)MBcur + (size_t)src * DD + li * 8), mf8);
                #pragma unroll
                for (int j = 0; j < 8; j++) a[j] += mf8[j];
            }
        }
        *(uint4*)&Al[r * 264 + li * 8] = pk8(a);
    }
    __syncthreads();

    // ---------- acc1 = S @ WTz2 ----------
    for (int k0 = 0; k0 < DD; k0 += 32) {
        #pragma unroll
        for (int it = 0; it < 2; ++it) {
            int nloc = (tid >> 2) + it * 128;
            int kq = (tid & 3) * 8;
            *(uint4*)&Bs[nloc * 40 + kq] =
                *(const uint4*)((const unsigned short*)WTz2 + (size_t)nloc * DD + k0 + kq);
        }
        __syncthreads();
        short8 af[4], bf8[4];
        #pragma unroll
        for (int mf = 0; mf < 4; mf++)
            af[mf] = *(const short8*)&Al[(wr * 64 + mf * 16 + fr) * 264 + k0 + ko];
        #pragma unroll
        for (int nf = 0; nf < 4; nf++)
            bf8[nf] = *(const short8*)&Bs[(wc * 64 + nf * 16 + fr) * 40 + ko];
        #pragma unroll
        for (int mf = 0; mf < 4; mf++)
            #pragma unroll
            for (int nf = 0; nf < 4; nf++)
                acc1[mf][nf] = __builtin_amdgcn_mfma_f32_16x16x32_bf16(af[mf], bf8[nf], acc1[mf][nf], 0, 0, 0);
        __syncthreads();
    }

    // ---------- epilogue: blend (S read from LDS) ----------
    #pragma unroll
    for (int mf = 0; mf < 4; mf++) {
        #pragma unroll
        for (int i = 0; i < 4; i++) {
            int mloc = wr * 64 + mf * 16 + (lane >> 4) * 4 + i;
            int gm = row0 + mloc;
            if (gm >= NE) continue;
            #pragma unroll
            for (int nf = 0; nf < 4; nf++) {
                int gc = wc * 64 + nf * 16 + fr;
                size_t idx = (size_t)gm * DD + gc;
                float z  = sigmoidf(acc1[mf][nf][i] + __bfloat162float(PZg[idx]));
                float mm = tanhf(acc2[mf][nf][i] + __bfloat162float(PMg[idx]));
                float s  = bf2f(Al[mloc * 264 + gc]);
                MBnext[idx] = __float2bfloat16((1.f - z) * s + z * mm);
            }
        }
    }
}

extern "C" void kernel_launch(void* const* d_in, const int* in_sizes, int n_in,
                              void* d_out, int out_size, void* d_ws, size_t ws_size,
                              hipStream_t stream)
{
    const float* node  = (const float*)d_in[0];
    const float* bond  = (const float*)d_in[1];
    const int* connect = (const int*)d_in[2];
    const int* bnb     = (const int*)d_in[3];
    const float* w_node       = (const float*)d_in[4];
    const float* b_node       = (const float*)d_in[5];
    const float* w_node_final = (const float*)d_in[6];
    const float* b_node_final = (const float*)d_in[7];
    const float* w_bond       = (const float*)d_in[8];
    const float* b_bond       = (const float*)d_in[9];
    const float* w_bond_final = (const float*)d_in[10];
    const float* b_bond_final = (const float*)d_in[11];
    const float* w_z = (const float*)d_in[12];
    const float* b_z = (const float*)d_in[13];
    const float* w_r = (const float*)d_in[14];
    const float* b_r = (const float*)d_in[15];
    const float* u_  = (const float*)d_in[16];
    const float* w_m = (const float*)d_in[17];
    const float* b_m = (const float*)d_in[18];
    const float* w_n = (const float*)d_in[19];
    const float* b_n = (const float*)d_in[20];
    const float* u_n = (const float*)d_in[21];

    const int* i_idx = connect;
    const int* j_idx = connect + NE;
    const int* ij    = bnb;
    const int* ki    = bnb + NB;

    const size_t EBH = (size_t)NE * DD * 2;        // 102,400,000
    const size_t B_WT = (size_t)3072 * 256 * 2;    // 1.57 MB packed weights
    const int NEpad = 196 * 1024;
    const int NNpad = 98 * 1024;
    const size_t B_CSR = (size_t)NEpad * 8 + (size_t)NB * 4
                       + (size_t)NNpad * 8 + (size_t)NE * 4 + 2048;
    const size_t NEED = 5 * EBH + B_WT + B_CSR;    // ~519.4 MB (known to fit)

    float* out_node = (float*)d_out;
    float* out_bond = out_node + (size_t)NN * DD;

    if (ws_size < NEED) {
        fill_kernel<<<2048, 256, 0, stream>>>((float*)d_out, 1e6f, (long)out_size / 4);
        return;
    }

    char* base = (char*)d_ws;
    bf16* PR  = (bf16*)base;                      base += EBH;
    bf16* MBa = (bf16*)base;                      base += EBH;
    bf16* TR  = (bf16*)base;                      base += EBH;   // also IBbf / AGG / final-node scratch
    bf16* PZ  = (bf16*)base;                      base += EBH;
    bf16* PM  = (bf16*)base;                      base += EBH;
    char* wt = base;                              base += B_WT;
    int* offE  = (int*)base;                      base += (size_t)NEpad * 4;
    int* curE  = (int*)base;                      base += (size_t)NEpad * 4;
    int* nbLst = (int*)base;                      base += (size_t)NB * 4;
    int* offN  = (int*)base;                      base += (size_t)NNpad * 4;
    int* curN  = (int*)base;                      base += (size_t)NNpad * 4;
    int* agLst = (int*)base;                      base += (size_t)NE * 4;
    int* bsumE = (int*)base;                      base += 1024;
    int* bsumN = (int*)base;

    bf16* IBbf = TR;                 // pre-loop + rebuilt post-loop
    bf16* AGG  = TR;                 // loop-internal (TR dead after fblend)
    float* scratchN = (float*)TR;    // final node f32 output
    bf16* MBb = (bf16*)out_bond;     // MB double-buffer, out region
    bf16* MN = (bf16*)out_node;
    bf16* PN = MN + (size_t)NN * DD;

    auto wtAlloc = [&](size_t elems) { bf16* p = (bf16*)wt; wt += elems * 2; return p; };
    bf16* WTr  = wtAlloc(160 * 256);   // w_r[0:147]
    bf16* WTz1 = wtAlloc(160 * 256);   // w_z[0:147]
    bf16* WTb  = wtAlloc(160 * 256);   // w_bond
    bf16* WTm1 = wtAlloc(160 * 256);   // w_m
    bf16* WTn0 = wtAlloc(160 * 256);   // w_node
    bf16* WTn  = wtAlloc(160 * 256);   // w_n
    bf16* WTr2 = wtAlloc(256 * 256);   // w_r[147:403]
    bf16* WTz2 = wtAlloc(256 * 256);   // w_z[147:403]
    bf16* WTu  = wtAlloc(256 * 256);   // u
    bf16* WTnu = wtAlloc(512 * 256);   // u_n
    bf16* WTbf = wtAlloc(416 * 256);   // w_bond_final: 147 | 13 zeros | 256
    bf16* WTnf = wtAlloc(416 * 256);   // w_node_final: 133 | 27 zeros | 256

    const float* w_r2 = w_r + (size_t)FIB * DD;
    const float* w_z2 = w_z + (size_t)FIB * DD;

    auto packG = [&](int ktpad) { return (256 * ktpad + 255) / 256; };
    pack_wt<<<packG(160), 256, 0, stream>>>(w_r, FIB, nullptr, 0, nullptr, 0, 160, WTr);
    pack_wt<<<packG(160), 256, 0, stream>>>(w_z, FIB, nullptr, 0, nullptr, 0, 160, WTz1);
    pack_wt<<<packG(160), 256, 0, stream>>>(w_bond, FIB, nullptr, 0, nullptr, 0, 160, WTb);
    pack_wt<<<packG(160), 256, 0, stream>>>(w_m, FIB, nullptr, 0, nullptr, 0, 160, WTm1);
    pack_wt<<<packG(160), 256, 0, stream>>>(w_node, FN, nullptr, 0, nullptr, 0, 160, WTn0);
    pack_wt<<<packG(160), 256, 0, stream>>>(w_n, FN, nullptr, 0, nullptr, 0, 160, WTn);
    pack_wt<<<packG(256), 256, 0, stream>>>(w_r2, DD, nullptr, 0, nullptr, 0, 256, WTr2);
    pack_wt<<<packG(256), 256, 0, stream>>>(w_z2, DD, nullptr, 0, nullptr, 0, 256, WTz2);
    pack_wt<<<packG(256), 256, 0, stream>>>(u_, DD, nullptr, 0, nullptr, 0, 256, WTu);
    pack_wt<<<packG(512), 256, 0, stream>>>(u_n, 2 * DD, nullptr, 0, nullptr, 0, 512, WTnu);
    pack_wt<<<packG(416), 256, 0, stream>>>(w_bond_final, FIB, nullptr, 13,
                                            w_bond_final + (size_t)FIB * DD, DD, 416, WTbf);
    pack_wt<<<packG(416), 256, 0, stream>>>(w_node_final, FN, nullptr, 27,
                                            w_node_final + (size_t)FN * DD, DD, 416, WTnf);

    // ---- CSR build (layer-invariant) ----
    fill_kernel<<<256, 256, 0, stream>>>((float*)offE, 0.f, NEpad / 4);
    fill_kernel<<<256, 256, 0, stream>>>((float*)offN, 0.f, NNpad / 4);
    count_kernel<<<(NB + 255) / 256, 256, 0, stream>>>(ij, NB, offE);
    count_kernel<<<(NE + 255) / 256, 256, 0, stream>>>(j_idx, NE, offN);
    scan_block<<<196, 256, 0, stream>>>(offE, bsumE);
    scan_bsum<<<1, 256, 0, stream>>>(bsumE, 196);
    scan_add<<<NEpad / 256, 256, 0, stream>>>(offE, bsumE, NEpad);
    scan_block<<<98, 256, 0, stream>>>(offN, bsumN);
    scan_bsum<<<1, 256, 0, stream>>>(bsumN, 98);
    scan_add<<<NNpad / 256, 256, 0, stream>>>(offN, bsumN, NNpad);
    copy_int<<<NEpad / 256, 256, 0, stream>>>(curE, offE, NEpad);
    copy_int<<<NNpad / 256, 256, 0, stream>>>(curN, offN, NNpad);
    fill_nb_list<<<(NB + 255) / 256, 256, 0, stream>>>(ij, ki, curE, nbLst);
    fill_agg_list<<<(NE + 255) / 256, 256, 0, stream>>>(j_idx, curN, agLst);

    dim3 gB2(1563, 2);    // NE rows, BN=128
    dim3 gB1(1563, 1);    // NE rows, BN=256
    dim3 gN2(782, 2);     // NN rows, BN=128
    dim3 gN1(782, 1);     // NN rows, BN=256
    int blkIB = NE * 64 / 256;

    // ---- pre-loop: IB once, hoisted layer-invariant GEMMs ----
    build_ib_bf<<<blkIB, 256, 0, stream>>>(node, bond, i_idx, IBbf);
    bg<128, 512, 1, 3><<<gB2, 512, 0, stream>>>(        // PR, PZ
        IBbf, 160, 160, 160, 0, nullptr, 0, 0, 0, 0,
        WTr, WTz1, 160, b_r, b_z, nullptr, nullptr, PR, PZ, NE);
    bg<128, 512, 1, 2><<<gB2, 512, 0, stream>>>(        // MB (-> MBb), PM
        IBbf, 160, 160, 160, 0, nullptr, 0, 0, 0, 0,
        WTb, WTm1, 160, b_bond, b_m, nullptr, nullptr, MBb, PM, NE);
    bg<128, 512, 1, 2><<<gN2, 512, 0, stream>>>(        // MN, PN
        node, FN, 160, FN, 1, nullptr, 0, 0, 0, 0,
        WTn0, WTn, 160, b_node, b_n, nullptr, nullptr, MN, PN, NN);

    // MB double-buffer: l0 reads MBb -> MBa; l1 MBa -> MBb; l2 MBb -> MBa
    bf16* MBr = MBb;
    bf16* MBw = MBa;
    for (int l = 0; l < 3; l++) {
        bg<256, 512, 0, 0><<<gB1, 512, 0, stream>>>(    // TR = MBr @ w_r2
            MBr, 256, 256, 256, 0, nullptr, 0, 0, 0, 0,
            WTr2, nullptr, 256, nullptr, nullptr, nullptr, nullptr, TR, nullptr, NE);
        fblend<<<1563, 512, 0, stream>>>(MBr, TR, PR, PZ, PM,
                                         offE, nbLst, WTz2, WTu, MBw);
        seg_s_kernel<<<(NN + 3) / 4, 256, 0, stream>>>(MBw, offN, agLst, AGG, NN);
        bg<256, 512, 0, 5><<<gN1, 512, 0, stream>>>(    // MN = hsw([MN|AGG]@u_n + PN)
            MN, 256, 256, 256, 0, AGG, 256, 256, 256, 0,
            WTnu, nullptr, 512, nullptr, nullptr, PN, nullptr, MN, nullptr, NN);
        bf16* t = MBr; MBr = MBw; MBw = t;
    }
    // after loop MBr == MBa (ws): final mess_bond

    // ---- finals ----
    build_ib_bf<<<blkIB, 256, 0, stream>>>(node, bond, i_idx, IBbf);  // TR slot free
    bg<256, 512, 0, 6><<<gB1, 512, 0, stream>>>(        // bond final -> f32 out_bond
        IBbf, 160, 160, 160, 0, MBa, 256, 256, 256, 0,
        WTbf, nullptr, 416, b_bond_final, nullptr, nullptr, nullptr, out_bond, nullptr, NE);
    bg<256, 512, 0, 6><<<gN1, 512, 0, stream>>>(        // node final -> f32 scratch
        node, FN, 160, FN, 1, MN, 256, 256, 256, 0,
        WTnf, nullptr, 416, b_node_final, nullptr, nullptr, nullptr, scratchN, nullptr, NN);
    hipMemcpyAsync(out_node, scratchN, (size_t)NN * DD * 4,
                   hipMemcpyDeviceToDevice, stream);
}

// Round 9
// 3054.800 us; speedup vs baseline: 1.1432x; 1.1432x over previous
//
#include <hip/hip_runtime.h>
#include <hip/hip_bf16.h>

#define NN 100000   // nodes
#define NE 200000   // bonds
#define NB 600000   // bond neighbours
#define FN 133
#define FB 14
#define FIB 147     // FN+FB
#define DD 256

typedef __hip_bfloat16 bf16;
typedef __attribute__((ext_vector_type(8))) short short8;   // 8 bf16 = 4 VGPR
typedef __attribute__((ext_vector_type(4))) float f32x4;

__device__ __forceinline__ float hswish(float x) {
    float c = fminf(fmaxf(x + 3.f, 0.f), 6.f);
    return x * c * (1.f / 6.f);
}
__device__ __forceinline__ float sigmoidf(float x) {
    return 1.f / (1.f + __expf(-x));
}
__device__ __forceinline__ float bf2f(unsigned short u) {
    union { unsigned int i; float f; } c; c.i = (unsigned int)u << 16; return c.f;
}
__device__ __forceinline__ unsigned short f2bf(float v) {
    bf16 b = __float2bfloat16(v);
    unsigned short u; __builtin_memcpy(&u, &b, 2); return u;
}

// ---------------- fill (zero counts + ws-guard sentinel) ----------------
__global__ __launch_bounds__(256) void fill_kernel(float* __restrict__ p, float v, long n4) {
    long i = (long)blockIdx.x * 256 + threadIdx.x;
    long st = (long)gridDim.x * 256;
    float4 z = {v, v, v, v};
    for (; i < n4; i += st) ((float4*)p)[i] = z;
}

// ---------------- IB build: IBbf[e][160] = [node[i_idx[e]] | bond[e] | 0]
__global__ __launch_bounds__(256) void build_ib_bf(
    const float* __restrict__ node, const float* __restrict__ bond,
    const int* __restrict__ i_idx, bf16* __restrict__ IB)
{
    int t = blockIdx.x * 256 + threadIdx.x;
    int row = t >> 6;
    if (row >= NE) return;
    int lane = t & 63;
    if (lane >= 40) return;
    int src = i_idx[row];
    int c = lane * 4;
    unsigned short us[4];
    #pragma unroll
    for (int j = 0; j < 4; j++) {
        int k = c + j;
        float v = 0.f;
        if (k < FN)       v = node[(size_t)src * FN + k];
        else if (k < FIB) v = bond[(size_t)row * FB + (k - FN)];
        us[j] = f2bf(v);
    }
    ushort4 o = {us[0], us[1], us[2], us[3]};
    *(ushort4*)((unsigned short*)IB + (size_t)row * 160 + c) = o;
}

// ---------------- CSR build helpers -------------------------------------
__global__ __launch_bounds__(256) void count_kernel(
    const int* __restrict__ idx, int n, int* __restrict__ cnt)
{
    int i = blockIdx.x * 256 + threadIdx.x;
    if (i < n) atomicAdd(&cnt[idx[i]], 1);
}

__global__ __launch_bounds__(256) void scan_block(int* __restrict__ data, int* __restrict__ bsum)
{
    __shared__ int lds[256];
    int base = blockIdx.x * 1024 + threadIdx.x * 4;
    int c0 = data[base], c1 = data[base + 1], c2 = data[base + 2], c3 = data[base + 3];
    int t = c0 + c1 + c2 + c3;
    lds[threadIdx.x] = t;
    __syncthreads();
    int x = t;
    for (int off = 1; off < 256; off <<= 1) {
        int y = (threadIdx.x >= off) ? lds[threadIdx.x - off] : 0;
        __syncthreads();
        x += y; lds[threadIdx.x] = x;
        __syncthreads();
    }
    int excl = x - t;
    data[base] = excl; data[base + 1] = excl + c0;
    data[base + 2] = excl + c0 + c1; data[base + 3] = excl + c0 + c1 + c2;
    if (threadIdx.x == 255) bsum[blockIdx.x] = x;
}

__global__ __launch_bounds__(256) void scan_bsum(int* __restrict__ bsum, int n)
{
    __shared__ int lds[256];
    int t = (threadIdx.x < n) ? bsum[threadIdx.x] : 0;
    lds[threadIdx.x] = t;
    __syncthreads();
    int x = t;
    for (int off = 1; off < 256; off <<= 1) {
        int y = (threadIdx.x >= off) ? lds[threadIdx.x - off] : 0;
        __syncthreads();
        x += y; lds[threadIdx.x] = x;
        __syncthreads();
    }
    if (threadIdx.x < n) bsum[threadIdx.x] = x - t;
}

__global__ __launch_bounds__(256) void scan_add(
    int* __restrict__ data, const int* __restrict__ bsum, int n)
{
    int i = blockIdx.x * 256 + threadIdx.x;
    if (i < n) data[i] += bsum[i >> 10];
}

__global__ __launch_bounds__(256) void copy_int(
    int* __restrict__ dst, const int* __restrict__ src, int n)
{
    int i = blockIdx.x * 256 + threadIdx.x;
    if (i < n) dst[i] = src[i];
}

__global__ __launch_bounds__(256) void fill_nb_list(
    const int* __restrict__ ij, const int* __restrict__ ki,
    int* __restrict__ cur, int* __restrict__ lst)
{
    int e = blockIdx.x * 256 + threadIdx.x;
    if (e < NB) { int p = atomicAdd(&cur[ij[e]], 1); lst[p] = ki[e]; }
}

__global__ __launch_bounds__(256) void fill_agg_list(
    const int* __restrict__ jidx, int* __restrict__ cur, int* __restrict__ lst)
{
    int e = blockIdx.x * 256 + threadIdx.x;
    if (e < NE) { int p = atomicAdd(&cur[jidx[e]], 1); lst[p] = e; }
}

// ---------------- CSR segment sum (AGG) ---------------------------------
__global__ __launch_bounds__(256) void seg_s_kernel(
    const bf16* __restrict__ MB, const int* __restrict__ off,
    const int* __restrict__ lst, bf16* __restrict__ S, int nseg)
{
    int sid = blockIdx.x * 4 + (threadIdx.x >> 6);
    if (sid >= nseg) return;
    int lane = threadIdx.x & 63;
    int b = off[sid], e = off[sid + 1];
    float a0 = 0, a1 = 0, a2 = 0, a3 = 0;
    for (int t = b; t < e; t++) {
        int src = lst[t];
        ushort4 u = *(const ushort4*)((const unsigned short*)MB + (size_t)src * DD + lane * 4);
        a0 += bf2f(u.x); a1 += bf2f(u.y); a2 += bf2f(u.z); a3 += bf2f(u.w);
    }
    ushort4 o = {f2bf(a0), f2bf(a1), f2bf(a2), f2bf(a3)};
    *(ushort4*)((unsigned short*)S + (size_t)sid * DD + lane * 4) = o;
}

// -------- fused seg_s + seg_r: one CSR walk, one MB gather pass ---------
// S[sid] = sum MB[src];  R[sid] = sum sigmoid(PR[sid]+TR[src]) * MB[src]
__global__ __launch_bounds__(256) void seg_sr_kernel(
    const bf16* __restrict__ MB, const bf16* __restrict__ TR,
    const bf16* __restrict__ PR, const int* __restrict__ off,
    const int* __restrict__ lst,
    bf16* __restrict__ S, bf16* __restrict__ R)
{
    int sid = blockIdx.x * 4 + (threadIdx.x >> 6);
    if (sid >= NE) return;
    int lane = threadIdx.x & 63;
    ushort4 up = *(const ushort4*)((const unsigned short*)PR + (size_t)sid * DD + lane * 4);
    float p0 = bf2f(up.x), p1 = bf2f(up.y), p2 = bf2f(up.z), p3 = bf2f(up.w);
    int b = off[sid], e = off[sid + 1];
    float s0 = 0, s1 = 0, s2 = 0, s3 = 0;
    float r0 = 0, r1 = 0, r2 = 0, r3 = 0;
    for (int t = b; t < e; t++) {
        int src = lst[t];
        ushort4 um = *(const ushort4*)((const unsigned short*)MB + (size_t)src * DD + lane * 4);
        ushort4 ut = *(const ushort4*)((const unsigned short*)TR + (size_t)src * DD + lane * 4);
        float m0 = bf2f(um.x), m1 = bf2f(um.y), m2 = bf2f(um.z), m3 = bf2f(um.w);
        s0 += m0; s1 += m1; s2 += m2; s3 += m3;
        r0 += sigmoidf(p0 + bf2f(ut.x)) * m0;
        r1 += sigmoidf(p1 + bf2f(ut.y)) * m1;
        r2 += sigmoidf(p2 + bf2f(ut.z)) * m2;
        r3 += sigmoidf(p3 + bf2f(ut.w)) * m3;
    }
    ushort4 os = {f2bf(s0), f2bf(s1), f2bf(s2), f2bf(s3)};
    ushort4 orr = {f2bf(r0), f2bf(r1), f2bf(r2), f2bf(r3)};
    *(ushort4*)((unsigned short*)S + (size_t)sid * DD + lane * 4) = os;
    *(ushort4*)((unsigned short*)R + (size_t)sid * DD + lane * 4) = orr;
}

// ------------- weight pack: dst[n][k] = bf16(seg(k, n)), K-padded -------
__global__ __launch_bounds__(256) void pack_wt(
    const float* W1, int K1, const float* W2, int K2, const float* W3, int K3,
    int KTpad, bf16* dst)
{
    int idx = blockIdx.x * 256 + threadIdx.x;
    if (idx >= 256 * KTpad) return;
    int n = idx / KTpad, k = idx % KTpad;
    float v = 0.f;
    if (k < K1)                { if (W1) v = W1[(size_t)k * DD + n]; }
    else if (k < K1 + K2)      { if (W2) v = W2[(size_t)(k - K1) * DD + n]; }
    else if (k < K1 + K2 + K3) { if (W3) v = W3[(size_t)(k - K1 - K2) * DD + n]; }
    dst[(size_t)n * KTpad + k] = __float2bfloat16(v);
}

// ---------------- unified MFMA GEMM, all-vector staging -----------------
// A = concat of seg1, seg2 (per-segment dtype/stride; kw mult of 32).
// DUAL: 0 none; 1 shared-A two-W; 2 split-A two-W (A1=seg1, A2 via seg2 desc)
// EPB: 0 lin(+b1)->bf16; 1 hsw(+b1)->bf16;
//      2 dual: out1=hsw(acc1+b1), out2=acc2+b2 (bf16);
//      3 dual: out1=acc1+b1, out2=acc2+b2 (bf16);
//      4 blend: z=sig(acc1+PZ), m=tanh(acc2+PM), out1=(1-z)*A1+z*m (bf16);
//      5 hsw(acc1 + PX[idx]) -> bf16  (PX passed as PZb);
//      6 hsw(acc1 + b1) -> f32
template <int BN, int NT, int DUAL, int EPB>
__global__ __launch_bounds__(NT) void bg(
    const void* __restrict__ A1, int a1stride, int a1kw, int a1real, int a1f32,
    const void* __restrict__ A2, int a2stride, int a2kw, int a2real, int a2f32,
    const bf16* __restrict__ WT1, const bf16* __restrict__ WT2, int KT,
    const float* __restrict__ bias1, const float* __restrict__ bias2,
    const bf16* __restrict__ PZb, const bf16* __restrict__ PMb,
    void* __restrict__ out1, void* __restrict__ out2, int M)
{
    constexpr int BM = 128;
    constexpr int nWc = BN / 64;
    constexpr int nWr = (NT / 64) / nWc;
    constexpr int MSPAN = BM / nWr;
    constexpr int MFR = MSPAN / 16;
    __shared__ __align__(16) unsigned short As[BM * 40];
    __shared__ __align__(16) unsigned short As2[(DUAL == 2 ? BM : 8) * 40];
    __shared__ __align__(16) unsigned short Bs[BN * 40];
    __shared__ __align__(16) unsigned short Bs2[(DUAL ? BN : 8) * 40];
    const int tid = threadIdx.x;
    const int row0 = blockIdx.x * BM, col0 = blockIdx.y * BN;
    const int lane = tid & 63, w = tid >> 6;
    const int wr = w / nWc, wc = w % nWc;
    const int fr = lane & 15, ko = (lane >> 4) * 8;

    f32x4 acc[MFR][4] = {};
    f32x4 acc2[DUAL ? MFR : 1][DUAL ? 4 : 1] = {};

    for (int k0 = 0; k0 < KT; k0 += 32) {
        #pragma unroll
        for (int it = 0; it < BM * 4 / NT; ++it) {
            int mloc = (tid >> 2) + it * (NT / 4);
            int mg = row0 + mloc;
            bool mok = (mg < M);
            int kq = (tid & 3) * 8;
            int kg = k0 + kq;
            if (DUAL == 2) {
                uint4 v1 = {0, 0, 0, 0}, v2 = {0, 0, 0, 0};
                if (mok) {
                    v1 = *(const uint4*)((const bf16*)A1 + (size_t)mg * a1stride + kg);
                    v2 = *(const uint4*)((const bf16*)A2 + (size_t)mg * a2stride + kg);
                }
                *(uint4*)&As[mloc * 40 + kq] = v1;
                *(uint4*)&As2[mloc * 40 + kq] = v2;
            } else {
                const void* p; int stride, real, isf; int kk;
                if (kg < a1kw) { p = A1; stride = a1stride; real = a1real; isf = a1f32; kk = kg; }
                else           { p = A2; stride = a2stride; real = a2real; isf = a2f32; kk = kg - a1kw; }
                uint4 v = {0, 0, 0, 0};
                if (mok) {
                    if (!isf) {
                        v = *(const uint4*)((const bf16*)p + (size_t)mg * stride + kk);
                    } else {
                        const float* fp = (const float*)p + (size_t)mg * stride;
                        unsigned short us[8];
                        #pragma unroll
                        for (int j = 0; j < 8; j++)
                            us[j] = (kk + j < real) ? f2bf(fp[kk + j]) : (unsigned short)0;
                        v.x = us[0] | ((unsigned)us[1] << 16);
                        v.y = us[2] | ((unsigned)us[3] << 16);
                        v.z = us[4] | ((unsigned)us[5] << 16);
                        v.w = us[6] | ((unsigned)us[7] << 16);
                    }
                }
                *(uint4*)&As[mloc * 40 + kq] = v;
            }
        }
        #pragma unroll
        for (int it = 0; it < BN * 4 / NT; ++it) {
            int nloc = (tid >> 2) + it * (NT / 4);
            int kq = (tid & 3) * 8;
            *(uint4*)&Bs[nloc * 40 + kq] =
                *(const uint4*)&WT1[(size_t)(col0 + nloc) * KT + k0 + kq];
            if (DUAL)
                *(uint4*)&Bs2[nloc * 40 + kq] =
                    *(const uint4*)&WT2[(size_t)(col0 + nloc) * KT + k0 + kq];
        }
        __syncthreads();
        short8 a1f[MFR], b1f[4];
        short8 a2f[DUAL == 2 ? MFR : 1], b2f[DUAL ? 4 : 1];
        #pragma unroll
        for (int mf = 0; mf < MFR; mf++) {
            a1f[mf] = *(const short8*)&As[(wr * MSPAN + mf * 16 + fr) * 40 + ko];
            if (DUAL == 2)
                a2f[mf] = *(const short8*)&As2[(wr * MSPAN + mf * 16 + fr) * 40 + ko];
        }
        #pragma unroll
        for (int nf = 0; nf < 4; nf++) {
            b1f[nf] = *(const short8*)&Bs[(wc * 64 + nf * 16 + fr) * 40 + ko];
            if (DUAL)
                b2f[nf] = *(const short8*)&Bs2[(wc * 64 + nf * 16 + fr) * 40 + ko];
        }
        #pragma unroll
        for (int mf = 0; mf < MFR; mf++)
            #pragma unroll
            for (int nf = 0; nf < 4; nf++) {
                acc[mf][nf] = __builtin_amdgcn_mfma_f32_16x16x32_bf16(a1f[mf], b1f[nf], acc[mf][nf], 0, 0, 0);
                if (DUAL)
                    acc2[mf][nf] = __builtin_amdgcn_mfma_f32_16x16x32_bf16(
                        DUAL == 2 ? a2f[mf] : a1f[mf], b2f[nf], acc2[mf][nf], 0, 0, 0);
            }
        __syncthreads();
    }

    #pragma unroll
    for (int mf = 0; mf < MFR; mf++) {
        #pragma unroll
        for (int i = 0; i < 4; i++) {
            int mloc = wr * MSPAN + mf * 16 + (lane >> 4) * 4 + i;
            int gm = row0 + mloc;
            if (gm >= M) continue;
            #pragma unroll
            for (int nf = 0; nf < 4; nf++) {
                int gc = col0 + wc * 64 + nf * 16 + fr;
                size_t idx = (size_t)gm * DD + gc;
                float v = acc[mf][nf][i];
                if (EPB == 0) {
                    if (bias1) v += bias1[gc];
                    ((bf16*)out1)[idx] = __float2bfloat16(v);
                } else if (EPB == 1) {
                    ((bf16*)out1)[idx] = __float2bfloat16(hswish(v + bias1[gc]));
                } else if (EPB == 2) {
                    ((bf16*)out1)[idx] = __float2bfloat16(hswish(v + bias1[gc]));
                    ((bf16*)out2)[idx] = __float2bfloat16(acc2[mf][nf][i] + bias2[gc]);
                } else if (EPB == 3) {
                    ((bf16*)out1)[idx] = __float2bfloat16(v + bias1[gc]);
                    ((bf16*)out2)[idx] = __float2bfloat16(acc2[mf][nf][i] + bias2[gc]);
                } else if (EPB == 4) {
                    float z  = sigmoidf(v + __bfloat162float(PZb[idx]));
                    float mm = tanhf(acc2[mf][nf][i] + __bfloat162float(PMb[idx]));
                    float s  = __bfloat162float(((const bf16*)A1)[idx]);
                    ((bf16*)out1)[idx] = __float2bfloat16((1.f - z) * s + z * mm);
                } else if (EPB == 5) {
                    ((bf16*)out1)[idx] =
                        __float2bfloat16(hswish(v + __bfloat162float(PZb[idx])));
                } else {  // EPB == 6
                    ((float*)out1)[idx] = hswish(v + bias1[gc]);
                }
            }
        }
    }
}

extern "C" void kernel_launch(void* const* d_in, const int* in_sizes, int n_in,
                              void* d_out, int out_size, void* d_ws, size_t ws_size,
                              hipStream_t stream)
{
    const float* node  = (const float*)d_in[0];
    const float* bond  = (const float*)d_in[1];
    const int* connect = (const int*)d_in[2];
    const int* bnb     = (const int*)d_in[3];
    const float* w_node       = (const float*)d_in[4];
    const float* b_node       = (const float*)d_in[5];
    const float* w_node_final = (const float*)d_in[6];
    const float* b_node_final = (const float*)d_in[7];
    const float* w_bond       = (const float*)d_in[8];
    const float* b_bond       = (const float*)d_in[9];
    const float* w_bond_final = (const float*)d_in[10];
    const float* b_bond_final = (const float*)d_in[11];
    const float* w_z = (const float*)d_in[12];
    const float* b_z = (const float*)d_in[13];
    const float* w_r = (const float*)d_in[14];
    const float* b_r = (const float*)d_in[15];
    const float* u_  = (const float*)d_in[16];
    const float* w_m = (const float*)d_in[17];
    const float* b_m = (const float*)d_in[18];
    const float* w_n = (const float*)d_in[19];
    const float* b_n = (const float*)d_in[20];
    const float* u_n = (const float*)d_in[21];

    const int* i_idx = connect;
    const int* j_idx = connect + NE;
    const int* ij    = bnb;
    const int* ki    = bnb + NB;

    const size_t EBH = (size_t)NE * DD * 2;        // 102,400,000
    const size_t B_WT = (size_t)3072 * 256 * 2;    // 1.57 MB packed weights
    const int NEpad = 196 * 1024;
    const int NNpad = 98 * 1024;
    const size_t B_CSR = (size_t)NEpad * 8 + (size_t)NB * 4
                       + (size_t)NNpad * 8 + (size_t)NE * 4 + 2048;
    const size_t NEED = 5 * EBH + B_WT + B_CSR;    // ~519.4 MB (known to fit)

    float* out_node = (float*)d_out;
    float* out_bond = out_node + (size_t)NN * DD;

    if (ws_size < NEED) {
        fill_kernel<<<2048, 256, 0, stream>>>((float*)d_out, 1e6f, (long)out_size / 4);
        return;
    }

    char* base = (char*)d_ws;
    bf16* PR = (bf16*)base;                       base += EBH;
    bf16* MB = (bf16*)base;                       base += EBH;
    bf16* TR = (bf16*)base;                       base += EBH;   // also IBbf / AGG / final-node scratch
    bf16* PZ = (bf16*)base;                       base += EBH;
    bf16* PM = (bf16*)base;                       base += EBH;
    char* wt = base;                              base += B_WT;
    int* offE  = (int*)base;                      base += (size_t)NEpad * 4;
    int* curE  = (int*)base;                      base += (size_t)NEpad * 4;
    int* nbLst = (int*)base;                      base += (size_t)NB * 4;
    int* offN  = (int*)base;                      base += (size_t)NNpad * 4;
    int* curN  = (int*)base;                      base += (size_t)NNpad * 4;
    int* agLst = (int*)base;                      base += (size_t)NE * 4;
    int* bsumE = (int*)base;                      base += 1024;
    int* bsumN = (int*)base;

    bf16* IBbf = TR;                 // pre-loop + rebuilt post-loop
    bf16* AGG  = TR;                 // loop-internal (TR dead after seg_sr... kept: AGG uses first half)
    float* scratchN = (float*)TR;    // final node f32 output
    bf16* R = (bf16*)out_bond;       // 102.4 MB
    bf16* S = R + (size_t)NE * DD;   // 102.4 MB
    bf16* MN = (bf16*)out_node;
    bf16* PN = MN + (size_t)NN * DD;

    auto wtAlloc = [&](size_t elems) { bf16* p = (bf16*)wt; wt += elems * 2; return p; };
    bf16* WTr  = wtAlloc(160 * 256);   // w_r[0:147]
    bf16* WTz1 = wtAlloc(160 * 256);   // w_z[0:147]
    bf16* WTb  = wtAlloc(160 * 256);   // w_bond
    bf16* WTm1 = wtAlloc(160 * 256);   // w_m
    bf16* WTn0 = wtAlloc(160 * 256);   // w_node
    bf16* WTn  = wtAlloc(160 * 256);   // w_n
    bf16* WTr2 = wtAlloc(256 * 256);   // w_r[147:403]
    bf16* WTz2 = wtAlloc(256 * 256);   // w_z[147:403]
    bf16* WTu  = wtAlloc(256 * 256);   // u
    bf16* WTnu = wtAlloc(512 * 256);   // u_n
    bf16* WTbf = wtAlloc(416 * 256);   // w_bond_final: 147 | 13 zeros | 256
    bf16* WTnf = wtAlloc(416 * 256);   // w_node_final: 133 | 27 zeros | 256

    const float* w_r2 = w_r + (size_t)FIB * DD;
    const float* w_z2 = w_z + (size_t)FIB * DD;

    auto packG = [&](int ktpad) { return (256 * ktpad + 255) / 256; };
    pack_wt<<<packG(160), 256, 0, stream>>>(w_r, FIB, nullptr, 0, nullptr, 0, 160, WTr);
    pack_wt<<<packG(160), 256, 0, stream>>>(w_z, FIB, nullptr, 0, nullptr, 0, 160, WTz1);
    pack_wt<<<packG(160), 256, 0, stream>>>(w_bond, FIB, nullptr, 0, nullptr, 0, 160, WTb);
    pack_wt<<<packG(160), 256, 0, stream>>>(w_m, FIB, nullptr, 0, nullptr, 0, 160, WTm1);
    pack_wt<<<packG(160), 256, 0, stream>>>(w_node, FN, nullptr, 0, nullptr, 0, 160, WTn0);
    pack_wt<<<packG(160), 256, 0, stream>>>(w_n, FN, nullptr, 0, nullptr, 0, 160, WTn);
    pack_wt<<<packG(256), 256, 0, stream>>>(w_r2, DD, nullptr, 0, nullptr, 0, 256, WTr2);
    pack_wt<<<packG(256), 256, 0, stream>>>(w_z2, DD, nullptr, 0, nullptr, 0, 256, WTz2);
    pack_wt<<<packG(256), 256, 0, stream>>>(u_, DD, nullptr, 0, nullptr, 0, 256, WTu);
    pack_wt<<<packG(512), 256, 0, stream>>>(u_n, 2 * DD, nullptr, 0, nullptr, 0, 512, WTnu);
    pack_wt<<<packG(416), 256, 0, stream>>>(w_bond_final, FIB, nullptr, 13,
                                            w_bond_final + (size_t)FIB * DD, DD, 416, WTbf);
    pack_wt<<<packG(416), 256, 0, stream>>>(w_node_final, FN, nullptr, 27,
                                            w_node_final + (size_t)FN * DD, DD, 416, WTnf);

    // ---- CSR build (layer-invariant) ----
    fill_kernel<<<256, 256, 0, stream>>>((float*)offE, 0.f, NEpad / 4);
    fill_kernel<<<256, 256, 0, stream>>>((float*)offN, 0.f, NNpad / 4);
    count_kernel<<<(NB + 255) / 256, 256, 0, stream>>>(ij, NB, offE);
    count_kernel<<<(NE + 255) / 256, 256, 0, stream>>>(j_idx, NE, offN);
    scan_block<<<196, 256, 0, stream>>>(offE, bsumE);
    scan_bsum<<<1, 256, 0, stream>>>(bsumE, 196);
    scan_add<<<NEpad / 256, 256, 0, stream>>>(offE, bsumE, NEpad);
    scan_block<<<98, 256, 0, stream>>>(offN, bsumN);
    scan_bsum<<<1, 256, 0, stream>>>(bsumN, 98);
    scan_add<<<NNpad / 256, 256, 0, stream>>>(offN, bsumN, NNpad);
    copy_int<<<NEpad / 256, 256, 0, stream>>>(curE, offE, NEpad);
    copy_int<<<NNpad / 256, 256, 0, stream>>>(curN, offN, NNpad);
    fill_nb_list<<<(NB + 255) / 256, 256, 0, stream>>>(ij, ki, curE, nbLst);
    fill_agg_list<<<(NE + 255) / 256, 256, 0, stream>>>(j_idx, curN, agLst);

    dim3 gB2(1563, 2);    // NE rows, BN=128
    dim3 gB1(1563, 1);    // NE rows, BN=256
    dim3 gN2(782, 2);     // NN rows, BN=128
    dim3 gN1(782, 1);     // NN rows, BN=256
    int blkIB = NE * 64 / 256;

    // ---- pre-loop: build IB once, hoist all layer-invariant GEMMs ----
    build_ib_bf<<<blkIB, 256, 0, stream>>>(node, bond, i_idx, IBbf);
    bg<128, 512, 1, 3><<<gB2, 512, 0, stream>>>(        // PR, PZ
        IBbf, 160, 160, 160, 0, nullptr, 0, 0, 0, 0,
        WTr, WTz1, 160, b_r, b_z, nullptr, nullptr, PR, PZ, NE);
    bg<128, 512, 1, 2><<<gB2, 512, 0, stream>>>(        // MB, PM
        IBbf, 160, 160, 160, 0, nullptr, 0, 0, 0, 0,
        WTb, WTm1, 160, b_bond, b_m, nullptr, nullptr, MB, PM, NE);
    bg<128, 512, 1, 2><<<gN2, 512, 0, stream>>>(        // MN, PN
        node, FN, 160, FN, 1, nullptr, 0, 0, 0, 0,
        WTn0, WTn, 160, b_node, b_n, nullptr, nullptr, MN, PN, NN);

    for (int l = 0; l < 3; l++) {
        bg<256, 512, 0, 0><<<gB1, 512, 0, stream>>>(    // TR = MB @ w_r2
            MB, 256, 256, 256, 0, nullptr, 0, 0, 0, 0,
            WTr2, nullptr, 256, nullptr, nullptr, nullptr, nullptr, TR, nullptr, NE);
        seg_sr_kernel<<<(NE + 3) / 4, 256, 0, stream>>>(MB, TR, PR, offE, nbLst, S, R);
        bg<256, 512, 2, 4><<<gB1, 512, 0, stream>>>(    // blend -> MB (in place)
            S, 256, 256, 256, 0, R, 256, 256, 256, 0,
            WTz2, WTu, 256, nullptr, nullptr, PZ, PM, MB, nullptr, NE);
        seg_s_kernel<<<(NN + 3) / 4, 256, 0, stream>>>(MB, offN, agLst, AGG, NN);
        bg<256, 512, 0, 5><<<gN1, 512, 0, stream>>>(    // MN = hsw([MN|AGG]@u_n + PN)
            MN, 256, 256, 256, 0, AGG, 256, 256, 256, 0,
            WTnu, nullptr, 512, nullptr, nullptr, PN, nullptr, MN, nullptr, NN);
    }

    // ---- finals ----
    build_ib_bf<<<blkIB, 256, 0, stream>>>(node, bond, i_idx, IBbf);  // TR slot free
    bg<256, 512, 0, 6><<<gB1, 512, 0, stream>>>(        // bond final -> f32 out_bond
        IBbf, 160, 160, 160, 0, MB, 256, 256, 256, 0,
        WTbf, nullptr, 416, b_bond_final, nullptr, nullptr, nullptr, out_bond, nullptr, NE);
    bg<256, 512, 0, 6><<<gN1, 512, 0, stream>>>(        // node final -> f32 scratch
        node, FN, 160, FN, 1, MN, 256, 256, 256, 0,
        WTnf, nullptr, 416, b_node_final, nullptr, nullptr, nullptr, scratchN, nullptr, NN);
    hipMemcpyAsync(out_node, scratchN, (size_t)NN * DD * 4,
                   hipMemcpyDeviceToDevice, stream);
}

// Round 10
// 2802.785 us; speedup vs baseline: 1.2460x; 1.0899x over previous
//
#include <hip/hip_runtime.h>
#include <hip/hip_bf16.h>

#define NN 100000   // nodes
#define NE 200000   // bonds
#define NB 600000   // bond neighbours
#define FN 133
#define FB 14
#define FIB 147     // FN+FB
#define DD 256

typedef __hip_bfloat16 bf16;
typedef __attribute__((ext_vector_type(8))) short short8;   // 8 bf16 = 4 VGPR
typedef __attribute__((ext_vector_type(4))) float f32x4;

__device__ __forceinline__ float hswish(float x) {
    float c = fminf(fmaxf(x + 3.f, 0.f), 6.f);
    return x * c * (1.f / 6.f);
}
__device__ __forceinline__ float sigmoidf(float x) {
    return 1.f / (1.f + __expf(-x));
}
__device__ __forceinline__ float bf2f(unsigned short u) {
    union { unsigned int i; float f; } c; c.i = (unsigned int)u << 16; return c.f;
}
__device__ __forceinline__ unsigned short f2bf(float v) {
    bf16 b = __float2bfloat16(v);
    unsigned short u; __builtin_memcpy(&u, &b, 2); return u;
}

// ---------------- fill (zero counts + ws-guard sentinel) ----------------
__global__ __launch_bounds__(256) void fill_kernel(float* __restrict__ p, float v, long n4) {
    long i = (long)blockIdx.x * 256 + threadIdx.x;
    long st = (long)gridDim.x * 256;
    float4 z = {v, v, v, v};
    for (; i < n4; i += st) ((float4*)p)[i] = z;
}

// ---------------- IB build: IBbf[e][160] = [node[i_idx[e]] | bond[e] | 0]
__global__ __launch_bounds__(256) void build_ib_bf(
    const float* __restrict__ node, const float* __restrict__ bond,
    const int* __restrict__ i_idx, bf16* __restrict__ IB)
{
    int t = blockIdx.x * 256 + threadIdx.x;
    int row = t >> 6;
    if (row >= NE) return;
    int lane = t & 63;
    if (lane >= 40) return;
    int src = i_idx[row];
    int c = lane * 4;
    unsigned short us[4];
    #pragma unroll
    for (int j = 0; j < 4; j++) {
        int k = c + j;
        float v = 0.f;
        if (k < FN)       v = node[(size_t)src * FN + k];
        else if (k < FIB) v = bond[(size_t)row * FB + (k - FN)];
        us[j] = f2bf(v);
    }
    ushort4 o = {us[0], us[1], us[2], us[3]};
    *(ushort4*)((unsigned short*)IB + (size_t)row * 160 + c) = o;
}

// ---------------- CSR build helpers -------------------------------------
__global__ __launch_bounds__(256) void count_kernel(
    const int* __restrict__ idx, int n, int* __restrict__ cnt)
{
    int i = blockIdx.x * 256 + threadIdx.x;
    if (i < n) atomicAdd(&cnt[idx[i]], 1);
}

__global__ __launch_bounds__(256) void scan_block(int* __restrict__ data, int* __restrict__ bsum)
{
    __shared__ int lds[256];
    int base = blockIdx.x * 1024 + threadIdx.x * 4;
    int c0 = data[base], c1 = data[base + 1], c2 = data[base + 2], c3 = data[base + 3];
    int t = c0 + c1 + c2 + c3;
    lds[threadIdx.x] = t;
    __syncthreads();
    int x = t;
    for (int off = 1; off < 256; off <<= 1) {
        int y = (threadIdx.x >= off) ? lds[threadIdx.x - off] : 0;
        __syncthreads();
        x += y; lds[threadIdx.x] = x;
        __syncthreads();
    }
    int excl = x - t;
    data[base] = excl; data[base + 1] = excl + c0;
    data[base + 2] = excl + c0 + c1; data[base + 3] = excl + c0 + c1 + c2;
    if (threadIdx.x == 255) bsum[blockIdx.x] = x;
}

__global__ __launch_bounds__(256) void scan_bsum(int* __restrict__ bsum, int n)
{
    __shared__ int lds[256];
    int t = (threadIdx.x < n) ? bsum[threadIdx.x] : 0;
    lds[threadIdx.x] = t;
    __syncthreads();
    int x = t;
    for (int off = 1; off < 256; off <<= 1) {
        int y = (threadIdx.x >= off) ? lds[threadIdx.x - off] : 0;
        __syncthreads();
        x += y; lds[threadIdx.x] = x;
        __syncthreads();
    }
    if (threadIdx.x < n) bsum[threadIdx.x] = x - t;
}

__global__ __launch_bounds__(256) void scan_add(
    int* __restrict__ data, const int* __restrict__ bsum, int n)
{
    int i = blockIdx.x * 256 + threadIdx.x;
    if (i < n) data[i] += bsum[i >> 10];
}

__global__ __launch_bounds__(256) void copy_int(
    int* __restrict__ dst, const int* __restrict__ src, int n)
{
    int i = blockIdx.x * 256 + threadIdx.x;
    if (i < n) dst[i] = src[i];
}

__global__ __launch_bounds__(256) void fill_nb_list(
    const int* __restrict__ ij, const int* __restrict__ ki,
    int* __restrict__ cur, int* __restrict__ lst)
{
    int e = blockIdx.x * 256 + threadIdx.x;
    if (e < NB) { int p = atomicAdd(&cur[ij[e]], 1); lst[p] = ki[e]; }
}

__global__ __launch_bounds__(256) void fill_agg_list(
    const int* __restrict__ jidx, int* __restrict__ cur, int* __restrict__ lst)
{
    int e = blockIdx.x * 256 + threadIdx.x;
    if (e < NE) { int p = atomicAdd(&cur[jidx[e]], 1); lst[p] = e; }
}

// ---------------- CSR segment sum (AGG) ---------------------------------
__global__ __launch_bounds__(256) void seg_s_kernel(
    const bf16* __restrict__ MB, const int* __restrict__ off,
    const int* __restrict__ lst, bf16* __restrict__ S, int nseg)
{
    int sid = blockIdx.x * 4 + (threadIdx.x >> 6);
    if (sid >= nseg) return;
    int lane = threadIdx.x & 63;
    int b = off[sid], e = off[sid + 1];
    float a0 = 0, a1 = 0, a2 = 0, a3 = 0;
    for (int t = b; t < e; t++) {
        int src = lst[t];
        ushort4 u = *(const ushort4*)((const unsigned short*)MB + (size_t)src * DD + lane * 4);
        a0 += bf2f(u.x); a1 += bf2f(u.y); a2 += bf2f(u.z); a3 += bf2f(u.w);
    }
    ushort4 o = {f2bf(a0), f2bf(a1), f2bf(a2), f2bf(a3)};
    *(ushort4*)((unsigned short*)S + (size_t)sid * DD + lane * 4) = o;
}

// -------- fused seg_s + seg_r: one CSR walk, one MB gather pass ---------
__global__ __launch_bounds__(256) void seg_sr_kernel(
    const bf16* __restrict__ MB, const bf16* __restrict__ TR,
    const bf16* __restrict__ PR, const int* __restrict__ off,
    const int* __restrict__ lst,
    bf16* __restrict__ S, bf16* __restrict__ R)
{
    int sid = blockIdx.x * 4 + (threadIdx.x >> 6);
    if (sid >= NE) return;
    int lane = threadIdx.x & 63;
    ushort4 up = *(const ushort4*)((const unsigned short*)PR + (size_t)sid * DD + lane * 4);
    float p0 = bf2f(up.x), p1 = bf2f(up.y), p2 = bf2f(up.z), p3 = bf2f(up.w);
    int b = off[sid], e = off[sid + 1];
    float s0 = 0, s1 = 0, s2 = 0, s3 = 0;
    float r0 = 0, r1 = 0, r2 = 0, r3 = 0;
    for (int t = b; t < e; t++) {
        int src = lst[t];
        ushort4 um = *(const ushort4*)((const unsigned short*)MB + (size_t)src * DD + lane * 4);
        ushort4 ut = *(const ushort4*)((const unsigned short*)TR + (size_t)src * DD + lane * 4);
        float m0 = bf2f(um.x), m1 = bf2f(um.y), m2 = bf2f(um.z), m3 = bf2f(um.w);
        s0 += m0; s1 += m1; s2 += m2; s3 += m3;
        r0 += sigmoidf(p0 + bf2f(ut.x)) * m0;
        r1 += sigmoidf(p1 + bf2f(ut.y)) * m1;
        r2 += sigmoidf(p2 + bf2f(ut.z)) * m2;
        r3 += sigmoidf(p3 + bf2f(ut.w)) * m3;
    }
    ushort4 os = {f2bf(s0), f2bf(s1), f2bf(s2), f2bf(s3)};
    ushort4 orr = {f2bf(r0), f2bf(r1), f2bf(r2), f2bf(r3)};
    *(ushort4*)((unsigned short*)S + (size_t)sid * DD + lane * 4) = os;
    *(ushort4*)((unsigned short*)R + (size_t)sid * DD + lane * 4) = orr;
}

// ------------- weight pack: dst[n][k] = bf16(seg(k, n)), K-padded -------
__global__ __launch_bounds__(256) void pack_wt(
    const float* W1, int K1, const float* W2, int K2, const float* W3, int K3,
    int KTpad, bf16* dst)
{
    int idx = blockIdx.x * 256 + threadIdx.x;
    if (idx >= 256 * KTpad) return;
    int n = idx / KTpad, k = idx % KTpad;
    float v = 0.f;
    if (k < K1)                { if (W1) v = W1[(size_t)k * DD + n]; }
    else if (k < K1 + K2)      { if (W2) v = W2[(size_t)(k - K1) * DD + n]; }
    else if (k < K1 + K2 + K3) { if (W3) v = W3[(size_t)(k - K1 - K2) * DD + n]; }
    dst[(size_t)n * KTpad + k] = __float2bfloat16(v);
}

// ======== blend2: two sequential K=256 GEMM phases, small LDS ===========
// acc1 = S @ WTz2 ; acc2 = R @ WTu (phases share one A/B LDS buffer)
// MB[idx] = (1-z)*S + z*tanh(acc2+PM), z = sigmoid(acc1+PZ)
__global__ __launch_bounds__(512) void blend2(
    const bf16* __restrict__ S, const bf16* __restrict__ R,
    const bf16* __restrict__ WTz2, const bf16* __restrict__ WTu,
    const bf16* __restrict__ PZ, const bf16* __restrict__ PM,
    bf16* __restrict__ MB)
{
    // BM=128, BN=128, NT=512: nWc=2, nWr=4, MSPAN=32, MFR=2
    __shared__ __align__(16) unsigned short As[128 * 40];   // 10 KB
    __shared__ __align__(16) unsigned short Bs[128 * 40];   // 10 KB
    const int tid = threadIdx.x;
    const int row0 = blockIdx.x * 128, col0 = blockIdx.y * 128;
    const int lane = tid & 63, w = tid >> 6;
    const int wr = w >> 1, wc = w & 1;
    const int fr = lane & 15, ko = (lane >> 4) * 8;

    f32x4 acc1[2][4] = {};
    f32x4 acc2[2][4] = {};

    #pragma unroll
    for (int ph = 0; ph < 2; ph++) {
        const bf16* A = (ph == 0) ? S : R;
        const bf16* W = (ph == 0) ? WTz2 : WTu;
        for (int k0 = 0; k0 < DD; k0 += 32) {
            {
                int mloc = tid >> 2, kq = (tid & 3) * 8;
                int mg = row0 + mloc;
                uint4 v = {0, 0, 0, 0};
                if (mg < NE)
                    v = *(const uint4*)((const unsigned short*)A + (size_t)mg * DD + k0 + kq);
                *(uint4*)&As[mloc * 40 + kq] = v;
                *(uint4*)&Bs[mloc * 40 + kq] =
                    *(const uint4*)((const unsigned short*)W + (size_t)(col0 + mloc) * DD + k0 + kq);
            }
            __syncthreads();
            short8 af[2], bf8[4];
            #pragma unroll
            for (int mf = 0; mf < 2; mf++)
                af[mf] = *(const short8*)&As[(wr * 32 + mf * 16 + fr) * 40 + ko];
            #pragma unroll
            for (int nf = 0; nf < 4; nf++)
                bf8[nf] = *(const short8*)&Bs[(wc * 64 + nf * 16 + fr) * 40 + ko];
            #pragma unroll
            for (int mf = 0; mf < 2; mf++)
                #pragma unroll
                for (int nf = 0; nf < 4; nf++) {
                    if (ph == 0)
                        acc1[mf][nf] = __builtin_amdgcn_mfma_f32_16x16x32_bf16(af[mf], bf8[nf], acc1[mf][nf], 0, 0, 0);
                    else
                        acc2[mf][nf] = __builtin_amdgcn_mfma_f32_16x16x32_bf16(af[mf], bf8[nf], acc2[mf][nf], 0, 0, 0);
                }
            __syncthreads();
        }
    }

    #pragma unroll
    for (int mf = 0; mf < 2; mf++) {
        #pragma unroll
        for (int i = 0; i < 4; i++) {
            int mloc = wr * 32 + mf * 16 + (lane >> 4) * 4 + i;
            int gm = row0 + mloc;
            if (gm >= NE) continue;
            #pragma unroll
            for (int nf = 0; nf < 4; nf++) {
                int gc = col0 + wc * 64 + nf * 16 + fr;
                size_t idx = (size_t)gm * DD + gc;
                float z  = sigmoidf(acc1[mf][nf][i] + __bfloat162float(PZ[idx]));
                float mm = tanhf(acc2[mf][nf][i] + __bfloat162float(PM[idx]));
                float s  = __bfloat162float(S[idx]);
                MB[idx] = __float2bfloat16((1.f - z) * s + z * mm);
            }
        }
    }
}

// ---------------- unified MFMA GEMM, all-vector staging -----------------
// (unchanged from round 9)
template <int BN, int NT, int DUAL, int EPB>
__global__ __launch_bounds__(NT) void bg(
    const void* __restrict__ A1, int a1stride, int a1kw, int a1real, int a1f32,
    const void* __restrict__ A2, int a2stride, int a2kw, int a2real, int a2f32,
    const bf16* __restrict__ WT1, const bf16* __restrict__ WT2, int KT,
    const float* __restrict__ bias1, const float* __restrict__ bias2,
    const bf16* __restrict__ PZb, const bf16* __restrict__ PMb,
    void* __restrict__ out1, void* __restrict__ out2, int M)
{
    constexpr int BM = 128;
    constexpr int nWc = BN / 64;
    constexpr int nWr = (NT / 64) / nWc;
    constexpr int MSPAN = BM / nWr;
    constexpr int MFR = MSPAN / 16;
    __shared__ __align__(16) unsigned short As[BM * 40];
    __shared__ __align__(16) unsigned short As2[(DUAL == 2 ? BM : 8) * 40];
    __shared__ __align__(16) unsigned short Bs[BN * 40];
    __shared__ __align__(16) unsigned short Bs2[(DUAL ? BN : 8) * 40];
    const int tid = threadIdx.x;
    const int row0 = blockIdx.x * BM, col0 = blockIdx.y * BN;
    const int lane = tid & 63, w = tid >> 6;
    const int wr = w / nWc, wc = w % nWc;
    const int fr = lane & 15, ko = (lane >> 4) * 8;

    f32x4 acc[MFR][4] = {};
    f32x4 acc2[DUAL ? MFR : 1][DUAL ? 4 : 1] = {};

    for (int k0 = 0; k0 < KT; k0 += 32) {
        #pragma unroll
        for (int it = 0; it < BM * 4 / NT; ++it) {
            int mloc = (tid >> 2) + it * (NT / 4);
            int mg = row0 + mloc;
            bool mok = (mg < M);
            int kq = (tid & 3) * 8;
            int kg = k0 + kq;
            if (DUAL == 2) {
                uint4 v1 = {0, 0, 0, 0}, v2 = {0, 0, 0, 0};
                if (mok) {
                    v1 = *(const uint4*)((const bf16*)A1 + (size_t)mg * a1stride + kg);
                    v2 = *(const uint4*)((const bf16*)A2 + (size_t)mg * a2stride + kg);
                }
                *(uint4*)&As[mloc * 40 + kq] = v1;
                *(uint4*)&As2[mloc * 40 + kq] = v2;
            } else {
                const void* p; int stride, real, isf; int kk;
                if (kg < a1kw) { p = A1; stride = a1stride; real = a1real; isf = a1f32; kk = kg; }
                else           { p = A2; stride = a2stride; real = a2real; isf = a2f32; kk = kg - a1kw; }
                uint4 v = {0, 0, 0, 0};
                if (mok) {
                    if (!isf) {
                        v = *(const uint4*)((const bf16*)p + (size_t)mg * stride + kk);
                    } else {
                        const float* fp = (const float*)p + (size_t)mg * stride;
                        unsigned short us[8];
                        #pragma unroll
                        for (int j = 0; j < 8; j++)
                            us[j] = (kk + j < real) ? f2bf(fp[kk + j]) : (unsigned short)0;
                        v.x = us[0] | ((unsigned)us[1] << 16);
                        v.y = us[2] | ((unsigned)us[3] << 16);
                        v.z = us[4] | ((unsigned)us[5] << 16);
                        v.w = us[6] | ((unsigned)us[7] << 16);
                    }
                }
                *(uint4*)&As[mloc * 40 + kq] = v;
            }
        }
        #pragma unroll
        for (int it = 0; it < BN * 4 / NT; ++it) {
            int nloc = (tid >> 2) + it * (NT / 4);
            int kq = (tid & 3) * 8;
            *(uint4*)&Bs[nloc * 40 + kq] =
                *(const uint4*)&WT1[(size_t)(col0 + nloc) * KT + k0 + kq];
            if (DUAL)
                *(uint4*)&Bs2[nloc * 40 + kq] =
                    *(const uint4*)&WT2[(size_t)(col0 + nloc) * KT + k0 + kq];
        }
        __syncthreads();
        short8 a1f[MFR], b1f[4];
        short8 a2f[DUAL == 2 ? MFR : 1], b2f[DUAL ? 4 : 1];
        #pragma unroll
        for (int mf = 0; mf < MFR; mf++) {
            a1f[mf] = *(const short8*)&As[(wr * MSPAN + mf * 16 + fr) * 40 + ko];
            if (DUAL == 2)
                a2f[mf] = *(const short8*)&As2[(wr * MSPAN + mf * 16 + fr) * 40 + ko];
        }
        #pragma unroll
        for (int nf = 0; nf < 4; nf++) {
            b1f[nf] = *(const short8*)&Bs[(wc * 64 + nf * 16 + fr) * 40 + ko];
            if (DUAL)
                b2f[nf] = *(const short8*)&Bs2[(wc * 64 + nf * 16 + fr) * 40 + ko];
        }
        #pragma unroll
        for (int mf = 0; mf < MFR; mf++)
            #pragma unroll
            for (int nf = 0; nf < 4; nf++) {
                acc[mf][nf] = __builtin_amdgcn_mfma_f32_16x16x32_bf16(a1f[mf], b1f[nf], acc[mf][nf], 0, 0, 0);
                if (DUAL)
                    acc2[mf][nf] = __builtin_amdgcn_mfma_f32_16x16x32_bf16(
                        DUAL == 2 ? a2f[mf] : a1f[mf], b2f[nf], acc2[mf][nf], 0, 0, 0);
            }
        __syncthreads();
    }

    #pragma unroll
    for (int mf = 0; mf < MFR; mf++) {
        #pragma unroll
        for (int i = 0; i < 4; i++) {
            int mloc = wr * MSPAN + mf * 16 + (lane >> 4) * 4 + i;
            int gm = row0 + mloc;
            if (gm >= M) continue;
            #pragma unroll
            for (int nf = 0; nf < 4; nf++) {
                int gc = col0 + wc * 64 + nf * 16 + fr;
                size_t idx = (size_t)gm * DD + gc;
                float v = acc[mf][nf][i];
                if (EPB == 0) {
                    if (bias1) v += bias1[gc];
                    ((bf16*)out1)[idx] = __float2bfloat16(v);
                } else if (EPB == 1) {
                    ((bf16*)out1)[idx] = __float2bfloat16(hswish(v + bias1[gc]));
                } else if (EPB == 2) {
                    ((bf16*)out1)[idx] = __float2bfloat16(hswish(v + bias1[gc]));
                    ((bf16*)out2)[idx] = __float2bfloat16(acc2[mf][nf][i] + bias2[gc]);
                } else if (EPB == 3) {
                    ((bf16*)out1)[idx] = __float2bfloat16(v + bias1[gc]);
                    ((bf16*)out2)[idx] = __float2bfloat16(acc2[mf][nf][i] + bias2[gc]);
                } else if (EPB == 4) {
                    float z  = sigmoidf(v + __bfloat162float(PZb[idx]));
                    float mm = tanhf(acc2[mf][nf][i] + __bfloat162float(PMb[idx]));
                    float s  = __bfloat162float(((const bf16*)A1)[idx]);
                    ((bf16*)out1)[idx] = __float2bfloat16((1.f - z) * s + z * mm);
                } else if (EPB == 5) {
                    ((bf16*)out1)[idx] =
                        __float2bfloat16(hswish(v + __bfloat162float(PZb[idx])));
                } else {  // EPB == 6
                    ((float*)out1)[idx] = hswish(v + bias1[gc]);
                }
            }
        }
    }
}

extern "C" void kernel_launch(void* const* d_in, const int* in_sizes, int n_in,
                              void* d_out, int out_size, void* d_ws, size_t ws_size,
                              hipStream_t stream)
{
    const float* node  = (const float*)d_in[0];
    const float* bond  = (const float*)d_in[1];
    const int* connect = (const int*)d_in[2];
    const int* bnb     = (const int*)d_in[3];
    const float* w_node       = (const float*)d_in[4];
    const float* b_node       = (const float*)d_in[5];
    const float* w_node_final = (const float*)d_in[6];
    const float* b_node_final = (const float*)d_in[7];
    const float* w_bond       = (const float*)d_in[8];
    const float* b_bond       = (const float*)d_in[9];
    const float* w_bond_final = (const float*)d_in[10];
    const float* b_bond_final = (const float*)d_in[11];
    const float* w_z = (const float*)d_in[12];
    const float* b_z = (const float*)d_in[13];
    const float* w_r = (const float*)d_in[14];
    const float* b_r = (const float*)d_in[15];
    const float* u_  = (const float*)d_in[16];
    const float* w_m = (const float*)d_in[17];
    const float* b_m = (const float*)d_in[18];
    const float* w_n = (const float*)d_in[19];
    const float* b_n = (const float*)d_in[20];
    const float* u_n = (const float*)d_in[21];

    const int* i_idx = connect;
    const int* j_idx = connect + NE;
    const int* ij    = bnb;
    const int* ki    = bnb + NB;

    const size_t EBH = (size_t)NE * DD * 2;        // 102,400,000
    const size_t B_WT = (size_t)3072 * 256 * 2;    // 1.57 MB packed weights
    const int NEpad = 196 * 1024;
    const int NNpad = 98 * 1024;
    const size_t B_CSR = (size_t)NEpad * 8 + (size_t)NB * 4
                       + (size_t)NNpad * 8 + (size_t)NE * 4 + 2048;
    const size_t NEED = 5 * EBH + B_WT + B_CSR;    // ~519.4 MB (known to fit)

    float* out_node = (float*)d_out;
    float* out_bond = out_node + (size_t)NN * DD;

    if (ws_size < NEED) {
        fill_kernel<<<2048, 256, 0, stream>>>((float*)d_out, 1e6f, (long)out_size / 4);
        return;
    }

    char* base = (char*)d_ws;
    bf16* PR = (bf16*)base;                       base += EBH;
    bf16* MB = (bf16*)base;                       base += EBH;
    bf16* TR = (bf16*)base;                       base += EBH;   // also IBbf / AGG / final-node scratch
    bf16* PZ = (bf16*)base;                       base += EBH;
    bf16* PM = (bf16*)base;                       base += EBH;
    char* wt = base;                              base += B_WT;
    int* offE  = (int*)base;                      base += (size_t)NEpad * 4;
    int* curE  = (int*)base;                      base += (size_t)NEpad * 4;
    int* nbLst = (int*)base;                      base += (size_t)NB * 4;
    int* offN  = (int*)base;                      base += (size_t)NNpad * 4;
    int* curN  = (int*)base;                      base += (size_t)NNpad * 4;
    int* agLst = (int*)base;                      base += (size_t)NE * 4;
    int* bsumE = (int*)base;                      base += 1024;
    int* bsumN = (int*)base;

    bf16* IBbf = TR;
    bf16* AGG  = TR;
    float* scratchN = (float*)TR;
    bf16* R = (bf16*)out_bond;
    bf16* S = R + (size_t)NE * DD;
    bf16* MN = (bf16*)out_node;
    bf16* PN = MN + (size_t)NN * DD;

    auto wtAlloc = [&](size_t elems) { bf16* p = (bf16*)wt; wt += elems * 2; return p; };
    bf16* WTr  = wtAlloc(160 * 256);   // w_r[0:147]
    bf16* WTz1 = wtAlloc(160 * 256);   // w_z[0:147]
    bf16* WTb  = wtAlloc(160 * 256);   // w_bond
    bf16* WTm1 = wtAlloc(160 * 256);   // w_m
    bf16* WTn0 = wtAlloc(160 * 256);   // w_node
    bf16* WTn  = wtAlloc(160 * 256);   // w_n
    bf16* WTr2 = wtAlloc(256 * 256);   // w_r[147:403]
    bf16* WTz2 = wtAlloc(256 * 256);   // w_z[147:403]
    bf16* WTu  = wtAlloc(256 * 256);   // u
    bf16* WTnu = wtAlloc(512 * 256);   // u_n
    bf16* WTbf = wtAlloc(416 * 256);   // w_bond_final
    bf16* WTnf = wtAlloc(416 * 256);   // w_node_final

    const float* w_r2 = w_r + (size_t)FIB * DD;
    const float* w_z2 = w_z + (size_t)FIB * DD;

    auto packG = [&](int ktpad) { return (256 * ktpad + 255) / 256; };
    pack_wt<<<packG(160), 256, 0, stream>>>(w_r, FIB, nullptr, 0, nullptr, 0, 160, WTr);
    pack_wt<<<packG(160), 256, 0, stream>>>(w_z, FIB, nullptr, 0, nullptr, 0, 160, WTz1);
    pack_wt<<<packG(160), 256, 0, stream>>>(w_bond, FIB, nullptr, 0, nullptr, 0, 160, WTb);
    pack_wt<<<packG(160), 256, 0, stream>>>(w_m, FIB, nullptr, 0, nullptr, 0, 160, WTm1);
    pack_wt<<<packG(160), 256, 0, stream>>>(w_node, FN, nullptr, 0, nullptr, 0, 160, WTn0);
    pack_wt<<<packG(160), 256, 0, stream>>>(w_n, FN, nullptr, 0, nullptr, 0, 160, WTn);
    pack_wt<<<packG(256), 256, 0, stream>>>(w_r2, DD, nullptr, 0, nullptr, 0, 256, WTr2);
    pack_wt<<<packG(256), 256, 0, stream>>>(w_z2, DD, nullptr, 0, nullptr, 0, 256, WTz2);
    pack_wt<<<packG(256), 256, 0, stream>>>(u_, DD, nullptr, 0, nullptr, 0, 256, WTu);
    pack_wt<<<packG(512), 256, 0, stream>>>(u_n, 2 * DD, nullptr, 0, nullptr, 0, 512, WTnu);
    pack_wt<<<packG(416), 256, 0, stream>>>(w_bond_final, FIB, nullptr, 13,
                                            w_bond_final + (size_t)FIB * DD, DD, 416, WTbf);
    pack_wt<<<packG(416), 256, 0, stream>>>(w_node_final, FN, nullptr, 27,
                                            w_node_final + (size_t)FN * DD, DD, 416, WTnf);

    // ---- CSR build (layer-invariant) ----
    fill_kernel<<<256, 256, 0, stream>>>((float*)offE, 0.f, NEpad / 4);
    fill_kernel<<<256, 256, 0, stream>>>((float*)offN, 0.f, NNpad / 4);
    count_kernel<<<(NB + 255) / 256, 256, 0, stream>>>(ij, NB, offE);
    count_kernel<<<(NE + 255) / 256, 256, 0, stream>>>(j_idx, NE, offN);
    scan_block<<<196, 256, 0, stream>>>(offE, bsumE);
    scan_bsum<<<1, 256, 0, stream>>>(bsumE, 196);
    scan_add<<<NEpad / 256, 256, 0, stream>>>(offE, bsumE, NEpad);
    scan_block<<<98, 256, 0, stream>>>(offN, bsumN);
    scan_bsum<<<1, 256, 0, stream>>>(bsumN, 98);
    scan_add<<<NNpad / 256, 256, 0, stream>>>(offN, bsumN, NNpad);
    copy_int<<<NEpad / 256, 256, 0, stream>>>(curE, offE, NEpad);
    copy_int<<<NNpad / 256, 256, 0, stream>>>(curN, offN, NNpad);
    fill_nb_list<<<(NB + 255) / 256, 256, 0, stream>>>(ij, ki, curE, nbLst);
    fill_agg_list<<<(NE + 255) / 256, 256, 0, stream>>>(j_idx, curN, agLst);

    dim3 gB2(1563, 2);    // NE rows, BN=128
    dim3 gB1(1563, 1);    // NE rows, BN=256
    dim3 gN2(782, 2);     // NN rows, BN=128
    dim3 gN1(782, 1);     // NN rows, BN=256
    int blkIB = NE * 64 / 256;

    // ---- pre-loop: build IB once, hoist all layer-invariant GEMMs ----
    build_ib_bf<<<blkIB, 256, 0, stream>>>(node, bond, i_idx, IBbf);
    bg<128, 512, 1, 3><<<gB2, 512, 0, stream>>>(        // PR, PZ
        IBbf, 160, 160, 160, 0, nullptr, 0, 0, 0, 0,
        WTr, WTz1, 160, b_r, b_z, nullptr, nullptr, PR, PZ, NE);
    bg<128, 512, 1, 2><<<gB2, 512, 0, stream>>>(        // MB, PM
        IBbf, 160, 160, 160, 0, nullptr, 0, 0, 0, 0,
        WTb, WTm1, 160, b_bond, b_m, nullptr, nullptr, MB, PM, NE);
    bg<128, 512, 1, 2><<<gN2, 512, 0, stream>>>(        // MN, PN
        node, FN, 160, FN, 1, nullptr, 0, 0, 0, 0,
        WTn0, WTn, 160, b_node, b_n, nullptr, nullptr, MN, PN, NN);

    for (int l = 0; l < 3; l++) {
        bg<128, 256, 0, 0><<<gB2, 256, 0, stream>>>(    // TR = MB @ w_r2 (round-7 shape)
            MB, 256, 256, 256, 0, nullptr, 0, 0, 0, 0,
            WTr2, nullptr, 256, nullptr, nullptr, nullptr, nullptr, TR, nullptr, NE);
        seg_sr_kernel<<<(NE + 3) / 4, 256, 0, stream>>>(MB, TR, PR, offE, nbLst, S, R);
        blend2<<<gB2, 512, 0, stream>>>(S, R, WTz2, WTu, PZ, PM, MB);
        seg_s_kernel<<<(NN + 3) / 4, 256, 0, stream>>>(MB, offN, agLst, AGG, NN);
        bg<256, 512, 0, 5><<<gN1, 512, 0, stream>>>(    // MN = hsw([MN|AGG]@u_n + PN)
            MN, 256, 256, 256, 0, AGG, 256, 256, 256, 0,
            WTnu, nullptr, 512, nullptr, nullptr, PN, nullptr, MN, nullptr, NN);
    }

    // ---- finals ----
    build_ib_bf<<<blkIB, 256, 0, stream>>>(node, bond, i_idx, IBbf);
    bg<256, 512, 0, 6><<<gB1, 512, 0, stream>>>(        // bond final -> f32 out_bond
        IBbf, 160, 160, 160, 0, MB, 256, 256, 256, 0,
        WTbf, nullptr, 416, b_bond_final, nullptr, nullptr, nullptr, out_bond, nullptr, NE);
    bg<256, 512, 0, 6><<<gN1, 512, 0, stream>>>(        // node final -> f32 scratch
        node, FN, 160, FN, 1, MN, 256, 256, 256, 0,
        WTnf, nullptr, 416, b_node_final, nullptr, nullptr, nullptr, scratchN, nullptr, NN);
    hipMemcpyAsync(out_node, scratchN, (size_t)NN * DD * 4,
                   hipMemcpyDeviceToDevice, stream);
}

// Round 11
// 2555.647 us; speedup vs baseline: 1.3665x; 1.0967x over previous
//
#include <hip/hip_runtime.h>
#include <hip/hip_bf16.h>

#define NN 100000   // nodes
#define NE 200000   // bonds
#define NB 600000   // bond neighbours
#define FN 133
#define FB 14
#define FIB 147     // FN+FB
#define DD 256

typedef __hip_bfloat16 bf16;
typedef __attribute__((ext_vector_type(8))) short short8;   // 8 bf16 = 4 VGPR
typedef __attribute__((ext_vector_type(4))) float f32x4;

__device__ __forceinline__ float hswish(float x) {
    float c = fminf(fmaxf(x + 3.f, 0.f), 6.f);
    return x * c * (1.f / 6.f);
}
__device__ __forceinline__ float sigmoidf(float x) {
    return 1.f / (1.f + __expf(-x));
}
__device__ __forceinline__ float tanh_fast(float x) {
    // 1 - 2/(1+e^{2x}); saturates correctly for |x| large (exp->0 or inf)
    return 1.f - 2.f / (1.f + __expf(2.f * x));
}
__device__ __forceinline__ float bf2f(unsigned short u) {
    union { unsigned int i; float f; } c; c.i = (unsigned int)u << 16; return c.f;
}
__device__ __forceinline__ unsigned short f2bf(float v) {
    bf16 b = __float2bfloat16(v);
    unsigned short u; __builtin_memcpy(&u, &b, 2); return u;
}
__device__ __forceinline__ void unp8(short8 v, float* f) {
    #pragma unroll
    for (int j = 0; j < 8; j++) {
        short s = v[j]; unsigned short u; __builtin_memcpy(&u, &s, 2);
        f[j] = bf2f(u);
    }
}
__device__ __forceinline__ uint4 pk8(const float* f) {
    uint4 v;
    v.x = f2bf(f[0]) | ((unsigned)f2bf(f[1]) << 16);
    v.y = f2bf(f[2]) | ((unsigned)f2bf(f[3]) << 16);
    v.z = f2bf(f[4]) | ((unsigned)f2bf(f[5]) << 16);
    v.w = f2bf(f[6]) | ((unsigned)f2bf(f[7]) << 16);
    return v;
}

// ---------------- fill (zero counts + ws-guard sentinel) ----------------
__global__ __launch_bounds__(256) void fill_kernel(float* __restrict__ p, float v, long n4) {
    long i = (long)blockIdx.x * 256 + threadIdx.x;
    long st = (long)gridDim.x * 256;
    float4 z = {v, v, v, v};
    for (; i < n4; i += st) ((float4*)p)[i] = z;
}

// ---------------- IB build: IBbf[e][160] = [node[i_idx[e]] | bond[e] | 0]
__global__ __launch_bounds__(256) void build_ib_bf(
    const float* __restrict__ node, const float* __restrict__ bond,
    const int* __restrict__ i_idx, bf16* __restrict__ IB)
{
    int t = blockIdx.x * 256 + threadIdx.x;
    int row = t >> 6;
    if (row >= NE) return;
    int lane = t & 63;
    if (lane >= 40) return;
    int src = i_idx[row];
    int c = lane * 4;
    unsigned short us[4];
    #pragma unroll
    for (int j = 0; j < 4; j++) {
        int k = c + j;
        float v = 0.f;
        if (k < FN)       v = node[(size_t)src * FN + k];
        else if (k < FIB) v = bond[(size_t)row * FB + (k - FN)];
        us[j] = f2bf(v);
    }
    ushort4 o = {us[0], us[1], us[2], us[3]};
    *(ushort4*)((unsigned short*)IB + (size_t)row * 160 + c) = o;
}

// ---------------- CSR build helpers -------------------------------------
__global__ __launch_bounds__(256) void count_kernel(
    const int* __restrict__ idx, int n, int* __restrict__ cnt)
{
    int i = blockIdx.x * 256 + threadIdx.x;
    if (i < n) atomicAdd(&cnt[idx[i]], 1);
}

__global__ __launch_bounds__(256) void scan_block(int* __restrict__ data, int* __restrict__ bsum)
{
    __shared__ int lds[256];
    int base = blockIdx.x * 1024 + threadIdx.x * 4;
    int c0 = data[base], c1 = data[base + 1], c2 = data[base + 2], c3 = data[base + 3];
    int t = c0 + c1 + c2 + c3;
    lds[threadIdx.x] = t;
    __syncthreads();
    int x = t;
    for (int off = 1; off < 256; off <<= 1) {
        int y = (threadIdx.x >= off) ? lds[threadIdx.x - off] : 0;
        __syncthreads();
        x += y; lds[threadIdx.x] = x;
        __syncthreads();
    }
    int excl = x - t;
    data[base] = excl; data[base + 1] = excl + c0;
    data[base + 2] = excl + c0 + c1; data[base + 3] = excl + c0 + c1 + c2;
    if (threadIdx.x == 255) bsum[blockIdx.x] = x;
}

__global__ __launch_bounds__(256) void scan_bsum(int* __restrict__ bsum, int n)
{
    __shared__ int lds[256];
    int t = (threadIdx.x < n) ? bsum[threadIdx.x] : 0;
    lds[threadIdx.x] = t;
    __syncthreads();
    int x = t;
    for (int off = 1; off < 256; off <<= 1) {
        int y = (threadIdx.x >= off) ? lds[threadIdx.x - off] : 0;
        __syncthreads();
        x += y; lds[threadIdx.x] = x;
        __syncthreads();
    }
    if (threadIdx.x < n) bsum[threadIdx.x] = x - t;
}

__global__ __launch_bounds__(256) void scan_add(
    int* __restrict__ data, const int* __restrict__ bsum, int n)
{
    int i = blockIdx.x * 256 + threadIdx.x;
    if (i < n) data[i] += bsum[i >> 10];
}

__global__ __launch_bounds__(256) void copy_int(
    int* __restrict__ dst, const int* __restrict__ src, int n)
{
    int i = blockIdx.x * 256 + threadIdx.x;
    if (i < n) dst[i] = src[i];
}

__global__ __launch_bounds__(256) void fill_nb_list(
    const int* __restrict__ ij, const int* __restrict__ ki,
    int* __restrict__ cur, int* __restrict__ lst)
{
    int e = blockIdx.x * 256 + threadIdx.x;
    if (e < NB) { int p = atomicAdd(&cur[ij[e]], 1); lst[p] = ki[e]; }
}

__global__ __launch_bounds__(256) void fill_agg_list(
    const int* __restrict__ jidx, int* __restrict__ cur, int* __restrict__ lst)
{
    int e = blockIdx.x * 256 + threadIdx.x;
    if (e < NE) { int p = atomicAdd(&cur[jidx[e]], 1); lst[p] = e; }
}

// -------- fused seg_s + seg_r: one CSR walk, one MB gather pass ---------
__global__ __launch_bounds__(256) void seg_sr_kernel(
    const bf16* __restrict__ MB, const bf16* __restrict__ TR,
    const bf16* __restrict__ PR, const int* __restrict__ off,
    const int* __restrict__ lst,
    bf16* __restrict__ S, bf16* __restrict__ R)
{
    int sid = blockIdx.x * 4 + (threadIdx.x >> 6);
    if (sid >= NE) return;
    int lane = threadIdx.x & 63;
    ushort4 up = *(const ushort4*)((const unsigned short*)PR + (size_t)sid * DD + lane * 4);
    float p0 = bf2f(up.x), p1 = bf2f(up.y), p2 = bf2f(up.z), p3 = bf2f(up.w);
    int b = off[sid], e = off[sid + 1];
    float s0 = 0, s1 = 0, s2 = 0, s3 = 0;
    float r0 = 0, r1 = 0, r2 = 0, r3 = 0;
    for (int t = b; t < e; t++) {
        int src = lst[t];
        ushort4 um = *(const ushort4*)((const unsigned short*)MB + (size_t)src * DD + lane * 4);
        ushort4 ut = *(const ushort4*)((const unsigned short*)TR + (size_t)src * DD + lane * 4);
        float m0 = bf2f(um.x), m1 = bf2f(um.y), m2 = bf2f(um.z), m3 = bf2f(um.w);
        s0 += m0; s1 += m1; s2 += m2; s3 += m3;
        r0 += sigmoidf(p0 + bf2f(ut.x)) * m0;
        r1 += sigmoidf(p1 + bf2f(ut.y)) * m1;
        r2 += sigmoidf(p2 + bf2f(ut.z)) * m2;
        r3 += sigmoidf(p3 + bf2f(ut.w)) * m3;
    }
    ushort4 os = {f2bf(s0), f2bf(s1), f2bf(s2), f2bf(s3)};
    ushort4 orr = {f2bf(r0), f2bf(r1), f2bf(r2), f2bf(r3)};
    *(ushort4*)((unsigned short*)S + (size_t)sid * DD + lane * 4) = os;
    *(ushort4*)((unsigned short*)R + (size_t)sid * DD + lane * 4) = orr;
}

// ------------- weight pack: dst[n][k] = bf16(seg(k, n)), K-padded -------
__global__ __launch_bounds__(256) void pack_wt(
    const float* W1, int K1, const float* W2, int K2, const float* W3, int K3,
    int KTpad, bf16* dst)
{
    int idx = blockIdx.x * 256 + threadIdx.x;
    if (idx >= 256 * KTpad) return;
    int n = idx / KTpad, k = idx % KTpad;
    float v = 0.f;
    if (k < K1)                { if (W1) v = W1[(size_t)k * DD + n]; }
    else if (k < K1 + K2)      { if (W2) v = W2[(size_t)(k - K1) * DD + n]; }
    else if (k < K1 + K2 + K3) { if (W3) v = W3[(size_t)(k - K1 - K2) * DD + n]; }
    dst[(size_t)n * KTpad + k] = __float2bfloat16(v);
}

// ======== blend2: two sequential K=256 GEMM phases, small LDS ===========
__global__ __launch_bounds__(512) void blend2(
    const bf16* __restrict__ S, const bf16* __restrict__ R,
    const bf16* __restrict__ WTz2, const bf16* __restrict__ WTu,
    const bf16* __restrict__ PZ, const bf16* __restrict__ PM,
    bf16* __restrict__ MB)
{
    __shared__ __align__(16) unsigned short As[128 * 40];   // 10 KB
    __shared__ __align__(16) unsigned short Bs[128 * 40];   // 10 KB
    const int tid = threadIdx.x;
    const int row0 = blockIdx.x * 128, col0 = blockIdx.y * 128;
    const int lane = tid & 63, w = tid >> 6;
    const int wr = w >> 1, wc = w & 1;
    const int fr = lane & 15, ko = (lane >> 4) * 8;

    f32x4 acc1[2][4] = {};
    f32x4 acc2[2][4] = {};

    #pragma unroll
    for (int ph = 0; ph < 2; ph++) {
        const bf16* A = (ph == 0) ? S : R;
        const bf16* W = (ph == 0) ? WTz2 : WTu;
        for (int k0 = 0; k0 < DD; k0 += 32) {
            {
                int mloc = tid >> 2, kq = (tid & 3) * 8;
                int mg = row0 + mloc;
                uint4 v = {0, 0, 0, 0};
                if (mg < NE)
                    v = *(const uint4*)((const unsigned short*)A + (size_t)mg * DD + k0 + kq);
                *(uint4*)&As[mloc * 40 + kq] = v;
                *(uint4*)&Bs[mloc * 40 + kq] =
                    *(const uint4*)((const unsigned short*)W + (size_t)(col0 + mloc) * DD + k0 + kq);
            }
            __syncthreads();
            short8 af[2], bf8[4];
            #pragma unroll
            for (int mf = 0; mf < 2; mf++)
                af[mf] = *(const short8*)&As[(wr * 32 + mf * 16 + fr) * 40 + ko];
            #pragma unroll
            for (int nf = 0; nf < 4; nf++)
                bf8[nf] = *(const short8*)&Bs[(wc * 64 + nf * 16 + fr) * 40 + ko];
            #pragma unroll
            for (int mf = 0; mf < 2; mf++)
                #pragma unroll
                for (int nf = 0; nf < 4; nf++) {
                    if (ph == 0)
                        acc1[mf][nf] = __builtin_amdgcn_mfma_f32_16x16x32_bf16(af[mf], bf8[nf], acc1[mf][nf], 0, 0, 0);
                    else
                        acc2[mf][nf] = __builtin_amdgcn_mfma_f32_16x16x32_bf16(af[mf], bf8[nf], acc2[mf][nf], 0, 0, 0);
                }
            __syncthreads();
        }
    }

    #pragma unroll
    for (int mf = 0; mf < 2; mf++) {
        #pragma unroll
        for (int i = 0; i < 4; i++) {
            int mloc = wr * 32 + mf * 16 + (lane >> 4) * 4 + i;
            int gm = row0 + mloc;
            if (gm >= NE) continue;
            #pragma unroll
            for (int nf = 0; nf < 4; nf++) {
                int gc = col0 + wc * 64 + nf * 16 + fr;
                size_t idx = (size_t)gm * DD + gc;
                float z  = sigmoidf(acc1[mf][nf][i] + __bfloat162float(PZ[idx]));
                float mm = tanh_fast(acc2[mf][nf][i] + __bfloat162float(PM[idx]));
                float s  = __bfloat162float(S[idx]);
                MB[idx] = __float2bfloat16((1.f - z) * s + z * mm);
            }
        }
    }
}

// ======== pairk: [TR-GEMM blocks] ∥ [node-update blocks w/ fused AGG] ====
// blocks < trblocks : TR = MBn @ WTr2   (BM=128, BN=128, K=256)
// blocks >= trblocks: MN = hsw([MN | gatherAGG(MBn)] @ WTnu + PN)
//                     (BM=128, BN=256, K=512, in-place safe: full-row blocks)
__global__ __launch_bounds__(512) void pairk(
    int trblocks,
    const bf16* __restrict__ MBn, const bf16* __restrict__ WTr2,
    bf16* __restrict__ TRo,
    const bf16* __restrict__ MN, const int* __restrict__ offN,
    const int* __restrict__ agLst, const bf16* __restrict__ WTnu,
    const bf16* __restrict__ PN, bf16* __restrict__ MNout)
{
    __shared__ __align__(16) unsigned short As[128 * 40];   // 10 KB
    __shared__ __align__(16) unsigned short Bs[256 * 40];   // 20 KB
    const int tid = threadIdx.x, lane = tid & 63, w = tid >> 6;
    const int fr = lane & 15, ko = (lane >> 4) * 8;
    const int mloc = tid >> 2, kq = (tid & 3) * 8;

    if ((int)blockIdx.x < trblocks) {
        // ---------------- TR GEMM ----------------
        const int bx = blockIdx.x % 1563, by = blockIdx.x / 1563;
        const int row0 = bx * 128, col0 = by * 128;
        const int wr = w >> 1, wc = w & 1;
        const int mg = row0 + mloc;
        f32x4 acc[2][4] = {};
        for (int k0 = 0; k0 < 256; k0 += 32) {
            uint4 v = {0, 0, 0, 0};
            if (mg < NE)
                v = *(const uint4*)((const unsigned short*)MBn + (size_t)mg * DD + k0 + kq);
            *(uint4*)&As[mloc * 40 + kq] = v;
            *(uint4*)&Bs[mloc * 40 + kq] =
                *(const uint4*)((const unsigned short*)WTr2 + (size_t)(col0 + mloc) * DD + k0 + kq);
            __syncthreads();
            short8 af[2], bw[4];
            #pragma unroll
            for (int mf = 0; mf < 2; mf++)
                af[mf] = *(const short8*)&As[(wr * 32 + mf * 16 + fr) * 40 + ko];
            #pragma unroll
            for (int nf = 0; nf < 4; nf++)
                bw[nf] = *(const short8*)&Bs[(wc * 64 + nf * 16 + fr) * 40 + ko];
            #pragma unroll
            for (int mf = 0; mf < 2; mf++)
                #pragma unroll
                for (int nf = 0; nf < 4; nf++)
                    acc[mf][nf] = __builtin_amdgcn_mfma_f32_16x16x32_bf16(af[mf], bw[nf], acc[mf][nf], 0, 0, 0);
            __syncthreads();
        }
        #pragma unroll
        for (int mf = 0; mf < 2; mf++)
            #pragma unroll
            for (int i = 0; i < 4; i++) {
                int ml = wr * 32 + mf * 16 + (lane >> 4) * 4 + i;
                int gm = row0 + ml;
                if (gm >= NE) continue;
                #pragma unroll
                for (int nf = 0; nf < 4; nf++) {
                    int gc = col0 + wc * 64 + nf * 16 + fr;
                    TRo[(size_t)gm * DD + gc] = __float2bfloat16(acc[mf][nf][i]);
                }
            }
    } else {
        // ---------------- node update with fused AGG gather ----------------
        const int bx = blockIdx.x - trblocks;
        const int row0 = bx * 128;
        const int wr = w >> 2, wc = w & 3;
        const int mg = row0 + mloc;
        int eb = 0, ee = 0;
        if (mg < NN) { eb = offN[mg]; ee = offN[mg + 1]; }
        f32x4 acc[4][4] = {};
        for (int k0 = 0; k0 < 512; k0 += 32) {
            const int kg = k0 + kq;
            uint4 v = {0, 0, 0, 0};
            if (mg < NN) {
                if (kg < 256) {
                    v = *(const uint4*)((const unsigned short*)MN + (size_t)mg * DD + kg);
                } else {
                    const int kk = kg - 256;
                    float a[8] = {0, 0, 0, 0, 0, 0, 0, 0};
                    for (int t = eb; t < ee; t++) {
                        int src = agLst[t];
                        float m8[8];
                        unp8(*(const short8*)((const unsigned short*)MBn + (size_t)src * DD + kk), m8);
                        #pragma unroll
                        for (int j = 0; j < 8; j++) a[j] += m8[j];
                    }
                    v = pk8(a);
                }
            }
            *(uint4*)&As[mloc * 40 + kq] = v;
            #pragma unroll
            for (int it = 0; it < 2; ++it) {
                int nloc = (tid >> 2) + it * 128;
                *(uint4*)&Bs[nloc * 40 + kq] =
                    *(const uint4*)((const unsigned short*)WTnu + (size_t)nloc * 512 + k0 + kq);
            }
            __syncthreads();
            short8 af[4], bw[4];
            #pragma unroll
            for (int mf = 0; mf < 4; mf++)
                af[mf] = *(const short8*)&As[(wr * 64 + mf * 16 + fr) * 40 + ko];
            #pragma unroll
            for (int nf = 0; nf < 4; nf++)
                bw[nf] = *(const short8*)&Bs[(wc * 64 + nf * 16 + fr) * 40 + ko];
            #pragma unroll
            for (int mf = 0; mf < 4; mf++)
                #pragma unroll
                for (int nf = 0; nf < 4; nf++)
                    acc[mf][nf] = __builtin_amdgcn_mfma_f32_16x16x32_bf16(af[mf], bw[nf], acc[mf][nf], 0, 0, 0);
            __syncthreads();
        }
        #pragma unroll
        for (int mf = 0; mf < 4; mf++)
            #pragma unroll
            for (int i = 0; i < 4; i++) {
                int ml = wr * 64 + mf * 16 + (lane >> 4) * 4 + i;
                int gm = row0 + ml;
                if (gm >= NN) continue;
                #pragma unroll
                for (int nf = 0; nf < 4; nf++) {
                    int gc = wc * 64 + nf * 16 + fr;
                    size_t idx = (size_t)gm * DD + gc;
                    MNout[idx] = __float2bfloat16(
                        hswish(acc[mf][nf][i] + __bfloat162float(PN[idx])));
                }
            }
    }
}

// ---------------- unified MFMA GEMM, all-vector staging -----------------
// (pre/post-loop only; unchanged structure)
template <int BN, int NT, int DUAL, int EPB>
__global__ __launch_bounds__(NT) void bg(
    const void* __restrict__ A1, int a1stride, int a1kw, int a1real, int a1f32,
    const void* __restrict__ A2, int a2stride, int a2kw, int a2real, int a2f32,
    const bf16* __restrict__ WT1, const bf16* __restrict__ WT2, int KT,
    const float* __restrict__ bias1, const float* __restrict__ bias2,
    const bf16* __restrict__ PZb, const bf16* __restrict__ PMb,
    void* __restrict__ out1, void* __restrict__ out2, int M)
{
    constexpr int BM = 128;
    constexpr int nWc = BN / 64;
    constexpr int nWr = (NT / 64) / nWc;
    constexpr int MSPAN = BM / nWr;
    constexpr int MFR = MSPAN / 16;
    __shared__ __align__(16) unsigned short As[BM * 40];
    __shared__ __align__(16) unsigned short As2[(DUAL == 2 ? BM : 8) * 40];
    __shared__ __align__(16) unsigned short Bs[BN * 40];
    __shared__ __align__(16) unsigned short Bs2[(DUAL ? BN : 8) * 40];
    const int tid = threadIdx.x;
    const int row0 = blockIdx.x * BM, col0 = blockIdx.y * BN;
    const int lane = tid & 63, w = tid >> 6;
    const int wr = w / nWc, wc = w % nWc;
    const int fr = lane & 15, ko = (lane >> 4) * 8;

    f32x4 acc[MFR][4] = {};
    f32x4 acc2[DUAL ? MFR : 1][DUAL ? 4 : 1] = {};

    for (int k0 = 0; k0 < KT; k0 += 32) {
        #pragma unroll
        for (int it = 0; it < BM * 4 / NT; ++it) {
            int mloc = (tid >> 2) + it * (NT / 4);
            int mg = row0 + mloc;
            bool mok = (mg < M);
            int kq = (tid & 3) * 8;
            int kg = k0 + kq;
            if (DUAL == 2) {
                uint4 v1 = {0, 0, 0, 0}, v2 = {0, 0, 0, 0};
                if (mok) {
                    v1 = *(const uint4*)((const bf16*)A1 + (size_t)mg * a1stride + kg);
                    v2 = *(const uint4*)((const bf16*)A2 + (size_t)mg * a2stride + kg);
                }
                *(uint4*)&As[mloc * 40 + kq] = v1;
                *(uint4*)&As2[mloc * 40 + kq] = v2;
            } else {
                const void* p; int stride, real, isf; int kk;
                if (kg < a1kw) { p = A1; stride = a1stride; real = a1real; isf = a1f32; kk = kg; }
                else           { p = A2; stride = a2stride; real = a2real; isf = a2f32; kk = kg - a1kw; }
                uint4 v = {0, 0, 0, 0};
                if (mok) {
                    if (!isf) {
                        v = *(const uint4*)((const bf16*)p + (size_t)mg * stride + kk);
                    } else {
                        const float* fp = (const float*)p + (size_t)mg * stride;
                        unsigned short us[8];
                        #pragma unroll
                        for (int j = 0; j < 8; j++)
                            us[j] = (kk + j < real) ? f2bf(fp[kk + j]) : (unsigned short)0;
                        v.x = us[0] | ((unsigned)us[1] << 16);
                        v.y = us[2] | ((unsigned)us[3] << 16);
                        v.z = us[4] | ((unsigned)us[5] << 16);
                        v.w = us[6] | ((unsigned)us[7] << 16);
                    }
                }
                *(uint4*)&As[mloc * 40 + kq] = v;
            }
        }
        #pragma unroll
        for (int it = 0; it < BN * 4 / NT; ++it) {
            int nloc = (tid >> 2) + it * (NT / 4);
            int kq = (tid & 3) * 8;
            *(uint4*)&Bs[nloc * 40 + kq] =
                *(const uint4*)&WT1[(size_t)(col0 + nloc) * KT + k0 + kq];
            if (DUAL)
                *(uint4*)&Bs2[nloc * 40 + kq] =
                    *(const uint4*)&WT2[(size_t)(col0 + nloc) * KT + k0 + kq];
        }
        __syncthreads();
        short8 a1f[MFR], b1f[4];
        short8 a2f[DUAL == 2 ? MFR : 1], b2f[DUAL ? 4 : 1];
        #pragma unroll
        for (int mf = 0; mf < MFR; mf++) {
            a1f[mf] = *(const short8*)&As[(wr * MSPAN + mf * 16 + fr) * 40 + ko];
            if (DUAL == 2)
                a2f[mf] = *(const short8*)&As2[(wr * MSPAN + mf * 16 + fr) * 40 + ko];
        }
        #pragma unroll
        for (int nf = 0; nf < 4; nf++) {
            b1f[nf] = *(const short8*)&Bs[(wc * 64 + nf * 16 + fr) * 40 + ko];
            if (DUAL)
                b2f[nf] = *(const short8*)&Bs2[(wc * 64 + nf * 16 + fr) * 40 + ko];
        }
        #pragma unroll
        for (int mf = 0; mf < MFR; mf++)
            #pragma unroll
            for (int nf = 0; nf < 4; nf++) {
                acc[mf][nf] = __builtin_amdgcn_mfma_f32_16x16x32_bf16(a1f[mf], b1f[nf], acc[mf][nf], 0, 0, 0);
                if (DUAL)
                    acc2[mf][nf] = __builtin_amdgcn_mfma_f32_16x16x32_bf16(
                        DUAL == 2 ? a2f[mf] : a1f[mf], b2f[nf], acc2[mf][nf], 0, 0, 0);
            }
        __syncthreads();
    }

    #pragma unroll
    for (int mf = 0; mf < MFR; mf++) {
        #pragma unroll
        for (int i = 0; i < 4; i++) {
            int mloc = wr * MSPAN + mf * 16 + (lane >> 4) * 4 + i;
            int gm = row0 + mloc;
            if (gm >= M) continue;
            #pragma unroll
            for (int nf = 0; nf < 4; nf++) {
                int gc = col0 + wc * 64 + nf * 16 + fr;
                size_t idx = (size_t)gm * DD + gc;
                float v = acc[mf][nf][i];
                if (EPB == 0) {
                    if (bias1) v += bias1[gc];
                    ((bf16*)out1)[idx] = __float2bfloat16(v);
                } else if (EPB == 1) {
                    ((bf16*)out1)[idx] = __float2bfloat16(hswish(v + bias1[gc]));
                } else if (EPB == 2) {
                    ((bf16*)out1)[idx] = __float2bfloat16(hswish(v + bias1[gc]));
                    ((bf16*)out2)[idx] = __float2bfloat16(acc2[mf][nf][i] + bias2[gc]);
                } else if (EPB == 3) {
                    ((bf16*)out1)[idx] = __float2bfloat16(v + bias1[gc]);
                    ((bf16*)out2)[idx] = __float2bfloat16(acc2[mf][nf][i] + bias2[gc]);
                } else if (EPB == 4) {
                    float z  = sigmoidf(v + __bfloat162float(PZb[idx]));
                    float mm = tanh_fast(acc2[mf][nf][i] + __bfloat162float(PMb[idx]));
                    float s  = __bfloat162float(((const bf16*)A1)[idx]);
                    ((bf16*)out1)[idx] = __float2bfloat16((1.f - z) * s + z * mm);
                } else if (EPB == 5) {
                    ((bf16*)out1)[idx] =
                        __float2bfloat16(hswish(v + __bfloat162float(PZb[idx])));
                } else {  // EPB == 6
                    ((float*)out1)[idx] = hswish(v + bias1[gc]);
                }
            }
        }
    }
}

extern "C" void kernel_launch(void* const* d_in, const int* in_sizes, int n_in,
                              void* d_out, int out_size, void* d_ws, size_t ws_size,
                              hipStream_t stream)
{
    const float* node  = (const float*)d_in[0];
    const float* bond  = (const float*)d_in[1];
    const int* connect = (const int*)d_in[2];
    const int* bnb     = (const int*)d_in[3];
    const float* w_node       = (const float*)d_in[4];
    const float* b_node       = (const float*)d_in[5];
    const float* w_node_final = (const float*)d_in[6];
    const float* b_node_final = (const float*)d_in[7];
    const float* w_bond       = (const float*)d_in[8];
    const float* b_bond       = (const float*)d_in[9];
    const float* w_bond_final = (const float*)d_in[10];
    const float* b_bond_final = (const float*)d_in[11];
    const float* w_z = (const float*)d_in[12];
    const float* b_z = (const float*)d_in[13];
    const float* w_r = (const float*)d_in[14];
    const float* b_r = (const float*)d_in[15];
    const float* u_  = (const float*)d_in[16];
    const float* w_m = (const float*)d_in[17];
    const float* b_m = (const float*)d_in[18];
    const float* w_n = (const float*)d_in[19];
    const float* b_n = (const float*)d_in[20];
    const float* u_n = (const float*)d_in[21];

    const int* i_idx = connect;
    const int* j_idx = connect + NE;
    const int* ij    = bnb;
    const int* ki    = bnb + NB;

    const size_t EBH = (size_t)NE * DD * 2;        // 102,400,000
    const size_t B_WT = (size_t)3072 * 256 * 2;    // 1.57 MB packed weights
    const int NEpad = 196 * 1024;
    const int NNpad = 98 * 1024;
    const size_t B_CSR = (size_t)NEpad * 8 + (size_t)NB * 4
                       + (size_t)NNpad * 8 + (size_t)NE * 4 + 2048;
    const size_t NEED = 5 * EBH + B_WT + B_CSR;    // ~519.4 MB (known to fit)

    float* out_node = (float*)d_out;
    float* out_bond = out_node + (size_t)NN * DD;

    if (ws_size < NEED) {
        fill_kernel<<<2048, 256, 0, stream>>>((float*)d_out, 1e6f, (long)out_size / 4);
        return;
    }

    char* base = (char*)d_ws;
    bf16* PR = (bf16*)base;                       base += EBH;
    bf16* MB = (bf16*)base;                       base += EBH;
    bf16* TR = (bf16*)base;                       base += EBH;   // also IBbf / final-node scratch
    bf16* PZ = (bf16*)base;                       base += EBH;
    bf16* PM = (bf16*)base;                       base += EBH;
    char* wt = base;                              base += B_WT;
    int* offE  = (int*)base;                      base += (size_t)NEpad * 4;
    int* curE  = (int*)base;                      base += (size_t)NEpad * 4;
    int* nbLst = (int*)base;                      base += (size_t)NB * 4;
    int* offN  = (int*)base;                      base += (size_t)NNpad * 4;
    int* curN  = (int*)base;                      base += (size_t)NNpad * 4;
    int* agLst = (int*)base;                      base += (size_t)NE * 4;
    int* bsumE = (int*)base;                      base += 1024;
    int* bsumN = (int*)base;

    bf16* IBbf = TR;
    float* scratchN = (float*)TR;
    bf16* R = (bf16*)out_bond;
    bf16* S = R + (size_t)NE * DD;
    bf16* MN = (bf16*)out_node;
    bf16* PN = MN + (size_t)NN * DD;

    auto wtAlloc = [&](size_t elems) { bf16* p = (bf16*)wt; wt += elems * 2; return p; };
    bf16* WTr  = wtAlloc(160 * 256);   // w_r[0:147]
    bf16* WTz1 = wtAlloc(160 * 256);   // w_z[0:147]
    bf16* WTb  = wtAlloc(160 * 256);   // w_bond
    bf16* WTm1 = wtAlloc(160 * 256);   // w_m
    bf16* WTn0 = wtAlloc(160 * 256);   // w_node
    bf16* WTn  = wtAlloc(160 * 256);   // w_n
    bf16* WTr2 = wtAlloc(256 * 256);   // w_r[147:403]
    bf16* WTz2 = wtAlloc(256 * 256);   // w_z[147:403]
    bf16* WTu  = wtAlloc(256 * 256);   // u
    bf16* WTnu = wtAlloc(512 * 256);   // u_n
    bf16* WTbf = wtAlloc(416 * 256);   // w_bond_final
    bf16* WTnf = wtAlloc(416 * 256);   // w_node_final

    const float* w_r2 = w_r + (size_t)FIB * DD;
    const float* w_z2 = w_z + (size_t)FIB * DD;

    auto packG = [&](int ktpad) { return (256 * ktpad + 255) / 256; };
    pack_wt<<<packG(160), 256, 0, stream>>>(w_r, FIB, nullptr, 0, nullptr, 0, 160, WTr);
    pack_wt<<<packG(160), 256, 0, stream>>>(w_z, FIB, nullptr, 0, nullptr, 0, 160, WTz1);
    pack_wt<<<packG(160), 256, 0, stream>>>(w_bond, FIB, nullptr, 0, nullptr, 0, 160, WTb);
    pack_wt<<<packG(160), 256, 0, stream>>>(w_m, FIB, nullptr, 0, nullptr, 0, 160, WTm1);
    pack_wt<<<packG(160), 256, 0, stream>>>(w_node, FN, nullptr, 0, nullptr, 0, 160, WTn0);
    pack_wt<<<packG(160), 256, 0, stream>>>(w_n, FN, nullptr, 0, nullptr, 0, 160, WTn);
    pack_wt<<<packG(256), 256, 0, stream>>>(w_r2, DD, nullptr, 0, nullptr, 0, 256, WTr2);
    pack_wt<<<packG(256), 256, 0, stream>>>(w_z2, DD, nullptr, 0, nullptr, 0, 256, WTz2);
    pack_wt<<<packG(256), 256, 0, stream>>>(u_, DD, nullptr, 0, nullptr, 0, 256, WTu);
    pack_wt<<<packG(512), 256, 0, stream>>>(u_n, 2 * DD, nullptr, 0, nullptr, 0, 512, WTnu);
    pack_wt<<<packG(416), 256, 0, stream>>>(w_bond_final, FIB, nullptr, 13,
                                            w_bond_final + (size_t)FIB * DD, DD, 416, WTbf);
    pack_wt<<<packG(416), 256, 0, stream>>>(w_node_final, FN, nullptr, 27,
                                            w_node_final + (size_t)FN * DD, DD, 416, WTnf);

    // ---- CSR build (layer-invariant) ----
    fill_kernel<<<256, 256, 0, stream>>>((float*)offE, 0.f, NEpad / 4);
    fill_kernel<<<256, 256, 0, stream>>>((float*)offN, 0.f, NNpad / 4);
    count_kernel<<<(NB + 255) / 256, 256, 0, stream>>>(ij, NB, offE);
    count_kernel<<<(NE + 255) / 256, 256, 0, stream>>>(j_idx, NE, offN);
    scan_block<<<196, 256, 0, stream>>>(offE, bsumE);
    scan_bsum<<<1, 256, 0, stream>>>(bsumE, 196);
    scan_add<<<NEpad / 256, 256, 0, stream>>>(offE, bsumE, NEpad);
    scan_block<<<98, 256, 0, stream>>>(offN, bsumN);
    scan_bsum<<<1, 256, 0, stream>>>(bsumN, 98);
    scan_add<<<NNpad / 256, 256, 0, stream>>>(offN, bsumN, NNpad);
    copy_int<<<NEpad / 256, 256, 0, stream>>>(curE, offE, NEpad);
    copy_int<<<NNpad / 256, 256, 0, stream>>>(curN, offN, NNpad);
    fill_nb_list<<<(NB + 255) / 256, 256, 0, stream>>>(ij, ki, curE, nbLst);
    fill_agg_list<<<(NE + 255) / 256, 256, 0, stream>>>(j_idx, curN, agLst);

    dim3 gB2(1563, 2);    // NE rows, BN=128
    dim3 gB1(1563, 1);    // NE rows, BN=256
    dim3 gN2(782, 2);     // NN rows, BN=128
    dim3 gN1(782, 1);     // NN rows, BN=256
    int blkIB = NE * 64 / 256;

    // ---- pre-loop: build IB once, hoist all layer-invariant GEMMs ----
    build_ib_bf<<<blkIB, 256, 0, stream>>>(node, bond, i_idx, IBbf);
    bg<128, 512, 1, 3><<<gB2, 512, 0, stream>>>(        // PR, PZ
        IBbf, 160, 160, 160, 0, nullptr, 0, 0, 0, 0,
        WTr, WTz1, 160, b_r, b_z, nullptr, nullptr, PR, PZ, NE);
    bg<128, 512, 1, 2><<<gB2, 512, 0, stream>>>(        // MB, PM
        IBbf, 160, 160, 160, 0, nullptr, 0, 0, 0, 0,
        WTb, WTm1, 160, b_bond, b_m, nullptr, nullptr, MB, PM, NE);
    bg<128, 512, 1, 2><<<gN2, 512, 0, stream>>>(        // MN, PN
        node, FN, 160, FN, 1, nullptr, 0, 0, 0, 0,
        WTn0, WTn, 160, b_node, b_n, nullptr, nullptr, MN, PN, NN);
    bg<128, 256, 0, 0><<<gB2, 256, 0, stream>>>(        // TR_0 = MB @ w_r2
        MB, 256, 256, 256, 0, nullptr, 0, 0, 0, 0,
        WTr2, nullptr, 256, nullptr, nullptr, nullptr, nullptr, TR, nullptr, NE);

    for (int l = 0; l < 3; l++) {
        seg_sr_kernel<<<(NE + 3) / 4, 256, 0, stream>>>(MB, TR, PR, offE, nbLst, S, R);
        blend2<<<gB2, 512, 0, stream>>>(S, R, WTz2, WTu, PZ, PM, MB);
        // [TR_{l+1} || node-update_l(fused AGG gather)] — both read new MB only
        int trb = (l < 2) ? 3126 : 0;
        pairk<<<trb + 782, 512, 0, stream>>>(trb, MB, WTr2, TR,
                                             MN, offN, agLst, WTnu, PN, MN);
    }

    // ---- finals ----
    build_ib_bf<<<blkIB, 256, 0, stream>>>(node, bond, i_idx, IBbf);
    bg<256, 512, 0, 6><<<gB1, 512, 0, stream>>>(        // bond final -> f32 out_bond
        IBbf, 160, 160, 160, 0, MB, 256, 256, 256, 0,
        WTbf, nullptr, 416, b_bond_final, nullptr, nullptr, nullptr, out_bond, nullptr, NE);
    bg<256, 512, 0, 6><<<gN1, 512, 0, stream>>>(        // node final -> f32 scratch
        node, FN, 160, FN, 1, MN, 256, 256, 256, 0,
        WTnf, nullptr, 416, b_node_final, nullptr, nullptr, nullptr, scratchN, nullptr, NN);
    hipMemcpyAsync(out_node, scratchN, (size_t)NN * DD * 4,
                   hipMemcpyDeviceToDevice, stream);
}

// Round 12
// 2482.462 us; speedup vs baseline: 1.4067x; 1.0295x over previous
//
#include <hip/hip_runtime.h>
#include <hip/hip_bf16.h>

#define NN 100000   // nodes
#define NE 200000   // bonds
#define NB 600000   // bond neighbours
#define FN 133
#define FB 14
#define FIB 147     // FN+FB
#define DD 256
#define NEPAD (196 * 1024)
#define NNPAD (98 * 1024)

typedef __hip_bfloat16 bf16;
typedef __attribute__((ext_vector_type(8))) short short8;   // 8 bf16 = 4 VGPR
typedef __attribute__((ext_vector_type(4))) float f32x4;

__device__ __forceinline__ float hswish(float x) {
    float c = fminf(fmaxf(x + 3.f, 0.f), 6.f);
    return x * c * (1.f / 6.f);
}
__device__ __forceinline__ float sigmoidf(float x) {
    return 1.f / (1.f + __expf(-x));
}
__device__ __forceinline__ float tanh_fast(float x) {
    return 1.f - 2.f / (1.f + __expf(2.f * x));
}
__device__ __forceinline__ float bf2f(unsigned short u) {
    union { unsigned int i; float f; } c; c.i = (unsigned int)u << 16; return c.f;
}
__device__ __forceinline__ unsigned short f2bf(float v) {
    bf16 b = __float2bfloat16(v);
    unsigned short u; __builtin_memcpy(&u, &b, 2); return u;
}
__device__ __forceinline__ void unp8(short8 v, float* f) {
    #pragma unroll
    for (int j = 0; j < 8; j++) {
        short s = v[j]; unsigned short u; __builtin_memcpy(&u, &s, 2);
        f[j] = bf2f(u);
    }
}
__device__ __forceinline__ uint4 pk8(const float* f) {
    uint4 v;
    v.x = f2bf(f[0]) | ((unsigned)f2bf(f[1]) << 16);
    v.y = f2bf(f[2]) | ((unsigned)f2bf(f[3]) << 16);
    v.z = f2bf(f[4]) | ((unsigned)f2bf(f[5]) << 16);
    v.w = f2bf(f[6]) | ((unsigned)f2bf(f[7]) << 16);
    return v;
}

// ---------------- fill (ws-guard sentinel only) -------------------------
__global__ __launch_bounds__(256) void fill_kernel(float* __restrict__ p, float v, long n4) {
    long i = (long)blockIdx.x * 256 + threadIdx.x;
    long st = (long)gridDim.x * 256;
    float4 z = {v, v, v, v};
    for (; i < n4; i += st) ((float4*)p)[i] = z;
}

// ---------------- IB build: IBbf[e][160] = [node[i_idx[e]] | bond[e] | 0]
__global__ __launch_bounds__(256) void build_ib_bf(
    const float* __restrict__ node, const float* __restrict__ bond,
    const int* __restrict__ i_idx, bf16* __restrict__ IB)
{
    int t = blockIdx.x * 256 + threadIdx.x;
    int row = t >> 6;
    if (row >= NE) return;
    int lane = t & 63;
    if (lane >= 40) return;
    int src = i_idx[row];
    int c = lane * 4;
    unsigned short us[4];
    #pragma unroll
    for (int j = 0; j < 4; j++) {
        int k = c + j;
        float v = 0.f;
        if (k < FN)       v = node[(size_t)src * FN + k];
        else if (k < FIB) v = bond[(size_t)row * FB + (k - FN)];
        us[j] = f2bf(v);
    }
    ushort4 o = {us[0], us[1], us[2], us[3]};
    *(ushort4*)((unsigned short*)IB + (size_t)row * 160 + c) = o;
}

// ---------------- merged CSR build (E and N in one pass each) -----------
__global__ __launch_bounds__(256) void zero2_kernel(int* __restrict__ offE, int* __restrict__ offN)
{
    int i = blockIdx.x * 256 + threadIdx.x;
    if (i < NEPAD) offE[i] = 0;
    else if (i < NEPAD + NNPAD) offN[i - NEPAD] = 0;
}

__global__ __launch_bounds__(256) void count2_kernel(
    const int* __restrict__ ij, const int* __restrict__ jidx,
    int* __restrict__ offE, int* __restrict__ offN)
{
    int i = blockIdx.x * 256 + threadIdx.x;
    if (i < NB) atomicAdd(&offE[ij[i]], 1);
    else if (i < NB + NE) atomicAdd(&offN[jidx[i - NB]], 1);
}

__global__ __launch_bounds__(256) void scan_block2(
    int* __restrict__ offE, int* __restrict__ offN,
    int* __restrict__ bsumE, int* __restrict__ bsumN)
{
    __shared__ int lds[256];
    int* data; int* bs; int bb;
    if ((int)blockIdx.x < 196) { data = offE; bs = bsumE; bb = blockIdx.x; }
    else                       { data = offN; bs = bsumN; bb = blockIdx.x - 196; }
    int base = bb * 1024 + threadIdx.x * 4;
    int c0 = data[base], c1 = data[base + 1], c2 = data[base + 2], c3 = data[base + 3];
    int t = c0 + c1 + c2 + c3;
    lds[threadIdx.x] = t;
    __syncthreads();
    int x = t;
    for (int off = 1; off < 256; off <<= 1) {
        int y = (threadIdx.x >= off) ? lds[threadIdx.x - off] : 0;
        __syncthreads();
        x += y; lds[threadIdx.x] = x;
        __syncthreads();
    }
    int excl = x - t;
    data[base] = excl; data[base + 1] = excl + c0;
    data[base + 2] = excl + c0 + c1; data[base + 3] = excl + c0 + c1 + c2;
    if (threadIdx.x == 255) bs[bb] = x;
}

__global__ __launch_bounds__(256) void scan_bsum2(int* __restrict__ bsumE, int* __restrict__ bsumN)
{
    __shared__ int lds[256];
    int* bs = blockIdx.x ? bsumN : bsumE;
    int n = blockIdx.x ? 98 : 196;
    int t = (threadIdx.x < n) ? bs[threadIdx.x] : 0;
    lds[threadIdx.x] = t;
    __syncthreads();
    int x = t;
    for (int off = 1; off < 256; off <<= 1) {
        int y = (threadIdx.x >= off) ? lds[threadIdx.x - off] : 0;
        __syncthreads();
        x += y; lds[threadIdx.x] = x;
        __syncthreads();
    }
    if (threadIdx.x < n) bs[threadIdx.x] = x - t;
}

__global__ __launch_bounds__(256) void scan_add2(
    int* __restrict__ offE, int* __restrict__ offN,
    const int* __restrict__ bsumE, const int* __restrict__ bsumN)
{
    int i = blockIdx.x * 256 + threadIdx.x;
    if (i < NEPAD) offE[i] += bsumE[i >> 10];
    else if (i < NEPAD + NNPAD) { int j = i - NEPAD; offN[j] += bsumN[j >> 10]; }
}

__global__ __launch_bounds__(256) void copy2_kernel(
    int* __restrict__ curE, int* __restrict__ curN,
    const int* __restrict__ offE, const int* __restrict__ offN)
{
    int i = blockIdx.x * 256 + threadIdx.x;
    if (i < NEPAD) curE[i] = offE[i];
    else if (i < NEPAD + NNPAD) { int j = i - NEPAD; curN[j] = offN[j]; }
}

__global__ __launch_bounds__(256) void lists2_kernel(
    const int* __restrict__ ij, const int* __restrict__ ki, const int* __restrict__ jidx,
    int* __restrict__ curE, int* __restrict__ curN,
    int* __restrict__ nbLst, int* __restrict__ agLst)
{
    int i = blockIdx.x * 256 + threadIdx.x;
    if (i < NB) { int p = atomicAdd(&curE[ij[i]], 1); nbLst[p] = ki[i]; }
    else if (i < NB + NE) {
        int e = i - NB;
        int p = atomicAdd(&curN[jidx[e]], 1); agLst[p] = e;
    }
}

// ------------- single-launch weight pack (fixed layout, 786432 elems) ---
// layout (elements): 6x[160x256] @0,40960,..,204800 (w_r,w_z,w_bond,w_m,w_node,w_n)
// 3x[256x256] @245760 (w_r2,w_z2,u); [512x256] @442368 (u_n);
// 2x[416x256] @573440 (w_bond_final, w_node_final: K1 | zeros..160 | +K1 rows)
__global__ __launch_bounds__(256) void pack_all(
    const float* __restrict__ w_r, const float* __restrict__ w_z,
    const float* __restrict__ w_bond, const float* __restrict__ w_m,
    const float* __restrict__ w_node, const float* __restrict__ w_n,
    const float* __restrict__ u_, const float* __restrict__ u_n,
    const float* __restrict__ w_bf, const float* __restrict__ w_nf,
    bf16* __restrict__ wt)
{
    int idx = blockIdx.x * 256 + threadIdx.x;
    if (idx >= 786432) return;
    float v = 0.f;
    if (idx < 245760) {
        int r = idx / 40960;
        int loc = idx - r * 40960;
        int n = loc / 160, k = loc % 160;
        const float* W = (r == 0) ? w_r : (r == 1) ? w_z : (r == 2) ? w_bond
                       : (r == 3) ? w_m : (r == 4) ? w_node : w_n;
        int K1 = (r < 4) ? FIB : FN;
        if (k < K1) v = W[(size_t)k * DD + n];
    } else if (idx < 442368) {
        int r = (idx - 245760) / 65536;
        int loc = (idx - 245760) - r * 65536;
        int n = loc / 256, k = loc % 256;
        const float* W = (r == 0) ? (w_r + (size_t)FIB * DD)
                       : (r == 1) ? (w_z + (size_t)FIB * DD) : u_;
        v = W[(size_t)k * DD + n];
    } else if (idx < 573440) {
        int loc = idx - 442368;
        int n = loc / 512, k = loc % 512;
        v = u_n[(size_t)k * DD + n];
    } else {
        int r = (idx - 573440) / 106496;
        int loc = (idx - 573440) - r * 106496;
        int n = loc / 416, k = loc % 416;
        const float* W = r ? w_nf : w_bf;
        int K1 = r ? FN : FIB;
        if (k < K1)        v = W[(size_t)k * DD + n];
        else if (k >= 160) v = W[(size_t)(K1 + k - 160) * DD + n];
    }
    wt[idx] = __float2bfloat16(v);
}

// -------- fused seg_s + seg_r: one CSR walk, one MB gather pass ---------
__global__ __launch_bounds__(256) void seg_sr_kernel(
    const bf16* __restrict__ MB, const bf16* __restrict__ TR,
    const bf16* __restrict__ PR, const int* __restrict__ off,
    const int* __restrict__ lst,
    bf16* __restrict__ S, bf16* __restrict__ R)
{
    int sid = blockIdx.x * 4 + (threadIdx.x >> 6);
    if (sid >= NE) return;
    int lane = threadIdx.x & 63;
    ushort4 up = *(const ushort4*)((const unsigned short*)PR + (size_t)sid * DD + lane * 4);
    float p0 = bf2f(up.x), p1 = bf2f(up.y), p2 = bf2f(up.z), p3 = bf2f(up.w);
    int b = off[sid], e = off[sid + 1];
    float s0 = 0, s1 = 0, s2 = 0, s3 = 0;
    float r0 = 0, r1 = 0, r2 = 0, r3 = 0;
    for (int t = b; t < e; t++) {
        int src = lst[t];
        ushort4 um = *(const ushort4*)((const unsigned short*)MB + (size_t)src * DD + lane * 4);
        ushort4 ut = *(const ushort4*)((const unsigned short*)TR + (size_t)src * DD + lane * 4);
        float m0 = bf2f(um.x), m1 = bf2f(um.y), m2 = bf2f(um.z), m3 = bf2f(um.w);
        s0 += m0; s1 += m1; s2 += m2; s3 += m3;
        r0 += sigmoidf(p0 + bf2f(ut.x)) * m0;
        r1 += sigmoidf(p1 + bf2f(ut.y)) * m1;
        r2 += sigmoidf(p2 + bf2f(ut.z)) * m2;
        r3 += sigmoidf(p3 + bf2f(ut.w)) * m3;
    }
    ushort4 os = {f2bf(s0), f2bf(s1), f2bf(s2), f2bf(s3)};
    ushort4 orr = {f2bf(r0), f2bf(r1), f2bf(r2), f2bf(r3)};
    *(ushort4*)((unsigned short*)S + (size_t)sid * DD + lane * 4) = os;
    *(ushort4*)((unsigned short*)R + (size_t)sid * DD + lane * 4) = orr;
}

// ======== blend2: two sequential K=256 GEMM phases, k-step 64 ===========
__global__ __launch_bounds__(512) void blend2(
    const bf16* __restrict__ S, const bf16* __restrict__ R,
    const bf16* __restrict__ WTz2, const bf16* __restrict__ WTu,
    const bf16* __restrict__ PZ, const bf16* __restrict__ PM,
    bf16* __restrict__ MB)
{
    __shared__ __align__(16) unsigned short As[128 * 72];   // 18.4 KB
    __shared__ __align__(16) unsigned short Bs[128 * 72];   // 18.4 KB
    const int tid = threadIdx.x;
    const int row0 = blockIdx.x * 128, col0 = blockIdx.y * 128;
    const int lane = tid & 63, w = tid >> 6;
    const int wr = w >> 1, wc = w & 1;
    const int fr = lane & 15, ko = (lane >> 4) * 8;

    f32x4 acc1[2][4] = {};
    f32x4 acc2[2][4] = {};

    #pragma unroll
    for (int ph = 0; ph < 2; ph++) {
        const bf16* A = (ph == 0) ? S : R;
        const bf16* W = (ph == 0) ? WTz2 : WTu;
        for (int k0 = 0; k0 < DD; k0 += 64) {
            {
                int mloc = tid >> 2, kq = (tid & 3) * 16;
                int mg = row0 + mloc;
                uint4 va = {0, 0, 0, 0}, va2 = {0, 0, 0, 0};
                if (mg < NE) {
                    va  = *(const uint4*)((const unsigned short*)A + (size_t)mg * DD + k0 + kq);
                    va2 = *(const uint4*)((const unsigned short*)A + (size_t)mg * DD + k0 + kq + 8);
                }
                uint4 vb  = *(const uint4*)((const unsigned short*)W + (size_t)(col0 + mloc) * DD + k0 + kq);
                uint4 vb2 = *(const uint4*)((const unsigned short*)W + (size_t)(col0 + mloc) * DD + k0 + kq + 8);
                *(uint4*)&As[mloc * 72 + kq] = va;
                *(uint4*)&As[mloc * 72 + kq + 8] = va2;
                *(uint4*)&Bs[mloc * 72 + kq] = vb;
                *(uint4*)&Bs[mloc * 72 + kq + 8] = vb2;
            }
            __syncthreads();
            #pragma unroll
            for (int kk = 0; kk < 64; kk += 32) {
                short8 af[2], bf8[4];
                #pragma unroll
                for (int mf = 0; mf < 2; mf++)
                    af[mf] = *(const short8*)&As[(wr * 32 + mf * 16 + fr) * 72 + kk + ko];
                #pragma unroll
                for (int nf = 0; nf < 4; nf++)
                    bf8[nf] = *(const short8*)&Bs[(wc * 64 + nf * 16 + fr) * 72 + kk + ko];
                #pragma unroll
                for (int mf = 0; mf < 2; mf++)
                    #pragma unroll
                    for (int nf = 0; nf < 4; nf++) {
                        if (ph == 0)
                            acc1[mf][nf] = __builtin_amdgcn_mfma_f32_16x16x32_bf16(af[mf], bf8[nf], acc1[mf][nf], 0, 0, 0);
                        else
                            acc2[mf][nf] = __builtin_amdgcn_mfma_f32_16x16x32_bf16(af[mf], bf8[nf], acc2[mf][nf], 0, 0, 0);
                    }
            }
            __syncthreads();
        }
    }

    #pragma unroll
    for (int mf = 0; mf < 2; mf++) {
        #pragma unroll
        for (int i = 0; i < 4; i++) {
            int mloc = wr * 32 + mf * 16 + (lane >> 4) * 4 + i;
            int gm = row0 + mloc;
            if (gm >= NE) continue;
            #pragma unroll
            for (int nf = 0; nf < 4; nf++) {
                int gc = col0 + wc * 64 + nf * 16 + fr;
                size_t idx = (size_t)gm * DD + gc;
                float z  = sigmoidf(acc1[mf][nf][i] + __bfloat162float(PZ[idx]));
                float mm = tanh_fast(acc2[mf][nf][i] + __bfloat162float(PM[idx]));
                float s  = __bfloat162float(S[idx]);
                MB[idx] = __float2bfloat16((1.f - z) * s + z * mm);
            }
        }
    }
}

// ======== pairk: [TR-GEMM blocks] ∥ [node-update blocks w/ fused AGG] ====
__global__ __launch_bounds__(512) void pairk(
    int trblocks,
    const bf16* __restrict__ MBn, const bf16* __restrict__ WTr2,
    bf16* __restrict__ TRo,
    const bf16* __restrict__ MN, const int* __restrict__ offN,
    const int* __restrict__ agLst, const bf16* __restrict__ WTnu,
    const bf16* __restrict__ PN, bf16* __restrict__ MNout)
{
    __shared__ __align__(16) unsigned short As[128 * 40];   // 10 KB
    __shared__ __align__(16) unsigned short Bs[256 * 40];   // 20 KB
    const int tid = threadIdx.x, lane = tid & 63, w = tid >> 6;
    const int fr = lane & 15, ko = (lane >> 4) * 8;
    const int mloc = tid >> 2, kq = (tid & 3) * 8;

    if ((int)blockIdx.x < trblocks) {
        const int bx = blockIdx.x % 1563, by = blockIdx.x / 1563;
        const int row0 = bx * 128, col0 = by * 128;
        const int wr = w >> 1, wc = w & 1;
        const int mg = row0 + mloc;
        f32x4 acc[2][4] = {};
        for (int k0 = 0; k0 < 256; k0 += 32) {
            uint4 v = {0, 0, 0, 0};
            if (mg < NE)
                v = *(const uint4*)((const unsigned short*)MBn + (size_t)mg * DD + k0 + kq);
            *(uint4*)&As[mloc * 40 + kq] = v;
            *(uint4*)&Bs[mloc * 40 + kq] =
                *(const uint4*)((const unsigned short*)WTr2 + (size_t)(col0 + mloc) * DD + k0 + kq);
            __syncthreads();
            short8 af[2], bw[4];
            #pragma unroll
            for (int mf = 0; mf < 2; mf++)
                af[mf] = *(const short8*)&As[(wr * 32 + mf * 16 + fr) * 40 + ko];
            #pragma unroll
            for (int nf = 0; nf < 4; nf++)
                bw[nf] = *(const short8*)&Bs[(wc * 64 + nf * 16 + fr) * 40 + ko];
            #pragma unroll
            for (int mf = 0; mf < 2; mf++)
                #pragma unroll
                for (int nf = 0; nf < 4; nf++)
                    acc[mf][nf] = __builtin_amdgcn_mfma_f32_16x16x32_bf16(af[mf], bw[nf], acc[mf][nf], 0, 0, 0);
            __syncthreads();
        }
        #pragma unroll
        for (int mf = 0; mf < 2; mf++)
            #pragma unroll
            for (int i = 0; i < 4; i++) {
                int ml = wr * 32 + mf * 16 + (lane >> 4) * 4 + i;
                int gm = row0 + ml;
                if (gm >= NE) continue;
                #pragma unroll
                for (int nf = 0; nf < 4; nf++) {
                    int gc = col0 + wc * 64 + nf * 16 + fr;
                    TRo[(size_t)gm * DD + gc] = __float2bfloat16(acc[mf][nf][i]);
                }
            }
    } else {
        const int bx = blockIdx.x - trblocks;
        const int row0 = bx * 128;
        const int wr = w >> 2, wc = w & 3;
        const int mg = row0 + mloc;
        int eb = 0, ee = 0;
        if (mg < NN) { eb = offN[mg]; ee = offN[mg + 1]; }
        f32x4 acc[4][4] = {};
        for (int k0 = 0; k0 < 512; k0 += 32) {
            const int kg = k0 + kq;
            uint4 v = {0, 0, 0, 0};
            if (mg < NN) {
                if (kg < 256) {
                    v = *(const uint4*)((const unsigned short*)MN + (size_t)mg * DD + kg);
                } else {
                    const int kk = kg - 256;
                    float a[8] = {0, 0, 0, 0, 0, 0, 0, 0};
                    for (int t = eb; t < ee; t++) {
                        int src = agLst[t];
                        float m8[8];
                        unp8(*(const short8*)((const unsigned short*)MBn + (size_t)src * DD + kk), m8);
                        #pragma unroll
                        for (int j = 0; j < 8; j++) a[j] += m8[j];
                    }
                    v = pk8(a);
                }
            }
            *(uint4*)&As[mloc * 40 + kq] = v;
            #pragma unroll
            for (int it = 0; it < 2; ++it) {
                int nloc = (tid >> 2) + it * 128;
                *(uint4*)&Bs[nloc * 40 + kq] =
                    *(const uint4*)((const unsigned short*)WTnu + (size_t)nloc * 512 + k0 + kq);
            }
            __syncthreads();
            short8 af[4], bw[4];
            #pragma unroll
            for (int mf = 0; mf < 4; mf++)
                af[mf] = *(const short8*)&As[(wr * 64 + mf * 16 + fr) * 40 + ko];
            #pragma unroll
            for (int nf = 0; nf < 4; nf++)
                bw[nf] = *(const short8*)&Bs[(wc * 64 + nf * 16 + fr) * 40 + ko];
            #pragma unroll
            for (int mf = 0; mf < 4; mf++)
                #pragma unroll
                for (int nf = 0; nf < 4; nf++)
                    acc[mf][nf] = __builtin_amdgcn_mfma_f32_16x16x32_bf16(af[mf], bw[nf], acc[mf][nf], 0, 0, 0);
            __syncthreads();
        }
        #pragma unroll
        for (int mf = 0; mf < 4; mf++)
            #pragma unroll
            for (int i = 0; i < 4; i++) {
                int ml = wr * 64 + mf * 16 + (lane >> 4) * 4 + i;
                int gm = row0 + ml;
                if (gm >= NN) continue;
                #pragma unroll
                for (int nf = 0; nf < 4; nf++) {
                    int gc = wc * 64 + nf * 16 + fr;
                    size_t idx = (size_t)gm * DD + gc;
                    MNout[idx] = __float2bfloat16(
                        hswish(acc[mf][nf][i] + __bfloat162float(PN[idx])));
                }
            }
    }
}

// ---------------- bg_body: unified MFMA GEMM as device function ---------
// EPB: 0 lin(+b1)->bf16; 2 dual hsw/lin; 3 dual lin/lin; 6 hsw->f32
template <int BN, int NT, int DUAL, int EPB>
__device__ __forceinline__ void bg_body(
    const void* __restrict__ A1, int a1stride, int a1kw, int a1real, int a1f32,
    const void* __restrict__ A2, int a2stride, int a2kw, int a2real, int a2f32,
    const bf16* __restrict__ WT1, const bf16* __restrict__ WT2, int KT,
    const float* __restrict__ bias1, const float* __restrict__ bias2,
    void* __restrict__ out1, void* __restrict__ out2, int M,
    int row0, int col0,
    unsigned short* As, unsigned short* Bs, unsigned short* Bs2)
{
    constexpr int BM = 128;
    constexpr int nWc = BN / 64;
    constexpr int nWr = (NT / 64) / nWc;
    constexpr int MSPAN = BM / nWr;
    constexpr int MFR = MSPAN / 16;
    const int tid = threadIdx.x;
    const int lane = tid & 63, w = tid >> 6;
    const int wr = w / nWc, wc = w % nWc;
    const int fr = lane & 15, ko = (lane >> 4) * 8;

    f32x4 acc[MFR][4] = {};
    f32x4 acc2[DUAL ? MFR : 1][DUAL ? 4 : 1] = {};

    for (int k0 = 0; k0 < KT; k0 += 32) {
        #pragma unroll
        for (int it = 0; it < BM * 4 / NT; ++it) {
            int mloc = (tid >> 2) + it * (NT / 4);
            int mg = row0 + mloc;
            bool mok = (mg < M);
            int kq = (tid & 3) * 8;
            int kg = k0 + kq;
            const void* p; int stride, real, isf; int kk;
            if (kg < a1kw) { p = A1; stride = a1stride; real = a1real; isf = a1f32; kk = kg; }
            else           { p = A2; stride = a2stride; real = a2real; isf = a2f32; kk = kg - a1kw; }
            uint4 v = {0, 0, 0, 0};
            if (mok) {
                if (!isf) {
                    v = *(const uint4*)((const bf16*)p + (size_t)mg * stride + kk);
                } else {
                    const float* fp = (const float*)p + (size_t)mg * stride;
                    unsigned short us[8];
                    #pragma unroll
                    for (int j = 0; j < 8; j++)
                        us[j] = (kk + j < real) ? f2bf(fp[kk + j]) : (unsigned short)0;
                    v.x = us[0] | ((unsigned)us[1] << 16);
                    v.y = us[2] | ((unsigned)us[3] << 16);
                    v.z = us[4] | ((unsigned)us[5] << 16);
                    v.w = us[6] | ((unsigned)us[7] << 16);
                }
            }
            *(uint4*)&As[mloc * 40 + kq] = v;
        }
        #pragma unroll
        for (int it = 0; it < BN * 4 / NT; ++it) {
            int nloc = (tid >> 2) + it * (NT / 4);
            int kq = (tid & 3) * 8;
            *(uint4*)&Bs[nloc * 40 + kq] =
                *(const uint4*)&WT1[(size_t)(col0 + nloc) * KT + k0 + kq];
            if (DUAL)
                *(uint4*)&Bs2[nloc * 40 + kq] =
                    *(const uint4*)&WT2[(size_t)(col0 + nloc) * KT + k0 + kq];
        }
        __syncthreads();
        short8 a1f[MFR], b1f[4], b2f[DUAL ? 4 : 1];
        #pragma unroll
        for (int mf = 0; mf < MFR; mf++)
            a1f[mf] = *(const short8*)&As[(wr * MSPAN + mf * 16 + fr) * 40 + ko];
        #pragma unroll
        for (int nf = 0; nf < 4; nf++) {
            b1f[nf] = *(const short8*)&Bs[(wc * 64 + nf * 16 + fr) * 40 + ko];
            if (DUAL)
                b2f[nf] = *(const short8*)&Bs2[(wc * 64 + nf * 16 + fr) * 40 + ko];
        }
        #pragma unroll
        for (int mf = 0; mf < MFR; mf++)
            #pragma unroll
            for (int nf = 0; nf < 4; nf++) {
                acc[mf][nf] = __builtin_amdgcn_mfma_f32_16x16x32_bf16(a1f[mf], b1f[nf], acc[mf][nf], 0, 0, 0);
                if (DUAL)
                    acc2[mf][nf] = __builtin_amdgcn_mfma_f32_16x16x32_bf16(a1f[mf], b2f[nf], acc2[mf][nf], 0, 0, 0);
            }
        __syncthreads();
    }

    #pragma unroll
    for (int mf = 0; mf < MFR; mf++) {
        #pragma unroll
        for (int i = 0; i < 4; i++) {
            int mloc = wr * MSPAN + mf * 16 + (lane >> 4) * 4 + i;
            int gm = row0 + mloc;
            if (gm >= M) continue;
            #pragma unroll
            for (int nf = 0; nf < 4; nf++) {
                int gc = col0 + wc * 64 + nf * 16 + fr;
                size_t idx = (size_t)gm * DD + gc;
                float v = acc[mf][nf][i];
                if (EPB == 0) {
                    if (bias1) v += bias1[gc];
                    ((bf16*)out1)[idx] = __float2bfloat16(v);
                } else if (EPB == 2) {
                    ((bf16*)out1)[idx] = __float2bfloat16(hswish(v + bias1[gc]));
                    ((bf16*)out2)[idx] = __float2bfloat16(acc2[mf][nf][i] + bias2[gc]);
                } else if (EPB == 3) {
                    ((bf16*)out1)[idx] = __float2bfloat16(v + bias1[gc]);
                    ((bf16*)out2)[idx] = __float2bfloat16(acc2[mf][nf][i] + bias2[gc]);
                } else {  // EPB == 6
                    ((float*)out1)[idx] = hswish(v + bias1[gc]);
                }
            }
        }
    }
}

// ---- pre_pair1: [PR/PZ (EPB3)] ∥ [MB/PM (EPB2)], both A=IBbf K=160 ----
__global__ __launch_bounds__(512) void pre_pair1(
    const bf16* __restrict__ IBbf,
    const bf16* __restrict__ WTr, const bf16* __restrict__ WTz1,
    const float* __restrict__ b_r, const float* __restrict__ b_z,
    bf16* __restrict__ PR, bf16* __restrict__ PZ,
    const bf16* __restrict__ WTb, const bf16* __restrict__ WTm1,
    const float* __restrict__ b_bond, const float* __restrict__ b_m,
    bf16* __restrict__ MB, bf16* __restrict__ PM)
{
    __shared__ __align__(16) unsigned short As[128 * 40];
    __shared__ __align__(16) unsigned short Bs[128 * 40];
    __shared__ __align__(16) unsigned short Bs2[128 * 40];
    int b = blockIdx.x;
    if (b < 3126) {
        int bx = b % 1563, by = b / 1563;
        bg_body<128, 512, 1, 3>(IBbf, 160, 160, 160, 0, nullptr, 0, 0, 0, 0,
            WTr, WTz1, 160, b_r, b_z, PR, PZ, NE, bx * 128, by * 128, As, Bs, Bs2);
    } else {
        int b2 = b - 3126;
        int bx = b2 % 1563, by = b2 / 1563;
        bg_body<128, 512, 1, 2>(IBbf, 160, 160, 160, 0, nullptr, 0, 0, 0, 0,
            WTb, WTm1, 160, b_bond, b_m, MB, PM, NE, bx * 128, by * 128, As, Bs, Bs2);
    }
}

// ---- pre_pair2: [MN/PN (EPB2, A=node f32)] ∥ [TR0 = MB@w_r2 (EPB0)] ---
__global__ __launch_bounds__(512) void pre_pair2(
    const float* __restrict__ node,
    const bf16* __restrict__ WTn0, const bf16* __restrict__ WTn,
    const float* __restrict__ b_node, const float* __restrict__ b_n,
    bf16* __restrict__ MN, bf16* __restrict__ PN,
    const bf16* __restrict__ MB, const bf16* __restrict__ WTr2,
    bf16* __restrict__ TR)
{
    __shared__ __align__(16) unsigned short As[128 * 40];
    __shared__ __align__(16) unsigned short Bs[128 * 40];
    __shared__ __align__(16) unsigned short Bs2[128 * 40];
    int b = blockIdx.x;
    if (b < 1564) {
        int bx = b % 782, by = b / 782;
        bg_body<128, 512, 1, 2>(node, FN, 160, FN, 1, nullptr, 0, 0, 0, 0,
            WTn0, WTn, 160, b_node, b_n, MN, PN, NN, bx * 128, by * 128, As, Bs, Bs2);
    } else {
        int b2 = b - 1564;
        int bx = b2 % 1563, by = b2 / 1563;
        bg_body<128, 512, 0, 0>(MB, 256, 256, 256, 0, nullptr, 0, 0, 0, 0,
            WTr2, nullptr, 256, nullptr, nullptr, TR, nullptr, NE,
            bx * 128, by * 128, As, Bs, Bs2);
    }
}

// ---- final_pair: [bond final -> f32 out_bond] ∥ [node final -> scratch]
__global__ __launch_bounds__(512) void final_pair(
    const bf16* __restrict__ IBbf, const bf16* __restrict__ MB,
    const bf16* __restrict__ WTbf, const float* __restrict__ b_bf,
    float* __restrict__ out_bond,
    const float* __restrict__ node, const bf16* __restrict__ MN,
    const bf16* __restrict__ WTnf, const float* __restrict__ b_nf,
    float* __restrict__ scratchN)
{
    __shared__ __align__(16) unsigned short As[128 * 40];
    __shared__ __align__(16) unsigned short Bs[256 * 40];
    __shared__ __align__(16) unsigned short Bs2[8 * 40];
    int b = blockIdx.x;
    if (b < 1563) {
        bg_body<256, 512, 0, 6>(IBbf, 160, 160, 160, 0, MB, 256, 256, 256, 0,
            WTbf, nullptr, 416, b_bf, nullptr, out_bond, nullptr, NE,
            b * 128, 0, As, Bs, Bs2);
    } else {
        bg_body<256, 512, 0, 6>(node, FN, 160, FN, 1, MN, 256, 256, 256, 0,
            WTnf, nullptr, 416, b_nf, nullptr, scratchN, nullptr, NN,
            (b - 1563) * 128, 0, As, Bs, Bs2);
    }
}

extern "C" void kernel_launch(void* const* d_in, const int* in_sizes, int n_in,
                              void* d_out, int out_size, void* d_ws, size_t ws_size,
                              hipStream_t stream)
{
    const float* node  = (const float*)d_in[0];
    const float* bond  = (const float*)d_in[1];
    const int* connect = (const int*)d_in[2];
    const int* bnb     = (const int*)d_in[3];
    const float* w_node       = (const float*)d_in[4];
    const float* b_node       = (const float*)d_in[5];
    const float* w_node_final = (const float*)d_in[6];
    const float* b_node_final = (const float*)d_in[7];
    const float* w_bond       = (const float*)d_in[8];
    const float* b_bond       = (const float*)d_in[9];
    const float* w_bond_final = (const float*)d_in[10];
    const float* b_bond_final = (const float*)d_in[11];
    const float* w_z = (const float*)d_in[12];
    const float* b_z = (const float*)d_in[13];
    const float* w_r = (const float*)d_in[14];
    const float* b_r = (const float*)d_in[15];
    const float* u_  = (const float*)d_in[16];
    const float* w_m = (const float*)d_in[17];
    const float* b_m = (const float*)d_in[18];
    const float* w_n = (const float*)d_in[19];
    const float* b_n = (const float*)d_in[20];
    const float* u_n = (const float*)d_in[21];

    const int* i_idx = connect;
    const int* j_idx = connect + NE;
    const int* ij    = bnb;
    const int* ki    = bnb + NB;

    const size_t EBH = (size_t)NE * DD * 2;        // 102,400,000
    const size_t B_WT = (size_t)786432 * 2;        // 1.57 MB packed weights
    const size_t B_CSR = (size_t)NEPAD * 8 + (size_t)NB * 4
                       + (size_t)NNPAD * 8 + (size_t)NE * 4 + 2048;
    const size_t NEED = 5 * EBH + B_WT + B_CSR;    // ~519.4 MB (known to fit)

    float* out_node = (float*)d_out;
    float* out_bond = out_node + (size_t)NN * DD;

    if (ws_size < NEED) {
        fill_kernel<<<2048, 256, 0, stream>>>((float*)d_out, 1e6f, (long)out_size / 4);
        return;
    }

    char* base = (char*)d_ws;
    bf16* PR = (bf16*)base;                       base += EBH;
    bf16* MB = (bf16*)base;                       base += EBH;
    bf16* TR = (bf16*)base;                       base += EBH;   // also IBbf / final-node scratch
    bf16* PZ = (bf16*)base;                       base += EBH;
    bf16* PM = (bf16*)base;                       base += EBH;
    char* wt = base;                              base += B_WT;
    int* offE  = (int*)base;                      base += (size_t)NEPAD * 4;
    int* curE  = (int*)base;                      base += (size_t)NEPAD * 4;
    int* nbLst = (int*)base;                      base += (size_t)NB * 4;
    int* offN  = (int*)base;                      base += (size_t)NNPAD * 4;
    int* curN  = (int*)base;                      base += (size_t)NNPAD * 4;
    int* agLst = (int*)base;                      base += (size_t)NE * 4;
    int* bsumE = (int*)base;                      base += 1024;
    int* bsumN = (int*)base;

    bf16* IBbf = TR;
    float* scratchN = (float*)TR;
    bf16* R = (bf16*)out_bond;
    bf16* S = R + (size_t)NE * DD;
    bf16* MN = (bf16*)out_node;
    bf16* PN = MN + (size_t)NN * DD;

    // packed-weight layout (elements) — must match pack_all
    bf16* wtb = (bf16*)wt;
    bf16* WTr  = wtb + 0;
    bf16* WTz1 = wtb + 40960;
    bf16* WTb  = wtb + 81920;
    bf16* WTm1 = wtb + 122880;
    bf16* WTn0 = wtb + 163840;
    bf16* WTn  = wtb + 204800;
    bf16* WTr2 = wtb + 245760;
    bf16* WTz2 = wtb + 311296;
    bf16* WTu  = wtb + 376832;
    bf16* WTnu = wtb + 442368;
    bf16* WTbf = wtb + 573440;
    bf16* WTnf = wtb + 679936;

    // ---- single-launch weight pack ----
    pack_all<<<3072, 256, 0, stream>>>(w_r, w_z, w_bond, w_m, w_node, w_n,
                                       u_, u_n, w_bond_final, w_node_final, wtb);

    // ---- merged CSR build (7 launches) ----
    zero2_kernel<<<(NEPAD + NNPAD + 255) / 256, 256, 0, stream>>>(offE, offN);
    count2_kernel<<<(NB + NE + 255) / 256, 256, 0, stream>>>(ij, j_idx, offE, offN);
    scan_block2<<<294, 256, 0, stream>>>(offE, offN, bsumE, bsumN);
    scan_bsum2<<<2, 256, 0, stream>>>(bsumE, bsumN);
    scan_add2<<<(NEPAD + NNPAD + 255) / 256, 256, 0, stream>>>(offE, offN, bsumE, bsumN);
    copy2_kernel<<<(NEPAD + NNPAD + 255) / 256, 256, 0, stream>>>(curE, curN, offE, offN);
    lists2_kernel<<<(NB + NE + 255) / 256, 256, 0, stream>>>(ij, ki, j_idx,
                                                             curE, curN, nbLst, agLst);

    int blkIB = NE * 64 / 256;
    dim3 gB2(1563, 2);

    // ---- pre-loop: IB once, paired hoist GEMMs ----
    build_ib_bf<<<blkIB, 256, 0, stream>>>(node, bond, i_idx, IBbf);
    pre_pair1<<<6252, 512, 0, stream>>>(IBbf, WTr, WTz1, b_r, b_z, PR, PZ,
                                        WTb, WTm1, b_bond, b_m, MB, PM);
    pre_pair2<<<4690, 512, 0, stream>>>(node, WTn0, WTn, b_node, b_n, MN, PN,
                                        MB, WTr2, TR);

    for (int l = 0; l < 3; l++) {
        seg_sr_kernel<<<(NE + 3) / 4, 256, 0, stream>>>(MB, TR, PR, offE, nbLst, S, R);
        blend2<<<gB2, 512, 0, stream>>>(S, R, WTz2, WTu, PZ, PM, MB);
        int trb = (l < 2) ? 3126 : 0;
        pairk<<<trb + 782, 512, 0, stream>>>(trb, MB, WTr2, TR,
                                             MN, offN, agLst, WTnu, PN, MN);
    }

    // ---- finals ----
    build_ib_bf<<<blkIB, 256, 0, stream>>>(node, bond, i_idx, IBbf);
    final_pair<<<2345, 512, 0, stream>>>(IBbf, MB, WTbf, b_bond_final, out_bond,
                                         node, MN, WTnf, b_node_final, scratchN);
    hipMemcpyAsync(out_node, scratchN, (size_t)NN * DD * 4,
                   hipMemcpyDeviceToDevice, stream);
}

// Round 13
// 2469.438 us; speedup vs baseline: 1.4142x; 1.0053x over previous
//
#include <hip/hip_runtime.h>
#include <hip/hip_bf16.h>

#define NN 100000   // nodes
#define NE 200000   // bonds
#define NB 600000   // bond neighbours
#define FN 133
#define FB 14
#define FIB 147     // FN+FB
#define DD 256
#define NEPAD (196 * 1024)
#define NNPAD (98 * 1024)

typedef __hip_bfloat16 bf16;
typedef __attribute__((ext_vector_type(8))) short short8;   // 8 bf16 = 4 VGPR
typedef __attribute__((ext_vector_type(4))) float f32x4;

__device__ __forceinline__ float hswish(float x) {
    float c = fminf(fmaxf(x + 3.f, 0.f), 6.f);
    return x * c * (1.f / 6.f);
}
__device__ __forceinline__ float sigmoidf(float x) {
    return 1.f / (1.f + __expf(-x));
}
__device__ __forceinline__ float tanh_fast(float x) {
    return 1.f - 2.f / (1.f + __expf(2.f * x));
}
__device__ __forceinline__ float bf2f(unsigned short u) {
    union { unsigned int i; float f; } c; c.i = (unsigned int)u << 16; return c.f;
}
__device__ __forceinline__ unsigned short f2bf(float v) {
    bf16 b = __float2bfloat16(v);
    unsigned short u; __builtin_memcpy(&u, &b, 2); return u;
}
__device__ __forceinline__ void unp8(short8 v, float* f) {
    #pragma unroll
    for (int j = 0; j < 8; j++) {
        short s = v[j]; unsigned short u; __builtin_memcpy(&u, &s, 2);
        f[j] = bf2f(u);
    }
}
__device__ __forceinline__ uint4 pk8(const float* f) {
    uint4 v;
    v.x = f2bf(f[0]) | ((unsigned)f2bf(f[1]) << 16);
    v.y = f2bf(f[2]) | ((unsigned)f2bf(f[3]) << 16);
    v.z = f2bf(f[4]) | ((unsigned)f2bf(f[5]) << 16);
    v.w = f2bf(f[6]) | ((unsigned)f2bf(f[7]) << 16);
    return v;
}

// ---------------- fill (ws-guard sentinel only) -------------------------
__global__ __launch_bounds__(256) void fill_kernel(float* __restrict__ p, float v, long n4) {
    long i = (long)blockIdx.x * 256 + threadIdx.x;
    long st = (long)gridDim.x * 256;
    float4 z = {v, v, v, v};
    for (; i < n4; i += st) ((float4*)p)[i] = z;
}

// ---------------- IB build: IBbf[e][160] = [node[i_idx[e]] | bond[e] | 0]
__global__ __launch_bounds__(256) void build_ib_bf(
    const float* __restrict__ node, const float* __restrict__ bond,
    const int* __restrict__ i_idx, bf16* __restrict__ IB)
{
    int t = blockIdx.x * 256 + threadIdx.x;
    int row = t >> 6;
    if (row >= NE) return;
    int lane = t & 63;
    if (lane >= 40) return;
    int src = i_idx[row];
    int c = lane * 4;
    unsigned short us[4];
    #pragma unroll
    for (int j = 0; j < 4; j++) {
        int k = c + j;
        float v = 0.f;
        if (k < FN)       v = node[(size_t)src * FN + k];
        else if (k < FIB) v = bond[(size_t)row * FB + (k - FN)];
        us[j] = f2bf(v);
    }
    ushort4 o = {us[0], us[1], us[2], us[3]};
    *(ushort4*)((unsigned short*)IB + (size_t)row * 160 + c) = o;
}

// ---------------- merged CSR build (E and N in one pass each) -----------
__global__ __launch_bounds__(256) void zero2_kernel(int* __restrict__ offE, int* __restrict__ offN)
{
    int i = blockIdx.x * 256 + threadIdx.x;
    if (i < NEPAD) offE[i] = 0;
    else if (i < NEPAD + NNPAD) offN[i - NEPAD] = 0;
}

__global__ __launch_bounds__(256) void count2_kernel(
    const int* __restrict__ ij, const int* __restrict__ jidx,
    int* __restrict__ offE, int* __restrict__ offN)
{
    int i = blockIdx.x * 256 + threadIdx.x;
    if (i < NB) atomicAdd(&offE[ij[i]], 1);
    else if (i < NB + NE) atomicAdd(&offN[jidx[i - NB]], 1);
}

__global__ __launch_bounds__(256) void scan_block2(
    int* __restrict__ offE, int* __restrict__ offN,
    int* __restrict__ bsumE, int* __restrict__ bsumN)
{
    __shared__ int lds[256];
    int* data; int* bs; int bb;
    if ((int)blockIdx.x < 196) { data = offE; bs = bsumE; bb = blockIdx.x; }
    else                       { data = offN; bs = bsumN; bb = blockIdx.x - 196; }
    int base = bb * 1024 + threadIdx.x * 4;
    int c0 = data[base], c1 = data[base + 1], c2 = data[base + 2], c3 = data[base + 3];
    int t = c0 + c1 + c2 + c3;
    lds[threadIdx.x] = t;
    __syncthreads();
    int x = t;
    for (int off = 1; off < 256; off <<= 1) {
        int y = (threadIdx.x >= off) ? lds[threadIdx.x - off] : 0;
        __syncthreads();
        x += y; lds[threadIdx.x] = x;
        __syncthreads();
    }
    int excl = x - t;
    data[base] = excl; data[base + 1] = excl + c0;
    data[base + 2] = excl + c0 + c1; data[base + 3] = excl + c0 + c1 + c2;
    if (threadIdx.x == 255) bs[bb] = x;
}

__global__ __launch_bounds__(256) void scan_bsum2(int* __restrict__ bsumE, int* __restrict__ bsumN)
{
    __shared__ int lds[256];
    int* bs = blockIdx.x ? bsumN : bsumE;
    int n = blockIdx.x ? 98 : 196;
    int t = (threadIdx.x < n) ? bs[threadIdx.x] : 0;
    lds[threadIdx.x] = t;
    __syncthreads();
    int x = t;
    for (int off = 1; off < 256; off <<= 1) {
        int y = (threadIdx.x >= off) ? lds[threadIdx.x - off] : 0;
        __syncthreads();
        x += y; lds[threadIdx.x] = x;
        __syncthreads();
    }
    if (threadIdx.x < n) bs[threadIdx.x] = x - t;
}

// merged scan_add + copy (offX finalized and mirrored into curX)
__global__ __launch_bounds__(256) void scan_add_copy2(
    int* __restrict__ offE, int* __restrict__ offN,
    const int* __restrict__ bsumE, const int* __restrict__ bsumN,
    int* __restrict__ curE, int* __restrict__ curN)
{
    int i = blockIdx.x * 256 + threadIdx.x;
    if (i < NEPAD) {
        int v = offE[i] + bsumE[i >> 10];
        offE[i] = v; curE[i] = v;
    } else if (i < NEPAD + NNPAD) {
        int j = i - NEPAD;
        int v = offN[j] + bsumN[j >> 10];
        offN[j] = v; curN[j] = v;
    }
}

__global__ __launch_bounds__(256) void lists2_kernel(
    const int* __restrict__ ij, const int* __restrict__ ki, const int* __restrict__ jidx,
    int* __restrict__ curE, int* __restrict__ curN,
    int* __restrict__ nbLst, int* __restrict__ agLst)
{
    int i = blockIdx.x * 256 + threadIdx.x;
    if (i < NB) { int p = atomicAdd(&curE[ij[i]], 1); nbLst[p] = ki[i]; }
    else if (i < NB + NE) {
        int e = i - NB;
        int p = atomicAdd(&curN[jidx[e]], 1); agLst[p] = e;
    }
}

// ------------- single-launch weight pack (fixed layout, 786432 elems) ---
__global__ __launch_bounds__(256) void pack_all(
    const float* __restrict__ w_r, const float* __restrict__ w_z,
    const float* __restrict__ w_bond, const float* __restrict__ w_m,
    const float* __restrict__ w_node, const float* __restrict__ w_n,
    const float* __restrict__ u_, const float* __restrict__ u_n,
    const float* __restrict__ w_bf, const float* __restrict__ w_nf,
    bf16* __restrict__ wt)
{
    int idx = blockIdx.x * 256 + threadIdx.x;
    if (idx >= 786432) return;
    float v = 0.f;
    if (idx < 245760) {
        int r = idx / 40960;
        int loc = idx - r * 40960;
        int n = loc / 160, k = loc % 160;
        const float* W = (r == 0) ? w_r : (r == 1) ? w_z : (r == 2) ? w_bond
                       : (r == 3) ? w_m : (r == 4) ? w_node : w_n;
        int K1 = (r < 4) ? FIB : FN;
        if (k < K1) v = W[(size_t)k * DD + n];
    } else if (idx < 442368) {
        int r = (idx - 245760) / 65536;
        int loc = (idx - 245760) - r * 65536;
        int n = loc / 256, k = loc % 256;
        const float* W = (r == 0) ? (w_r + (size_t)FIB * DD)
                       : (r == 1) ? (w_z + (size_t)FIB * DD) : u_;
        v = W[(size_t)k * DD + n];
    } else if (idx < 573440) {
        int loc = idx - 442368;
        int n = loc / 512, k = loc % 512;
        v = u_n[(size_t)k * DD + n];
    } else {
        int r = (idx - 573440) / 106496;
        int loc = (idx - 573440) - r * 106496;
        int n = loc / 416, k = loc % 416;
        const float* W = r ? w_nf : w_bf;
        int K1 = r ? FN : FIB;
        if (k < K1)        v = W[(size_t)k * DD + n];
        else if (k >= 160) v = W[(size_t)(K1 + k - 160) * DD + n];
    }
    wt[idx] = __float2bfloat16(v);
}

// -------- fused seg_s + seg_r: one CSR walk, one MB gather pass ---------
__global__ __launch_bounds__(256) void seg_sr_kernel(
    const bf16* __restrict__ MB, const bf16* __restrict__ TR,
    const bf16* __restrict__ PR, const int* __restrict__ off,
    const int* __restrict__ lst,
    bf16* __restrict__ S, bf16* __restrict__ R)
{
    int sid = blockIdx.x * 4 + (threadIdx.x >> 6);
    if (sid >= NE) return;
    int lane = threadIdx.x & 63;
    ushort4 up = *(const ushort4*)((const unsigned short*)PR + (size_t)sid * DD + lane * 4);
    float p0 = bf2f(up.x), p1 = bf2f(up.y), p2 = bf2f(up.z), p3 = bf2f(up.w);
    int b = off[sid], e = off[sid + 1];
    float s0 = 0, s1 = 0, s2 = 0, s3 = 0;
    float r0 = 0, r1 = 0, r2 = 0, r3 = 0;
    for (int t = b; t < e; t++) {
        int src = lst[t];
        ushort4 um = *(const ushort4*)((const unsigned short*)MB + (size_t)src * DD + lane * 4);
        ushort4 ut = *(const ushort4*)((const unsigned short*)TR + (size_t)src * DD + lane * 4);
        float m0 = bf2f(um.x), m1 = bf2f(um.y), m2 = bf2f(um.z), m3 = bf2f(um.w);
        s0 += m0; s1 += m1; s2 += m2; s3 += m3;
        r0 += sigmoidf(p0 + bf2f(ut.x)) * m0;
        r1 += sigmoidf(p1 + bf2f(ut.y)) * m1;
        r2 += sigmoidf(p2 + bf2f(ut.z)) * m2;
        r3 += sigmoidf(p3 + bf2f(ut.w)) * m3;
    }
    ushort4 os = {f2bf(s0), f2bf(s1), f2bf(s2), f2bf(s3)};
    ushort4 orr = {f2bf(r0), f2bf(r1), f2bf(r2), f2bf(r3)};
    *(ushort4*)((unsigned short*)S + (size_t)sid * DD + lane * 4) = os;
    *(ushort4*)((unsigned short*)R + (size_t)sid * DD + lane * 4) = orr;
}

// ======== blend2: two sequential K=256 GEMM phases, k-step 64 ===========
__global__ __launch_bounds__(512) void blend2(
    const bf16* __restrict__ S, const bf16* __restrict__ R,
    const bf16* __restrict__ WTz2, const bf16* __restrict__ WTu,
    const bf16* __restrict__ PZ, const bf16* __restrict__ PM,
    bf16* __restrict__ MB)
{
    __shared__ __align__(16) unsigned short As[128 * 72];   // 18.4 KB
    __shared__ __align__(16) unsigned short Bs[128 * 72];   // 18.4 KB
    const int tid = threadIdx.x;
    const int row0 = blockIdx.x * 128, col0 = blockIdx.y * 128;
    const int lane = tid & 63, w = tid >> 6;
    const int wr = w >> 1, wc = w & 1;
    const int fr = lane & 15, ko = (lane >> 4) * 8;

    f32x4 acc1[2][4] = {};
    f32x4 acc2[2][4] = {};

    #pragma unroll
    for (int ph = 0; ph < 2; ph++) {
        const bf16* A = (ph == 0) ? S : R;
        const bf16* W = (ph == 0) ? WTz2 : WTu;
        for (int k0 = 0; k0 < DD; k0 += 64) {
            {
                int mloc = tid >> 2, kq = (tid & 3) * 16;
                int mg = row0 + mloc;
                uint4 va = {0, 0, 0, 0}, va2 = {0, 0, 0, 0};
                if (mg < NE) {
                    va  = *(const uint4*)((const unsigned short*)A + (size_t)mg * DD + k0 + kq);
                    va2 = *(const uint4*)((const unsigned short*)A + (size_t)mg * DD + k0 + kq + 8);
                }
                uint4 vb  = *(const uint4*)((const unsigned short*)W + (size_t)(col0 + mloc) * DD + k0 + kq);
                uint4 vb2 = *(const uint4*)((const unsigned short*)W + (size_t)(col0 + mloc) * DD + k0 + kq + 8);
                *(uint4*)&As[mloc * 72 + kq] = va;
                *(uint4*)&As[mloc * 72 + kq + 8] = va2;
                *(uint4*)&Bs[mloc * 72 + kq] = vb;
                *(uint4*)&Bs[mloc * 72 + kq + 8] = vb2;
            }
            __syncthreads();
            #pragma unroll
            for (int kk = 0; kk < 64; kk += 32) {
                short8 af[2], bf8[4];
                #pragma unroll
                for (int mf = 0; mf < 2; mf++)
                    af[mf] = *(const short8*)&As[(wr * 32 + mf * 16 + fr) * 72 + kk + ko];
                #pragma unroll
                for (int nf = 0; nf < 4; nf++)
                    bf8[nf] = *(const short8*)&Bs[(wc * 64 + nf * 16 + fr) * 72 + kk + ko];
                #pragma unroll
                for (int mf = 0; mf < 2; mf++)
                    #pragma unroll
                    for (int nf = 0; nf < 4; nf++) {
                        if (ph == 0)
                            acc1[mf][nf] = __builtin_amdgcn_mfma_f32_16x16x32_bf16(af[mf], bf8[nf], acc1[mf][nf], 0, 0, 0);
                        else
                            acc2[mf][nf] = __builtin_amdgcn_mfma_f32_16x16x32_bf16(af[mf], bf8[nf], acc2[mf][nf], 0, 0, 0);
                    }
            }
            __syncthreads();
        }
    }

    #pragma unroll
    for (int mf = 0; mf < 2; mf++) {
        #pragma unroll
        for (int i = 0; i < 4; i++) {
            int mloc = wr * 32 + mf * 16 + (lane >> 4) * 4 + i;
            int gm = row0 + mloc;
            if (gm >= NE) continue;
            #pragma unroll
            for (int nf = 0; nf < 4; nf++) {
                int gc = col0 + wc * 64 + nf * 16 + fr;
                size_t idx = (size_t)gm * DD + gc;
                float z  = sigmoidf(acc1[mf][nf][i] + __bfloat162float(PZ[idx]));
                float mm = tanh_fast(acc2[mf][nf][i] + __bfloat162float(PM[idx]));
                float s  = __bfloat162float(S[idx]);
                MB[idx] = __float2bfloat16((1.f - z) * s + z * mm);
            }
        }
    }
}

// ======== pairk: [TR-GEMM blocks] ∥ [node-update blocks w/ fused AGG] ====
__global__ __launch_bounds__(512) void pairk(
    int trblocks,
    const bf16* __restrict__ MBn, const bf16* __restrict__ WTr2,
    bf16* __restrict__ TRo,
    const bf16* __restrict__ MN, const int* __restrict__ offN,
    const int* __restrict__ agLst, const bf16* __restrict__ WTnu,
    const bf16* __restrict__ PN, bf16* __restrict__ MNout)
{
    __shared__ __align__(16) unsigned short As[128 * 40];   // 10 KB
    __shared__ __align__(16) unsigned short Bs[256 * 40];   // 20 KB
    const int tid = threadIdx.x, lane = tid & 63, w = tid >> 6;
    const int fr = lane & 15, ko = (lane >> 4) * 8;
    const int mloc = tid >> 2, kq = (tid & 3) * 8;

    if ((int)blockIdx.x < trblocks) {
        const int bx = blockIdx.x % 1563, by = blockIdx.x / 1563;
        const int row0 = bx * 128, col0 = by * 128;
        const int wr = w >> 1, wc = w & 1;
        const int mg = row0 + mloc;
        f32x4 acc[2][4] = {};
        for (int k0 = 0; k0 < 256; k0 += 32) {
            uint4 v = {0, 0, 0, 0};
            if (mg < NE)
                v = *(const uint4*)((const unsigned short*)MBn + (size_t)mg * DD + k0 + kq);
            *(uint4*)&As[mloc * 40 + kq] = v;
            *(uint4*)&Bs[mloc * 40 + kq] =
                *(const uint4*)((const unsigned short*)WTr2 + (size_t)(col0 + mloc) * DD + k0 + kq);
            __syncthreads();
            short8 af[2], bw[4];
            #pragma unroll
            for (int mf = 0; mf < 2; mf++)
                af[mf] = *(const short8*)&As[(wr * 32 + mf * 16 + fr) * 40 + ko];
            #pragma unroll
            for (int nf = 0; nf < 4; nf++)
                bw[nf] = *(const short8*)&Bs[(wc * 64 + nf * 16 + fr) * 40 + ko];
            #pragma unroll
            for (int mf = 0; mf < 2; mf++)
                #pragma unroll
                for (int nf = 0; nf < 4; nf++)
                    acc[mf][nf] = __builtin_amdgcn_mfma_f32_16x16x32_bf16(af[mf], bw[nf], acc[mf][nf], 0, 0, 0);
            __syncthreads();
        }
        #pragma unroll
        for (int mf = 0; mf < 2; mf++)
            #pragma unroll
            for (int i = 0; i < 4; i++) {
                int ml = wr * 32 + mf * 16 + (lane >> 4) * 4 + i;
                int gm = row0 + ml;
                if (gm >= NE) continue;
                #pragma unroll
                for (int nf = 0; nf < 4; nf++) {
                    int gc = col0 + wc * 64 + nf * 16 + fr;
                    TRo[(size_t)gm * DD + gc] = __float2bfloat16(acc[mf][nf][i]);
                }
            }
    } else {
        const int bx = blockIdx.x - trblocks;
        const int row0 = bx * 128;
        const int wr = w >> 2, wc = w & 3;
        const int mg = row0 + mloc;
        int eb = 0, ee = 0;
        if (mg < NN) { eb = offN[mg]; ee = offN[mg + 1]; }
        f32x4 acc[4][4] = {};
        for (int k0 = 0; k0 < 512; k0 += 32) {
            const int kg = k0 + kq;
            uint4 v = {0, 0, 0, 0};
            if (mg < NN) {
                if (kg < 256) {
                    v = *(const uint4*)((const unsigned short*)MN + (size_t)mg * DD + kg);
                } else {
                    const int kk = kg - 256;
                    float a[8] = {0, 0, 0, 0, 0, 0, 0, 0};
                    for (int t = eb; t < ee; t++) {
                        int src = agLst[t];
                        float m8[8];
                        unp8(*(const short8*)((const unsigned short*)MBn + (size_t)src * DD + kk), m8);
                        #pragma unroll
                        for (int j = 0; j < 8; j++) a[j] += m8[j];
                    }
                    v = pk8(a);
                }
            }
            *(uint4*)&As[mloc * 40 + kq] = v;
            #pragma unroll
            for (int it = 0; it < 2; ++it) {
                int nloc = (tid >> 2) + it * 128;
                *(uint4*)&Bs[nloc * 40 + kq] =
                    *(const uint4*)((const unsigned short*)WTnu + (size_t)nloc * 512 + k0 + kq);
            }
            __syncthreads();
            short8 af[4], bw[4];
            #pragma unroll
            for (int mf = 0; mf < 4; mf++)
                af[mf] = *(const short8*)&As[(wr * 64 + mf * 16 + fr) * 40 + ko];
            #pragma unroll
            for (int nf = 0; nf < 4; nf++)
                bw[nf] = *(const short8*)&Bs[(wc * 64 + nf * 16 + fr) * 40 + ko];
            #pragma unroll
            for (int mf = 0; mf < 4; mf++)
                #pragma unroll
                for (int nf = 0; nf < 4; nf++)
                    acc[mf][nf] = __builtin_amdgcn_mfma_f32_16x16x32_bf16(af[mf], bw[nf], acc[mf][nf], 0, 0, 0);
            __syncthreads();
        }
        #pragma unroll
        for (int mf = 0; mf < 4; mf++)
            #pragma unroll
            for (int i = 0; i < 4; i++) {
                int ml = wr * 64 + mf * 16 + (lane >> 4) * 4 + i;
                int gm = row0 + ml;
                if (gm >= NN) continue;
                #pragma unroll
                for (int nf = 0; nf < 4; nf++) {
                    int gc = wc * 64 + nf * 16 + fr;
                    size_t idx = (size_t)gm * DD + gc;
                    MNout[idx] = __float2bfloat16(
                        hswish(acc[mf][nf][i] + __bfloat162float(PN[idx])));
                }
            }
    }
}

// ---------------- bg_body: unified MFMA GEMM as device function ---------
// EPB: 0 lin(+b1)->bf16; 2 dual hsw/lin; 3 dual lin/lin; 6 hsw->f32
template <int BN, int NT, int DUAL, int EPB>
__device__ __forceinline__ void bg_body(
    const void* __restrict__ A1, int a1stride, int a1kw, int a1real, int a1f32,
    const void* __restrict__ A2, int a2stride, int a2kw, int a2real, int a2f32,
    const bf16* __restrict__ WT1, const bf16* __restrict__ WT2, int KT,
    const float* __restrict__ bias1, const float* __restrict__ bias2,
    void* __restrict__ out1, void* __restrict__ out2, int M,
    int row0, int col0,
    unsigned short* As, unsigned short* Bs, unsigned short* Bs2)
{
    constexpr int BM = 128;
    constexpr int nWc = BN / 64;
    constexpr int nWr = (NT / 64) / nWc;
    constexpr int MSPAN = BM / nWr;
    constexpr int MFR = MSPAN / 16;
    const int tid = threadIdx.x;
    const int lane = tid & 63, w = tid >> 6;
    const int wr = w / nWc, wc = w % nWc;
    const int fr = lane & 15, ko = (lane >> 4) * 8;

    f32x4 acc[MFR][4] = {};
    f32x4 acc2[DUAL ? MFR : 1][DUAL ? 4 : 1] = {};

    for (int k0 = 0; k0 < KT; k0 += 32) {
        #pragma unroll
        for (int it = 0; it < BM * 4 / NT; ++it) {
            int mloc = (tid >> 2) + it * (NT / 4);
            int mg = row0 + mloc;
            bool mok = (mg < M);
            int kq = (tid & 3) * 8;
            int kg = k0 + kq;
            const void* p; int stride, real, isf; int kk;
            if (kg < a1kw) { p = A1; stride = a1stride; real = a1real; isf = a1f32; kk = kg; }
            else           { p = A2; stride = a2stride; real = a2real; isf = a2f32; kk = kg - a1kw; }
            uint4 v = {0, 0, 0, 0};
            if (mok) {
                if (!isf) {
                    v = *(const uint4*)((const bf16*)p + (size_t)mg * stride + kk);
                } else {
                    const float* fp = (const float*)p + (size_t)mg * stride;
                    unsigned short us[8];
                    #pragma unroll
                    for (int j = 0; j < 8; j++)
                        us[j] = (kk + j < real) ? f2bf(fp[kk + j]) : (unsigned short)0;
                    v.x = us[0] | ((unsigned)us[1] << 16);
                    v.y = us[2] | ((unsigned)us[3] << 16);
                    v.z = us[4] | ((unsigned)us[5] << 16);
                    v.w = us[6] | ((unsigned)us[7] << 16);
                }
            }
            *(uint4*)&As[mloc * 40 + kq] = v;
        }
        #pragma unroll
        for (int it = 0; it < BN * 4 / NT; ++it) {
            int nloc = (tid >> 2) + it * (NT / 4);
            int kq = (tid & 3) * 8;
            *(uint4*)&Bs[nloc * 40 + kq] =
                *(const uint4*)&WT1[(size_t)(col0 + nloc) * KT + k0 + kq];
            if (DUAL)
                *(uint4*)&Bs2[nloc * 40 + kq] =
                    *(const uint4*)&WT2[(size_t)(col0 + nloc) * KT + k0 + kq];
        }
        __syncthreads();
        short8 a1f[MFR], b1f[4], b2f[DUAL ? 4 : 1];
        #pragma unroll
        for (int mf = 0; mf < MFR; mf++)
            a1f[mf] = *(const short8*)&As[(wr * MSPAN + mf * 16 + fr) * 40 + ko];
        #pragma unroll
        for (int nf = 0; nf < 4; nf++) {
            b1f[nf] = *(const short8*)&Bs[(wc * 64 + nf * 16 + fr) * 40 + ko];
            if (DUAL)
                b2f[nf] = *(const short8*)&Bs2[(wc * 64 + nf * 16 + fr) * 40 + ko];
        }
        #pragma unroll
        for (int mf = 0; mf < MFR; mf++)
            #pragma unroll
            for (int nf = 0; nf < 4; nf++) {
                acc[mf][nf] = __builtin_amdgcn_mfma_f32_16x16x32_bf16(a1f[mf], b1f[nf], acc[mf][nf], 0, 0, 0);
                if (DUAL)
                    acc2[mf][nf] = __builtin_amdgcn_mfma_f32_16x16x32_bf16(a1f[mf], b2f[nf], acc2[mf][nf], 0, 0, 0);
            }
        __syncthreads();
    }

    #pragma unroll
    for (int mf = 0; mf < MFR; mf++) {
        #pragma unroll
        for (int i = 0; i < 4; i++) {
            int mloc = wr * MSPAN + mf * 16 + (lane >> 4) * 4 + i;
            int gm = row0 + mloc;
            if (gm >= M) continue;
            #pragma unroll
            for (int nf = 0; nf < 4; nf++) {
                int gc = col0 + wc * 64 + nf * 16 + fr;
                size_t idx = (size_t)gm * DD + gc;
                float v = acc[mf][nf][i];
                if (EPB == 0) {
                    if (bias1) v += bias1[gc];
                    ((bf16*)out1)[idx] = __float2bfloat16(v);
                } else if (EPB == 2) {
                    ((bf16*)out1)[idx] = __float2bfloat16(hswish(v + bias1[gc]));
                    ((bf16*)out2)[idx] = __float2bfloat16(acc2[mf][nf][i] + bias2[gc]);
                } else if (EPB == 3) {
                    ((bf16*)out1)[idx] = __float2bfloat16(v + bias1[gc]);
                    ((bf16*)out2)[idx] = __float2bfloat16(acc2[mf][nf][i] + bias2[gc]);
                } else {  // EPB == 6
                    ((float*)out1)[idx] = hswish(v + bias1[gc]);
                }
            }
        }
    }
}

// ---------------- bg64_body: BM=64, BN=256, NT=512, EPB=6 (f32 out) -----
__device__ __forceinline__ void bg64_body(
    const void* __restrict__ A1, int a1stride, int a1kw, int a1real, int a1f32,
    const void* __restrict__ A2, int a2stride, int a2kw, int a2real, int a2f32,
    const bf16* __restrict__ WT1, int KT, const float* __restrict__ bias1,
    float* __restrict__ out1, int M, int row0,
    unsigned short* As, unsigned short* Bs)
{
    // nWc=4, nWr=2, MSPAN=32, MFR=2
    const int tid = threadIdx.x;
    const int lane = tid & 63, w = tid >> 6;
    const int wr = w >> 2, wc = w & 3;
    const int fr = lane & 15, ko = (lane >> 4) * 8;

    f32x4 acc[2][4] = {};

    for (int k0 = 0; k0 < KT; k0 += 32) {
        if (tid < 256) {
            int mloc = tid >> 2, kq = (tid & 3) * 8;
            int mg = row0 + mloc;
            int kg = k0 + kq;
            const void* p; int stride, real, isf; int kk;
            if (kg < a1kw) { p = A1; stride = a1stride; real = a1real; isf = a1f32; kk = kg; }
            else           { p = A2; stride = a2stride; real = a2real; isf = a2f32; kk = kg - a1kw; }
            uint4 v = {0, 0, 0, 0};
            if (mg < M) {
                if (!isf) {
                    v = *(const uint4*)((const bf16*)p + (size_t)mg * stride + kk);
                } else {
                    const float* fp = (const float*)p + (size_t)mg * stride;
                    unsigned short us[8];
                    #pragma unroll
                    for (int j = 0; j < 8; j++)
                        us[j] = (kk + j < real) ? f2bf(fp[kk + j]) : (unsigned short)0;
                    v.x = us[0] | ((unsigned)us[1] << 16);
                    v.y = us[2] | ((unsigned)us[3] << 16);
                    v.z = us[4] | ((unsigned)us[5] << 16);
                    v.w = us[6] | ((unsigned)us[7] << 16);
                }
            }
            *(uint4*)&As[mloc * 40 + kq] = v;
        }
        {
            int kq = (tid & 3) * 8;
            #pragma unroll
            for (int it = 0; it < 2; ++it) {
                int nloc = (tid >> 2) + it * 128;
                *(uint4*)&Bs[nloc * 40 + kq] =
                    *(const uint4*)&WT1[(size_t)nloc * KT + k0 + kq];
            }
        }
        __syncthreads();
        short8 af[2], bw[4];
        #pragma unroll
        for (int mf = 0; mf < 2; mf++)
            af[mf] = *(const short8*)&As[(wr * 32 + mf * 16 + fr) * 40 + ko];
        #pragma unroll
        for (int nf = 0; nf < 4; nf++)
            bw[nf] = *(const short8*)&Bs[(wc * 64 + nf * 16 + fr) * 40 + ko];
        #pragma unroll
        for (int mf = 0; mf < 2; mf++)
            #pragma unroll
            for (int nf = 0; nf < 4; nf++)
                acc[mf][nf] = __builtin_amdgcn_mfma_f32_16x16x32_bf16(af[mf], bw[nf], acc[mf][nf], 0, 0, 0);
        __syncthreads();
    }

    #pragma unroll
    for (int mf = 0; mf < 2; mf++) {
        #pragma unroll
        for (int i = 0; i < 4; i++) {
            int mloc = wr * 32 + mf * 16 + (lane >> 4) * 4 + i;
            int gm = row0 + mloc;
            if (gm >= M) continue;
            #pragma unroll
            for (int nf = 0; nf < 4; nf++) {
                int gc = wc * 64 + nf * 16 + fr;
                out1[(size_t)gm * DD + gc] = hswish(acc[mf][nf][i] + bias1[gc]);
            }
        }
    }
}

// ---- pre_pair1: [PR/PZ (EPB3)] ∥ [MB/PM (EPB2)], both A=IBbf K=160 ----
__global__ __launch_bounds__(512) void pre_pair1(
    const bf16* __restrict__ IBbf,
    const bf16* __restrict__ WTr, const bf16* __restrict__ WTz1,
    const float* __restrict__ b_r, const float* __restrict__ b_z,
    bf16* __restrict__ PR, bf16* __restrict__ PZ,
    const bf16* __restrict__ WTb, const bf16* __restrict__ WTm1,
    const float* __restrict__ b_bond, const float* __restrict__ b_m,
    bf16* __restrict__ MB, bf16* __restrict__ PM)
{
    __shared__ __align__(16) unsigned short As[128 * 40];
    __shared__ __align__(16) unsigned short Bs[128 * 40];
    __shared__ __align__(16) unsigned short Bs2[128 * 40];
    int b = blockIdx.x;
    if (b < 3126) {
        int bx = b % 1563, by = b / 1563;
        bg_body<128, 512, 1, 3>(IBbf, 160, 160, 160, 0, nullptr, 0, 0, 0, 0,
            WTr, WTz1, 160, b_r, b_z, PR, PZ, NE, bx * 128, by * 128, As, Bs, Bs2);
    } else {
        int b2 = b - 3126;
        int bx = b2 % 1563, by = b2 / 1563;
        bg_body<128, 512, 1, 2>(IBbf, 160, 160, 160, 0, nullptr, 0, 0, 0, 0,
            WTb, WTm1, 160, b_bond, b_m, MB, PM, NE, bx * 128, by * 128, As, Bs, Bs2);
    }
}

// ---- pre_pair2: [MN/PN (EPB2, A=node f32)] ∥ [TR0 = MB@w_r2 (EPB0)] ---
__global__ __launch_bounds__(512) void pre_pair2(
    const float* __restrict__ node,
    const bf16* __restrict__ WTn0, const bf16* __restrict__ WTn,
    const float* __restrict__ b_node, const float* __restrict__ b_n,
    bf16* __restrict__ MN, bf16* __restrict__ PN,
    const bf16* __restrict__ MB, const bf16* __restrict__ WTr2,
    bf16* __restrict__ TR)
{
    __shared__ __align__(16) unsigned short As[128 * 40];
    __shared__ __align__(16) unsigned short Bs[128 * 40];
    __shared__ __align__(16) unsigned short Bs2[128 * 40];
    int b = blockIdx.x;
    if (b < 1564) {
        int bx = b % 782, by = b / 782;
        bg_body<128, 512, 1, 2>(node, FN, 160, FN, 1, nullptr, 0, 0, 0, 0,
            WTn0, WTn, 160, b_node, b_n, MN, PN, NN, bx * 128, by * 128, As, Bs, Bs2);
    } else {
        int b2 = b - 1564;
        int bx = b2 % 1563, by = b2 / 1563;
        bg_body<128, 512, 0, 0>(MB, 256, 256, 256, 0, nullptr, 0, 0, 0, 0,
            WTr2, nullptr, 256, nullptr, nullptr, TR, nullptr, NE,
            bx * 128, by * 128, As, Bs, Bs2);
    }
}

// ---- final_pair64: BM=64 — [bond final -> f32 out_bond] ∥ [node final]
__global__ __launch_bounds__(512) void final_pair64(
    const bf16* __restrict__ IBbf, const bf16* __restrict__ MB,
    const bf16* __restrict__ WTbf, const float* __restrict__ b_bf,
    float* __restrict__ out_bond,
    const float* __restrict__ node, const bf16* __restrict__ MN,
    const bf16* __restrict__ WTnf, const float* __restrict__ b_nf,
    float* __restrict__ scratchN)
{
    __shared__ __align__(16) unsigned short As[64 * 40];    // 5.1 KB
    __shared__ __align__(16) unsigned short Bs[256 * 40];   // 20.5 KB
    int b = blockIdx.x;
    if (b < 3125) {
        bg64_body(IBbf, 160, 160, 160, 0, MB, 256, 256, 256, 0,
                  WTbf, 416, b_bf, out_bond, NE, b * 64, As, Bs);
    } else {
        bg64_body(node, FN, 160, FN, 1, MN, 256, 256, 256, 0,
                  WTnf, 416, b_nf, scratchN, NN, (b - 3125) * 64, As, Bs);
    }
}

extern "C" void kernel_launch(void* const* d_in, const int* in_sizes, int n_in,
                              void* d_out, int out_size, void* d_ws, size_t ws_size,
                              hipStream_t stream)
{
    const float* node  = (const float*)d_in[0];
    const float* bond  = (const float*)d_in[1];
    const int* connect = (const int*)d_in[2];
    const int* bnb     = (const int*)d_in[3];
    const float* w_node       = (const float*)d_in[4];
    const float* b_node       = (const float*)d_in[5];
    const float* w_node_final = (const float*)d_in[6];
    const float* b_node_final = (const float*)d_in[7];
    const float* w_bond       = (const float*)d_in[8];
    const float* b_bond       = (const float*)d_in[9];
    const float* w_bond_final = (const float*)d_in[10];
    const float* b_bond_final = (const float*)d_in[11];
    const float* w_z = (const float*)d_in[12];
    const float* b_z = (const float*)d_in[13];
    const float* w_r = (const float*)d_in[14];
    const float* b_r = (const float*)d_in[15];
    const float* u_  = (const float*)d_in[16];
    const float* w_m = (const float*)d_in[17];
    const float* b_m = (const float*)d_in[18];
    const float* w_n = (const float*)d_in[19];
    const float* b_n = (const float*)d_in[20];
    const float* u_n = (const float*)d_in[21];

    const int* i_idx = connect;
    const int* j_idx = connect + NE;
    const int* ij    = bnb;
    const int* ki    = bnb + NB;

    const size_t EBH = (size_t)NE * DD * 2;        // 102,400,000
    const size_t B_WT = (size_t)786432 * 2;        // 1.57 MB packed weights
    const size_t B_CSR = (size_t)NEPAD * 8 + (size_t)NB * 4
                       + (size_t)NNPAD * 8 + (size_t)NE * 4 + 2048;
    const size_t NEED = 5 * EBH + B_WT + B_CSR;    // ~519.4 MB (known to fit)

    float* out_node = (float*)d_out;
    float* out_bond = out_node + (size_t)NN * DD;

    if (ws_size < NEED) {
        fill_kernel<<<2048, 256, 0, stream>>>((float*)d_out, 1e6f, (long)out_size / 4);
        return;
    }

    char* base = (char*)d_ws;
    bf16* PR = (bf16*)base;                       base += EBH;
    bf16* MB = (bf16*)base;                       base += EBH;
    bf16* TR = (bf16*)base;                       base += EBH;   // also IBbf
    bf16* PZ = (bf16*)base;                       base += EBH;   // also final-node scratch
    bf16* PM = (bf16*)base;                       base += EBH;
    char* wt = base;                              base += B_WT;
    int* offE  = (int*)base;                      base += (size_t)NEPAD * 4;
    int* curE  = (int*)base;                      base += (size_t)NEPAD * 4;
    int* nbLst = (int*)base;                      base += (size_t)NB * 4;
    int* offN  = (int*)base;                      base += (size_t)NNPAD * 4;
    int* curN  = (int*)base;                      base += (size_t)NNPAD * 4;
    int* agLst = (int*)base;                      base += (size_t)NE * 4;
    int* bsumE = (int*)base;                      base += 1024;
    int* bsumN = (int*)base;

    bf16* IBbf = TR;
    float* scratchN = (float*)PZ;    // PZ dead after last blend2 — no overlap with IBbf
    bf16* R = (bf16*)out_bond;
    bf16* S = R + (size_t)NE * DD;
    bf16* MN = (bf16*)out_node;
    bf16* PN = MN + (size_t)NN * DD;

    // packed-weight layout (elements) — must match pack_all
    bf16* wtb = (bf16*)wt;
    bf16* WTr  = wtb + 0;
    bf16* WTz1 = wtb + 40960;
    bf16* WTb  = wtb + 81920;
    bf16* WTm1 = wtb + 122880;
    bf16* WTn0 = wtb + 163840;
    bf16* WTn  = wtb + 204800;
    bf16* WTr2 = wtb + 245760;
    bf16* WTz2 = wtb + 311296;
    bf16* WTu  = wtb + 376832;
    bf16* WTnu = wtb + 442368;
    bf16* WTbf = wtb + 573440;
    bf16* WTnf = wtb + 679936;

    // ---- single-launch weight pack ----
    pack_all<<<3072, 256, 0, stream>>>(w_r, w_z, w_bond, w_m, w_node, w_n,
                                       u_, u_n, w_bond_final, w_node_final, wtb);

    // ---- merged CSR build (6 launches) ----
    zero2_kernel<<<(NEPAD + NNPAD + 255) / 256, 256, 0, stream>>>(offE, offN);
    count2_kernel<<<(NB + NE + 255) / 256, 256, 0, stream>>>(ij, j_idx, offE, offN);
    scan_block2<<<294, 256, 0, stream>>>(offE, offN, bsumE, bsumN);
    scan_bsum2<<<2, 256, 0, stream>>>(bsumE, bsumN);
    scan_add_copy2<<<(NEPAD + NNPAD + 255) / 256, 256, 0, stream>>>(
        offE, offN, bsumE, bsumN, curE, curN);
    lists2_kernel<<<(NB + NE + 255) / 256, 256, 0, stream>>>(ij, ki, j_idx,
                                                             curE, curN, nbLst, agLst);

    int blkIB = NE * 64 / 256;
    dim3 gB2(1563, 2);

    // ---- pre-loop: IB once, paired hoist GEMMs ----
    build_ib_bf<<<blkIB, 256, 0, stream>>>(node, bond, i_idx, IBbf);
    pre_pair1<<<6252, 512, 0, stream>>>(IBbf, WTr, WTz1, b_r, b_z, PR, PZ,
                                        WTb, WTm1, b_bond, b_m, MB, PM);
    pre_pair2<<<4690, 512, 0, stream>>>(node, WTn0, WTn, b_node, b_n, MN, PN,
                                        MB, WTr2, TR);

    for (int l = 0; l < 3; l++) {
        seg_sr_kernel<<<(NE + 3) / 4, 256, 0, stream>>>(MB, TR, PR, offE, nbLst, S, R);
        blend2<<<gB2, 512, 0, stream>>>(S, R, WTz2, WTu, PZ, PM, MB);
        int trb = (l < 2) ? 3126 : 0;
        pairk<<<trb + 782, 512, 0, stream>>>(trb, MB, WTr2, TR,
                                             MN, offN, agLst, WTnu, PN, MN);
    }

    // ---- finals ----
    build_ib_bf<<<blkIB, 256, 0, stream>>>(node, bond, i_idx, IBbf);
    final_pair64<<<4688, 512, 0, stream>>>(IBbf, MB, WTbf, b_bond_final, out_bond,
                                           node, MN, WTnf, b_node_final, scratchN);
    hipMemcpyAsync(out_node, scratchN, (size_t)NN * DD * 4,
                   hipMemcpyDeviceToDevice, stream);
}

// Round 14
// 2422.745 us; speedup vs baseline: 1.4414x; 1.0193x over previous
//
#include <hip/hip_runtime.h>
#include <hip/hip_bf16.h>

#define NN 100000   // nodes
#define NE 200000   // bonds
#define NB 600000   // bond neighbours
#define FN 133
#define FB 14
#define FIB 147     // FN+FB
#define DD 256
#define NEPAD (196 * 1024)
#define NNPAD (98 * 1024)

typedef __hip_bfloat16 bf16;
typedef __attribute__((ext_vector_type(8))) short short8;   // 8 bf16 = 4 VGPR
typedef __attribute__((ext_vector_type(4))) float f32x4;

__device__ __forceinline__ float hswish(float x) {
    float c = fminf(fmaxf(x + 3.f, 0.f), 6.f);
    return x * c * (1.f / 6.f);
}
__device__ __forceinline__ float sigmoidf(float x) {
    return 1.f / (1.f + __expf(-x));
}
__device__ __forceinline__ float tanh_fast(float x) {
    return 1.f - 2.f / (1.f + __expf(2.f * x));
}
__device__ __forceinline__ float bf2f(unsigned short u) {
    union { unsigned int i; float f; } c; c.i = (unsigned int)u << 16; return c.f;
}
__device__ __forceinline__ unsigned short f2bf(float v) {
    bf16 b = __float2bfloat16(v);
    unsigned short u; __builtin_memcpy(&u, &b, 2); return u;
}
__device__ __forceinline__ void unp8(short8 v, float* f) {
    #pragma unroll
    for (int j = 0; j < 8; j++) {
        short s = v[j]; unsigned short u; __builtin_memcpy(&u, &s, 2);
        f[j] = bf2f(u);
    }
}
__device__ __forceinline__ uint4 pk8(const float* f) {
    uint4 v;
    v.x = f2bf(f[0]) | ((unsigned)f2bf(f[1]) << 16);
    v.y = f2bf(f[2]) | ((unsigned)f2bf(f[3]) << 16);
    v.z = f2bf(f[4]) | ((unsigned)f2bf(f[5]) << 16);
    v.w = f2bf(f[6]) | ((unsigned)f2bf(f[7]) << 16);
    return v;
}

// ---------------- fill (ws-guard sentinel only) -------------------------
__global__ __launch_bounds__(256) void fill_kernel(float* __restrict__ p, float v, long n4) {
    long i = (long)blockIdx.x * 256 + threadIdx.x;
    long st = (long)gridDim.x * 256;
    float4 z = {v, v, v, v};
    for (; i < n4; i += st) ((float4*)p)[i] = z;
}

// ---------------- IB build: IBbf[e][160] = [node[i_idx[e]] | bond[e] | 0]
__global__ __launch_bounds__(256) void build_ib_bf(
    const float* __restrict__ node, const float* __restrict__ bond,
    const int* __restrict__ i_idx, bf16* __restrict__ IB)
{
    int t = blockIdx.x * 256 + threadIdx.x;
    int row = t >> 6;
    if (row >= NE) return;
    int lane = t & 63;
    if (lane >= 40) return;
    int src = i_idx[row];
    int c = lane * 4;
    unsigned short us[4];
    #pragma unroll
    for (int j = 0; j < 4; j++) {
        int k = c + j;
        float v = 0.f;
        if (k < FN)       v = node[(size_t)src * FN + k];
        else if (k < FIB) v = bond[(size_t)row * FB + (k - FN)];
        us[j] = f2bf(v);
    }
    ushort4 o = {us[0], us[1], us[2], us[3]};
    *(ushort4*)((unsigned short*)IB + (size_t)row * 160 + c) = o;
}

// ---------------- merged CSR build (E and N in one pass each) -----------
__global__ __launch_bounds__(256) void zero2_kernel(int* __restrict__ offE, int* __restrict__ offN)
{
    int i = blockIdx.x * 256 + threadIdx.x;
    if (i < NEPAD) offE[i] = 0;
    else if (i < NEPAD + NNPAD) offN[i - NEPAD] = 0;
}

__global__ __launch_bounds__(256) void count2_kernel(
    const int* __restrict__ ij, const int* __restrict__ jidx,
    int* __restrict__ offE, int* __restrict__ offN)
{
    int i = blockIdx.x * 256 + threadIdx.x;
    if (i < NB) atomicAdd(&offE[ij[i]], 1);
    else if (i < NB + NE) atomicAdd(&offN[jidx[i - NB]], 1);
}

__global__ __launch_bounds__(256) void scan_block2(
    int* __restrict__ offE, int* __restrict__ offN,
    int* __restrict__ bsumE, int* __restrict__ bsumN)
{
    __shared__ int lds[256];
    int* data; int* bs; int bb;
    if ((int)blockIdx.x < 196) { data = offE; bs = bsumE; bb = blockIdx.x; }
    else                       { data = offN; bs = bsumN; bb = blockIdx.x - 196; }
    int base = bb * 1024 + threadIdx.x * 4;
    int c0 = data[base], c1 = data[base + 1], c2 = data[base + 2], c3 = data[base + 3];
    int t = c0 + c1 + c2 + c3;
    lds[threadIdx.x] = t;
    __syncthreads();
    int x = t;
    for (int off = 1; off < 256; off <<= 1) {
        int y = (threadIdx.x >= off) ? lds[threadIdx.x - off] : 0;
        __syncthreads();
        x += y; lds[threadIdx.x] = x;
        __syncthreads();
    }
    int excl = x - t;
    data[base] = excl; data[base + 1] = excl + c0;
    data[base + 2] = excl + c0 + c1; data[base + 3] = excl + c0 + c1 + c2;
    if (threadIdx.x == 255) bs[bb] = x;
}

__global__ __launch_bounds__(256) void scan_bsum2(int* __restrict__ bsumE, int* __restrict__ bsumN)
{
    __shared__ int lds[256];
    int* bs = blockIdx.x ? bsumN : bsumE;
    int n = blockIdx.x ? 98 : 196;
    int t = (threadIdx.x < n) ? bs[threadIdx.x] : 0;
    lds[threadIdx.x] = t;
    __syncthreads();
    int x = t;
    for (int off = 1; off < 256; off <<= 1) {
        int y = (threadIdx.x >= off) ? lds[threadIdx.x - off] : 0;
        __syncthreads();
        x += y; lds[threadIdx.x] = x;
        __syncthreads();
    }
    if (threadIdx.x < n) bs[threadIdx.x] = x - t;
}

// merged scan_add + copy (offX finalized and mirrored into curX)
__global__ __launch_bounds__(256) void scan_add_copy2(
    int* __restrict__ offE, int* __restrict__ offN,
    const int* __restrict__ bsumE, const int* __restrict__ bsumN,
    int* __restrict__ curE, int* __restrict__ curN)
{
    int i = blockIdx.x * 256 + threadIdx.x;
    if (i < NEPAD) {
        int v = offE[i] + bsumE[i >> 10];
        offE[i] = v; curE[i] = v;
    } else if (i < NEPAD + NNPAD) {
        int j = i - NEPAD;
        int v = offN[j] + bsumN[j >> 10];
        offN[j] = v; curN[j] = v;
    }
}

__global__ __launch_bounds__(256) void lists2_kernel(
    const int* __restrict__ ij, const int* __restrict__ ki, const int* __restrict__ jidx,
    int* __restrict__ curE, int* __restrict__ curN,
    int* __restrict__ nbLst, int* __restrict__ agLst)
{
    int i = blockIdx.x * 256 + threadIdx.x;
    if (i < NB) { int p = atomicAdd(&curE[ij[i]], 1); nbLst[p] = ki[i]; }
    else if (i < NB + NE) {
        int e = i - NB;
        int p = atomicAdd(&curN[jidx[e]], 1); agLst[p] = e;
    }
}

// ------------- single-launch weight pack (fixed layout, 786432 elems) ---
__global__ __launch_bounds__(256) void pack_all(
    const float* __restrict__ w_r, const float* __restrict__ w_z,
    const float* __restrict__ w_bond, const float* __restrict__ w_m,
    const float* __restrict__ w_node, const float* __restrict__ w_n,
    const float* __restrict__ u_, const float* __restrict__ u_n,
    const float* __restrict__ w_bf, const float* __restrict__ w_nf,
    bf16* __restrict__ wt)
{
    int idx = blockIdx.x * 256 + threadIdx.x;
    if (idx >= 786432) return;
    float v = 0.f;
    if (idx < 245760) {
        int r = idx / 40960;
        int loc = idx - r * 40960;
        int n = loc / 160, k = loc % 160;
        const float* W = (r == 0) ? w_r : (r == 1) ? w_z : (r == 2) ? w_bond
                       : (r == 3) ? w_m : (r == 4) ? w_node : w_n;
        int K1 = (r < 4) ? FIB : FN;
        if (k < K1) v = W[(size_t)k * DD + n];
    } else if (idx < 442368) {
        int r = (idx - 245760) / 65536;
        int loc = (idx - 245760) - r * 65536;
        int n = loc / 256, k = loc % 256;
        const float* W = (r == 0) ? (w_r + (size_t)FIB * DD)
                       : (r == 1) ? (w_z + (size_t)FIB * DD) : u_;
        v = W[(size_t)k * DD + n];
    } else if (idx < 573440) {
        int loc = idx - 442368;
        int n = loc / 512, k = loc % 512;
        v = u_n[(size_t)k * DD + n];
    } else {
        int r = (idx - 573440) / 106496;
        int loc = (idx - 573440) - r * 106496;
        int n = loc / 416, k = loc % 416;
        const float* W = r ? w_nf : w_bf;
        int K1 = r ? FN : FIB;
        if (k < K1)        v = W[(size_t)k * DD + n];
        else if (k >= 160) v = W[(size_t)(K1 + k - 160) * DD + n];
    }
    wt[idx] = __float2bfloat16(v);
}

// -------- fused seg_s + seg_r: one CSR walk, one MB gather pass ---------
__global__ __launch_bounds__(256) void seg_sr_kernel(
    const bf16* __restrict__ MB, const bf16* __restrict__ TR,
    const bf16* __restrict__ PR, const int* __restrict__ off,
    const int* __restrict__ lst,
    bf16* __restrict__ S, bf16* __restrict__ R)
{
    int sid = blockIdx.x * 4 + (threadIdx.x >> 6);
    if (sid >= NE) return;
    int lane = threadIdx.x & 63;
    ushort4 up = *(const ushort4*)((const unsigned short*)PR + (size_t)sid * DD + lane * 4);
    float p0 = bf2f(up.x), p1 = bf2f(up.y), p2 = bf2f(up.z), p3 = bf2f(up.w);
    int b = off[sid], e = off[sid + 1];
    float s0 = 0, s1 = 0, s2 = 0, s3 = 0;
    float r0 = 0, r1 = 0, r2 = 0, r3 = 0;
    for (int t = b; t < e; t++) {
        int src = lst[t];
        ushort4 um = *(const ushort4*)((const unsigned short*)MB + (size_t)src * DD + lane * 4);
        ushort4 ut = *(const ushort4*)((const unsigned short*)TR + (size_t)src * DD + lane * 4);
        float m0 = bf2f(um.x), m1 = bf2f(um.y), m2 = bf2f(um.z), m3 = bf2f(um.w);
        s0 += m0; s1 += m1; s2 += m2; s3 += m3;
        r0 += sigmoidf(p0 + bf2f(ut.x)) * m0;
        r1 += sigmoidf(p1 + bf2f(ut.y)) * m1;
        r2 += sigmoidf(p2 + bf2f(ut.z)) * m2;
        r3 += sigmoidf(p3 + bf2f(ut.w)) * m3;
    }
    ushort4 os = {f2bf(s0), f2bf(s1), f2bf(s2), f2bf(s3)};
    ushort4 orr = {f2bf(r0), f2bf(r1), f2bf(r2), f2bf(r3)};
    *(ushort4*)((unsigned short*)S + (size_t)sid * DD + lane * 4) = os;
    *(ushort4*)((unsigned short*)R + (size_t)sid * DD + lane * 4) = orr;
}

// ======== blend2: two sequential K=256 GEMM phases, k-step 64 ===========
__global__ __launch_bounds__(512) void blend2(
    const bf16* __restrict__ S, const bf16* __restrict__ R,
    const bf16* __restrict__ WTz2, const bf16* __restrict__ WTu,
    const bf16* __restrict__ PZ, const bf16* __restrict__ PM,
    bf16* __restrict__ MB)
{
    __shared__ __align__(16) unsigned short As[128 * 72];   // 18.4 KB
    __shared__ __align__(16) unsigned short Bs[128 * 72];   // 18.4 KB
    const int tid = threadIdx.x;
    const int row0 = blockIdx.x * 128, col0 = blockIdx.y * 128;
    const int lane = tid & 63, w = tid >> 6;
    const int wr = w >> 1, wc = w & 1;
    const int fr = lane & 15, ko = (lane >> 4) * 8;

    f32x4 acc1[2][4] = {};
    f32x4 acc2[2][4] = {};

    #pragma unroll
    for (int ph = 0; ph < 2; ph++) {
        const bf16* A = (ph == 0) ? S : R;
        const bf16* W = (ph == 0) ? WTz2 : WTu;
        for (int k0 = 0; k0 < DD; k0 += 64) {
            {
                int mloc = tid >> 2, kq = (tid & 3) * 16;
                int mg = row0 + mloc;
                uint4 va = {0, 0, 0, 0}, va2 = {0, 0, 0, 0};
                if (mg < NE) {
                    va  = *(const uint4*)((const unsigned short*)A + (size_t)mg * DD + k0 + kq);
                    va2 = *(const uint4*)((const unsigned short*)A + (size_t)mg * DD + k0 + kq + 8);
                }
                uint4 vb  = *(const uint4*)((const unsigned short*)W + (size_t)(col0 + mloc) * DD + k0 + kq);
                uint4 vb2 = *(const uint4*)((const unsigned short*)W + (size_t)(col0 + mloc) * DD + k0 + kq + 8);
                *(uint4*)&As[mloc * 72 + kq] = va;
                *(uint4*)&As[mloc * 72 + kq + 8] = va2;
                *(uint4*)&Bs[mloc * 72 + kq] = vb;
                *(uint4*)&Bs[mloc * 72 + kq + 8] = vb2;
            }
            __syncthreads();
            #pragma unroll
            for (int kk = 0; kk < 64; kk += 32) {
                short8 af[2], bf8[4];
                #pragma unroll
                for (int mf = 0; mf < 2; mf++)
                    af[mf] = *(const short8*)&As[(wr * 32 + mf * 16 + fr) * 72 + kk + ko];
                #pragma unroll
                for (int nf = 0; nf < 4; nf++)
                    bf8[nf] = *(const short8*)&Bs[(wc * 64 + nf * 16 + fr) * 72 + kk + ko];
                #pragma unroll
                for (int mf = 0; mf < 2; mf++)
                    #pragma unroll
                    for (int nf = 0; nf < 4; nf++) {
                        if (ph == 0)
                            acc1[mf][nf] = __builtin_amdgcn_mfma_f32_16x16x32_bf16(af[mf], bf8[nf], acc1[mf][nf], 0, 0, 0);
                        else
                            acc2[mf][nf] = __builtin_amdgcn_mfma_f32_16x16x32_bf16(af[mf], bf8[nf], acc2[mf][nf], 0, 0, 0);
                    }
            }
            __syncthreads();
        }
    }

    #pragma unroll
    for (int mf = 0; mf < 2; mf++) {
        #pragma unroll
        for (int i = 0; i < 4; i++) {
            int mloc = wr * 32 + mf * 16 + (lane >> 4) * 4 + i;
            int gm = row0 + mloc;
            if (gm >= NE) continue;
            #pragma unroll
            for (int nf = 0; nf < 4; nf++) {
                int gc = col0 + wc * 64 + nf * 16 + fr;
                size_t idx = (size_t)gm * DD + gc;
                float z  = sigmoidf(acc1[mf][nf][i] + __bfloat162float(PZ[idx]));
                float mm = tanh_fast(acc2[mf][nf][i] + __bfloat162float(PM[idx]));
                float s  = __bfloat162float(S[idx]);
                MB[idx] = __float2bfloat16((1.f - z) * s + z * mm);
            }
        }
    }
}

// ======== pairk: [TR-GEMM BN=256 blocks] ∥ [node-update w/ fused AGG] ===
__global__ __launch_bounds__(512) void pairk(
    int trblocks,
    const bf16* __restrict__ MBn, const bf16* __restrict__ WTr2,
    bf16* __restrict__ TRo,
    const bf16* __restrict__ MN, const int* __restrict__ offN,
    const int* __restrict__ agLst, const bf16* __restrict__ WTnu,
    const bf16* __restrict__ PN, bf16* __restrict__ MNout)
{
    __shared__ __align__(16) unsigned short As[128 * 40];   // 10 KB
    __shared__ __align__(16) unsigned short Bs[256 * 40];   // 20 KB
    const int tid = threadIdx.x, lane = tid & 63, w = tid >> 6;
    const int fr = lane & 15, ko = (lane >> 4) * 8;
    const int mloc = tid >> 2, kq = (tid & 3) * 8;

    if ((int)blockIdx.x < trblocks) {
        // ---------------- TR GEMM: BM=128, BN=256 (MB read once) --------
        const int row0 = blockIdx.x * 128;
        const int wr = w >> 2, wc = w & 3;      // 2 x 4 waves
        const int mg = row0 + mloc;
        f32x4 acc[4][4] = {};
        for (int k0 = 0; k0 < 256; k0 += 32) {
            uint4 v = {0, 0, 0, 0};
            if (mg < NE)
                v = *(const uint4*)((const unsigned short*)MBn + (size_t)mg * DD + k0 + kq);
            *(uint4*)&As[mloc * 40 + kq] = v;
            #pragma unroll
            for (int it = 0; it < 2; ++it) {
                int nloc = (tid >> 2) + it * 128;
                *(uint4*)&Bs[nloc * 40 + kq] =
                    *(const uint4*)((const unsigned short*)WTr2 + (size_t)nloc * DD + k0 + kq);
            }
            __syncthreads();
            short8 af[4], bw[4];
            #pragma unroll
            for (int mf = 0; mf < 4; mf++)
                af[mf] = *(const short8*)&As[(wr * 64 + mf * 16 + fr) * 40 + ko];
            #pragma unroll
            for (int nf = 0; nf < 4; nf++)
                bw[nf] = *(const short8*)&Bs[(wc * 64 + nf * 16 + fr) * 40 + ko];
            #pragma unroll
            for (int mf = 0; mf < 4; mf++)
                #pragma unroll
                for (int nf = 0; nf < 4; nf++)
                    acc[mf][nf] = __builtin_amdgcn_mfma_f32_16x16x32_bf16(af[mf], bw[nf], acc[mf][nf], 0, 0, 0);
            __syncthreads();
        }
        #pragma unroll
        for (int mf = 0; mf < 4; mf++)
            #pragma unroll
            for (int i = 0; i < 4; i++) {
                int ml = wr * 64 + mf * 16 + (lane >> 4) * 4 + i;
                int gm = row0 + ml;
                if (gm >= NE) continue;
                #pragma unroll
                for (int nf = 0; nf < 4; nf++) {
                    int gc = wc * 64 + nf * 16 + fr;
                    TRo[(size_t)gm * DD + gc] = __float2bfloat16(acc[mf][nf][i]);
                }
            }
    } else {
        // ---------------- node update with fused AGG gather ----------------
        const int bx = blockIdx.x - trblocks;
        const int row0 = bx * 128;
        const int wr = w >> 2, wc = w & 3;
        const int mg = row0 + mloc;
        int eb = 0, ee = 0;
        if (mg < NN) { eb = offN[mg]; ee = offN[mg + 1]; }
        f32x4 acc[4][4] = {};
        for (int k0 = 0; k0 < 512; k0 += 32) {
            const int kg = k0 + kq;
            uint4 v = {0, 0, 0, 0};
            if (mg < NN) {
                if (kg < 256) {
                    v = *(const uint4*)((const unsigned short*)MN + (size_t)mg * DD + kg);
                } else {
                    const int kk = kg - 256;
                    float a[8] = {0, 0, 0, 0, 0, 0, 0, 0};
                    for (int t = eb; t < ee; t++) {
                        int src = agLst[t];
                        float m8[8];
                        unp8(*(const short8*)((const unsigned short*)MBn + (size_t)src * DD + kk), m8);
                        #pragma unroll
                        for (int j = 0; j < 8; j++) a[j] += m8[j];
                    }
                    v = pk8(a);
                }
            }
            *(uint4*)&As[mloc * 40 + kq] = v;
            #pragma unroll
            for (int it = 0; it < 2; ++it) {
                int nloc = (tid >> 2) + it * 128;
                *(uint4*)&Bs[nloc * 40 + kq] =
                    *(const uint4*)((const unsigned short*)WTnu + (size_t)nloc * 512 + k0 + kq);
            }
            __syncthreads();
            short8 af[4], bw[4];
            #pragma unroll
            for (int mf = 0; mf < 4; mf++)
                af[mf] = *(const short8*)&As[(wr * 64 + mf * 16 + fr) * 40 + ko];
            #pragma unroll
            for (int nf = 0; nf < 4; nf++)
                bw[nf] = *(const short8*)&Bs[(wc * 64 + nf * 16 + fr) * 40 + ko];
            #pragma unroll
            for (int mf = 0; mf < 4; mf++)
                #pragma unroll
                for (int nf = 0; nf < 4; nf++)
                    acc[mf][nf] = __builtin_amdgcn_mfma_f32_16x16x32_bf16(af[mf], bw[nf], acc[mf][nf], 0, 0, 0);
            __syncthreads();
        }
        #pragma unroll
        for (int mf = 0; mf < 4; mf++)
            #pragma unroll
            for (int i = 0; i < 4; i++) {
                int ml = wr * 64 + mf * 16 + (lane >> 4) * 4 + i;
                int gm = row0 + ml;
                if (gm >= NN) continue;
                #pragma unroll
                for (int nf = 0; nf < 4; nf++) {
                    int gc = wc * 64 + nf * 16 + fr;
                    size_t idx = (size_t)gm * DD + gc;
                    MNout[idx] = __float2bfloat16(
                        hswish(acc[mf][nf][i] + __bfloat162float(PN[idx])));
                }
            }
    }
}

// ---------------- bg_body: unified MFMA GEMM as device function ---------
// EPB: 0 lin(+b1)->bf16; 2 dual hsw/lin; 3 dual lin/lin; 6 hsw->f32
template <int BN, int NT, int DUAL, int EPB>
__device__ __forceinline__ void bg_body(
    const void* __restrict__ A1, int a1stride, int a1kw, int a1real, int a1f32,
    const void* __restrict__ A2, int a2stride, int a2kw, int a2real, int a2f32,
    const bf16* __restrict__ WT1, const bf16* __restrict__ WT2, int KT,
    const float* __restrict__ bias1, const float* __restrict__ bias2,
    void* __restrict__ out1, void* __restrict__ out2, int M,
    int row0, int col0,
    unsigned short* As, unsigned short* Bs, unsigned short* Bs2)
{
    constexpr int BM = 128;
    constexpr int nWc = BN / 64;
    constexpr int nWr = (NT / 64) / nWc;
    constexpr int MSPAN = BM / nWr;
    constexpr int MFR = MSPAN / 16;
    const int tid = threadIdx.x;
    const int lane = tid & 63, w = tid >> 6;
    const int wr = w / nWc, wc = w % nWc;
    const int fr = lane & 15, ko = (lane >> 4) * 8;

    f32x4 acc[MFR][4] = {};
    f32x4 acc2[DUAL ? MFR : 1][DUAL ? 4 : 1] = {};

    for (int k0 = 0; k0 < KT; k0 += 32) {
        #pragma unroll
        for (int it = 0; it < BM * 4 / NT; ++it) {
            int mloc = (tid >> 2) + it * (NT / 4);
            int mg = row0 + mloc;
            bool mok = (mg < M);
            int kq = (tid & 3) * 8;
            int kg = k0 + kq;
            const void* p; int stride, real, isf; int kk;
            if (kg < a1kw) { p = A1; stride = a1stride; real = a1real; isf = a1f32; kk = kg; }
            else           { p = A2; stride = a2stride; real = a2real; isf = a2f32; kk = kg - a1kw; }
            uint4 v = {0, 0, 0, 0};
            if (mok) {
                if (!isf) {
                    v = *(const uint4*)((const bf16*)p + (size_t)mg * stride + kk);
                } else {
                    const float* fp = (const float*)p + (size_t)mg * stride;
                    unsigned short us[8];
                    #pragma unroll
                    for (int j = 0; j < 8; j++)
                        us[j] = (kk + j < real) ? f2bf(fp[kk + j]) : (unsigned short)0;
                    v.x = us[0] | ((unsigned)us[1] << 16);
                    v.y = us[2] | ((unsigned)us[3] << 16);
                    v.z = us[4] | ((unsigned)us[5] << 16);
                    v.w = us[6] | ((unsigned)us[7] << 16);
                }
            }
            *(uint4*)&As[mloc * 40 + kq] = v;
        }
        #pragma unroll
        for (int it = 0; it < BN * 4 / NT; ++it) {
            int nloc = (tid >> 2) + it * (NT / 4);
            int kq = (tid & 3) * 8;
            *(uint4*)&Bs[nloc * 40 + kq] =
                *(const uint4*)&WT1[(size_t)(col0 + nloc) * KT + k0 + kq];
            if (DUAL)
                *(uint4*)&Bs2[nloc * 40 + kq] =
                    *(const uint4*)&WT2[(size_t)(col0 + nloc) * KT + k0 + kq];
        }
        __syncthreads();
        short8 a1f[MFR], b1f[4], b2f[DUAL ? 4 : 1];
        #pragma unroll
        for (int mf = 0; mf < MFR; mf++)
            a1f[mf] = *(const short8*)&As[(wr * MSPAN + mf * 16 + fr) * 40 + ko];
        #pragma unroll
        for (int nf = 0; nf < 4; nf++) {
            b1f[nf] = *(const short8*)&Bs[(wc * 64 + nf * 16 + fr) * 40 + ko];
            if (DUAL)
                b2f[nf] = *(const short8*)&Bs2[(wc * 64 + nf * 16 + fr) * 40 + ko];
        }
        #pragma unroll
        for (int mf = 0; mf < MFR; mf++)
            #pragma unroll
            for (int nf = 0; nf < 4; nf++) {
                acc[mf][nf] = __builtin_amdgcn_mfma_f32_16x16x32_bf16(a1f[mf], b1f[nf], acc[mf][nf], 0, 0, 0);
                if (DUAL)
                    acc2[mf][nf] = __builtin_amdgcn_mfma_f32_16x16x32_bf16(a1f[mf], b2f[nf], acc2[mf][nf], 0, 0, 0);
            }
        __syncthreads();
    }

    #pragma unroll
    for (int mf = 0; mf < MFR; mf++) {
        #pragma unroll
        for (int i = 0; i < 4; i++) {
            int mloc = wr * MSPAN + mf * 16 + (lane >> 4) * 4 + i;
            int gm = row0 + mloc;
            if (gm >= M) continue;
            #pragma unroll
            for (int nf = 0; nf < 4; nf++) {
                int gc = col0 + wc * 64 + nf * 16 + fr;
                size_t idx = (size_t)gm * DD + gc;
                float v = acc[mf][nf][i];
                if (EPB == 0) {
                    if (bias1) v += bias1[gc];
                    ((bf16*)out1)[idx] = __float2bfloat16(v);
                } else if (EPB == 2) {
                    ((bf16*)out1)[idx] = __float2bfloat16(hswish(v + bias1[gc]));
                    ((bf16*)out2)[idx] = __float2bfloat16(acc2[mf][nf][i] + bias2[gc]);
                } else if (EPB == 3) {
                    ((bf16*)out1)[idx] = __float2bfloat16(v + bias1[gc]);
                    ((bf16*)out2)[idx] = __float2bfloat16(acc2[mf][nf][i] + bias2[gc]);
                } else {  // EPB == 6
                    ((float*)out1)[idx] = hswish(v + bias1[gc]);
                }
            }
        }
    }
}

// ---------------- bg64_body: BM=64, BN=256, NT=512, EPB=6 (f32 out) -----
__device__ __forceinline__ void bg64_body(
    const void* __restrict__ A1, int a1stride, int a1kw, int a1real, int a1f32,
    const void* __restrict__ A2, int a2stride, int a2kw, int a2real, int a2f32,
    const bf16* __restrict__ WT1, int KT, const float* __restrict__ bias1,
    float* __restrict__ out1, int M, int row0,
    unsigned short* As, unsigned short* Bs)
{
    // nWc=4, nWr=2, MSPAN=32, MFR=2
    const int tid = threadIdx.x;
    const int lane = tid & 63, w = tid >> 6;
    const int wr = w >> 2, wc = w & 3;
    const int fr = lane & 15, ko = (lane >> 4) * 8;

    f32x4 acc[2][4] = {};

    for (int k0 = 0; k0 < KT; k0 += 32) {
        if (tid < 256) {
            int mloc = tid >> 2, kq = (tid & 3) * 8;
            int mg = row0 + mloc;
            int kg = k0 + kq;
            const void* p; int stride, real, isf; int kk;
            if (kg < a1kw) { p = A1; stride = a1stride; real = a1real; isf = a1f32; kk = kg; }
            else           { p = A2; stride = a2stride; real = a2real; isf = a2f32; kk = kg - a1kw; }
            uint4 v = {0, 0, 0, 0};
            if (mg < M) {
                if (!isf) {
                    v = *(const uint4*)((const bf16*)p + (size_t)mg * stride + kk);
                } else {
                    const float* fp = (const float*)p + (size_t)mg * stride;
                    unsigned short us[8];
                    #pragma unroll
                    for (int j = 0; j < 8; j++)
                        us[j] = (kk + j < real) ? f2bf(fp[kk + j]) : (unsigned short)0;
                    v.x = us[0] | ((unsigned)us[1] << 16);
                    v.y = us[2] | ((unsigned)us[3] << 16);
                    v.z = us[4] | ((unsigned)us[5] << 16);
                    v.w = us[6] | ((unsigned)us[7] << 16);
                }
            }
            *(uint4*)&As[mloc * 40 + kq] = v;
        }
        {
            int kq = (tid & 3) * 8;
            #pragma unroll
            for (int it = 0; it < 2; ++it) {
                int nloc = (tid >> 2) + it * 128;
                *(uint4*)&Bs[nloc * 40 + kq] =
                    *(const uint4*)&WT1[(size_t)nloc * KT + k0 + kq];
            }
        }
        __syncthreads();
        short8 af[2], bw[4];
        #pragma unroll
        for (int mf = 0; mf < 2; mf++)
            af[mf] = *(const short8*)&As[(wr * 32 + mf * 16 + fr) * 40 + ko];
        #pragma unroll
        for (int nf = 0; nf < 4; nf++)
            bw[nf] = *(const short8*)&Bs[(wc * 64 + nf * 16 + fr) * 40 + ko];
        #pragma unroll
        for (int mf = 0; mf < 2; mf++)
            #pragma unroll
            for (int nf = 0; nf < 4; nf++)
                acc[mf][nf] = __builtin_amdgcn_mfma_f32_16x16x32_bf16(af[mf], bw[nf], acc[mf][nf], 0, 0, 0);
        __syncthreads();
    }

    #pragma unroll
    for (int mf = 0; mf < 2; mf++) {
        #pragma unroll
        for (int i = 0; i < 4; i++) {
            int mloc = wr * 32 + mf * 16 + (lane >> 4) * 4 + i;
            int gm = row0 + mloc;
            if (gm >= M) continue;
            #pragma unroll
            for (int nf = 0; nf < 4; nf++) {
                int gc = wc * 64 + nf * 16 + fr;
                out1[(size_t)gm * DD + gc] = hswish(acc[mf][nf][i] + bias1[gc]);
            }
        }
    }
}

// ---- pre_pair1: [PR/PZ (EPB3)] ∥ [MB/PM (EPB2)], both A=IBbf K=160 ----
__global__ __launch_bounds__(512) void pre_pair1(
    const bf16* __restrict__ IBbf,
    const bf16* __restrict__ WTr, const bf16* __restrict__ WTz1,
    const float* __restrict__ b_r, const float* __restrict__ b_z,
    bf16* __restrict__ PR, bf16* __restrict__ PZ,
    const bf16* __restrict__ WTb, const bf16* __restrict__ WTm1,
    const float* __restrict__ b_bond, const float* __restrict__ b_m,
    bf16* __restrict__ MB, bf16* __restrict__ PM)
{
    __shared__ __align__(16) unsigned short As[128 * 40];
    __shared__ __align__(16) unsigned short Bs[128 * 40];
    __shared__ __align__(16) unsigned short Bs2[128 * 40];
    int b = blockIdx.x;
    if (b < 3126) {
        int bx = b % 1563, by = b / 1563;
        bg_body<128, 512, 1, 3>(IBbf, 160, 160, 160, 0, nullptr, 0, 0, 0, 0,
            WTr, WTz1, 160, b_r, b_z, PR, PZ, NE, bx * 128, by * 128, As, Bs, Bs2);
    } else {
        int b2 = b - 3126;
        int bx = b2 % 1563, by = b2 / 1563;
        bg_body<128, 512, 1, 2>(IBbf, 160, 160, 160, 0, nullptr, 0, 0, 0, 0,
            WTb, WTm1, 160, b_bond, b_m, MB, PM, NE, bx * 128, by * 128, As, Bs, Bs2);
    }
}

// ---- pre_pair2: [MN/PN (EPB2, A=node f32)] ∥ [TR0 = MB@w_r2 (EPB0)] ---
__global__ __launch_bounds__(512) void pre_pair2(
    const float* __restrict__ node,
    const bf16* __restrict__ WTn0, const bf16* __restrict__ WTn,
    const float* __restrict__ b_node, const float* __restrict__ b_n,
    bf16* __restrict__ MN, bf16* __restrict__ PN,
    const bf16* __restrict__ MB, const bf16* __restrict__ WTr2,
    bf16* __restrict__ TR)
{
    __shared__ __align__(16) unsigned short As[128 * 40];
    __shared__ __align__(16) unsigned short Bs[128 * 40];
    __shared__ __align__(16) unsigned short Bs2[128 * 40];
    int b = blockIdx.x;
    if (b < 1564) {
        int bx = b % 782, by = b / 782;
        bg_body<128, 512, 1, 2>(node, FN, 160, FN, 1, nullptr, 0, 0, 0, 0,
            WTn0, WTn, 160, b_node, b_n, MN, PN, NN, bx * 128, by * 128, As, Bs, Bs2);
    } else {
        int b2 = b - 1564;
        int bx = b2 % 1563, by = b2 / 1563;
        bg_body<128, 512, 0, 0>(MB, 256, 256, 256, 0, nullptr, 0, 0, 0, 0,
            WTr2, nullptr, 256, nullptr, nullptr, TR, nullptr, NE,
            bx * 128, by * 128, As, Bs, Bs2);
    }
}

// ---- final_pair64: BM=64 — [bond final -> out_bond] ∥ [node final -> out_node]
__global__ __launch_bounds__(512) void final_pair64(
    const bf16* __restrict__ IBbf, const bf16* __restrict__ MB,
    const bf16* __restrict__ WTbf, const float* __restrict__ b_bf,
    float* __restrict__ out_bond,
    const float* __restrict__ node, const bf16* __restrict__ MNf,
    const bf16* __restrict__ WTnf, const float* __restrict__ b_nf,
    float* __restrict__ out_node)
{
    __shared__ __align__(16) unsigned short As[64 * 40];    // 5.1 KB
    __shared__ __align__(16) unsigned short Bs[256 * 40];   // 20.5 KB
    int b = blockIdx.x;
    if (b < 3125) {
        bg64_body(IBbf, 160, 160, 160, 0, MB, 256, 256, 256, 0,
                  WTbf, 416, b_bf, out_bond, NE, b * 64, As, Bs);
    } else {
        bg64_body(node, FN, 160, FN, 1, MNf, 256, 256, 256, 0,
                  WTnf, 416, b_nf, out_node, NN, (b - 3125) * 64, As, Bs);
    }
}

extern "C" void kernel_launch(void* const* d_in, const int* in_sizes, int n_in,
                              void* d_out, int out_size, void* d_ws, size_t ws_size,
                              hipStream_t stream)
{
    const float* node  = (const float*)d_in[0];
    const float* bond  = (const float*)d_in[1];
    const int* connect = (const int*)d_in[2];
    const int* bnb     = (const int*)d_in[3];
    const float* w_node       = (const float*)d_in[4];
    const float* b_node       = (const float*)d_in[5];
    const float* w_node_final = (const float*)d_in[6];
    const float* b_node_final = (const float*)d_in[7];
    const float* w_bond       = (const float*)d_in[8];
    const float* b_bond       = (const float*)d_in[9];
    const float* w_bond_final = (const float*)d_in[10];
    const float* b_bond_final = (const float*)d_in[11];
    const float* w_z = (const float*)d_in[12];
    const float* b_z = (const float*)d_in[13];
    const float* w_r = (const float*)d_in[14];
    const float* b_r = (const float*)d_in[15];
    const float* u_  = (const float*)d_in[16];
    const float* w_m = (const float*)d_in[17];
    const float* b_m = (const float*)d_in[18];
    const float* w_n = (const float*)d_in[19];
    const float* b_n = (const float*)d_in[20];
    const float* u_n = (const float*)d_in[21];

    const int* i_idx = connect;
    const int* j_idx = connect + NE;
    const int* ij    = bnb;
    const int* ki    = bnb + NB;

    const size_t EBH = (size_t)NE * DD * 2;        // 102,400,000
    const size_t B_WT = (size_t)786432 * 2;        // 1.57 MB packed weights
    const size_t B_CSR = (size_t)NEPAD * 8 + (size_t)NB * 4
                       + (size_t)NNPAD * 8 + (size_t)NE * 4 + 2048;
    const size_t NEED = 5 * EBH + B_WT + B_CSR;    // ~519.4 MB (known to fit)

    float* out_node = (float*)d_out;
    float* out_bond = out_node + (size_t)NN * DD;

    if (ws_size < NEED) {
        fill_kernel<<<2048, 256, 0, stream>>>((float*)d_out, 1e6f, (long)out_size / 4);
        return;
    }

    char* base = (char*)d_ws;
    bf16* PR = (bf16*)base;                       base += EBH;   // also MN_final (l=2 out)
    bf16* MB = (bf16*)base;                       base += EBH;
    bf16* TR = (bf16*)base;                       base += EBH;   // also IBbf
    bf16* PZ = (bf16*)base;                       base += EBH;
    bf16* PM = (bf16*)base;                       base += EBH;
    char* wt = base;                              base += B_WT;
    int* offE  = (int*)base;                      base += (size_t)NEPAD * 4;
    int* curE  = (int*)base;                      base += (size_t)NEPAD * 4;
    int* nbLst = (int*)base;                      base += (size_t)NB * 4;
    int* offN  = (int*)base;                      base += (size_t)NNPAD * 4;
    int* curN  = (int*)base;                      base += (size_t)NNPAD * 4;
    int* agLst = (int*)base;                      base += (size_t)NE * 4;
    int* bsumE = (int*)base;                      base += 1024;
    int* bsumN = (int*)base;

    bf16* IBbf = TR;
    bf16* MNf = PR;                  // final MN (l=2 output); PR dead after l=2 seg_sr
    bf16* R = (bf16*)out_bond;
    bf16* S = R + (size_t)NE * DD;
    bf16* MN = (bf16*)out_node;
    bf16* PN = MN + (size_t)NN * DD;

    // packed-weight layout (elements) — must match pack_all
    bf16* wtb = (bf16*)wt;
    bf16* WTr  = wtb + 0;
    bf16* WTz1 = wtb + 40960;
    bf16* WTb  = wtb + 81920;
    bf16* WTm1 = wtb + 122880;
    bf16* WTn0 = wtb + 163840;
    bf16* WTn  = wtb + 204800;
    bf16* WTr2 = wtb + 245760;
    bf16* WTz2 = wtb + 311296;
    bf16* WTu  = wtb + 376832;
    bf16* WTnu = wtb + 442368;
    bf16* WTbf = wtb + 573440;
    bf16* WTnf = wtb + 679936;

    // ---- single-launch weight pack ----
    pack_all<<<3072, 256, 0, stream>>>(w_r, w_z, w_bond, w_m, w_node, w_n,
                                       u_, u_n, w_bond_final, w_node_final, wtb);

    // ---- merged CSR build (6 launches) ----
    zero2_kernel<<<(NEPAD + NNPAD + 255) / 256, 256, 0, stream>>>(offE, offN);
    count2_kernel<<<(NB + NE + 255) / 256, 256, 0, stream>>>(ij, j_idx, offE, offN);
    scan_block2<<<294, 256, 0, stream>>>(offE, offN, bsumE, bsumN);
    scan_bsum2<<<2, 256, 0, stream>>>(bsumE, bsumN);
    scan_add_copy2<<<(NEPAD + NNPAD + 255) / 256, 256, 0, stream>>>(
        offE, offN, bsumE, bsumN, curE, curN);
    lists2_kernel<<<(NB + NE + 255) / 256, 256, 0, stream>>>(ij, ki, j_idx,
                                                             curE, curN, nbLst, agLst);

    int blkIB = NE * 64 / 256;
    dim3 gB2(1563, 2);

    // ---- pre-loop: IB once, paired hoist GEMMs ----
    build_ib_bf<<<blkIB, 256, 0, stream>>>(node, bond, i_idx, IBbf);
    pre_pair1<<<6252, 512, 0, stream>>>(IBbf, WTr, WTz1, b_r, b_z, PR, PZ,
                                        WTb, WTm1, b_bond, b_m, MB, PM);
    pre_pair2<<<4690, 512, 0, stream>>>(node, WTn0, WTn, b_node, b_n, MN, PN,
                                        MB, WTr2, TR);

    for (int l = 0; l < 3; l++) {
        seg_sr_kernel<<<(NE + 3) / 4, 256, 0, stream>>>(MB, TR, PR, offE, nbLst, S, R);
        blend2<<<gB2, 512, 0, stream>>>(S, R, WTz2, WTu, PZ, PM, MB);
        // l<2: [TR_{l+1} (BN=256) || node-update in-place]; l=2: node-update -> MNf (PR slot)
        int trb = (l < 2) ? 1563 : 0;
        bf16* mnout = (l == 2) ? MNf : MN;
        pairk<<<trb + 782, 512, 0, stream>>>(trb, MB, WTr2, TR,
                                             MN, offN, agLst, WTnu, PN, mnout);
    }

    // ---- finals: direct f32 writes to d_out (no scratch, no memcpy) ----
    build_ib_bf<<<blkIB, 256, 0, stream>>>(node, bond, i_idx, IBbf);
    final_pair64<<<4688, 512, 0, stream>>>(IBbf, MB, WTbf, b_bond_final, out_bond,
                                           node, MNf, WTnf, b_node_final, out_node);
}